// Round 1
// baseline (564.398 us; speedup 1.0000x reference)
//
#include <hip/hip_runtime.h>
#include <math.h>

#define NNODES 20000
#define XP_COLS 65
#define NEG 0.2f

__device__ __forceinline__ float lrelu(float v){ return v > 0.f ? v : NEG * v; }

// ---------------- CSR build ----------------
__global__ void k_init_deg(int* __restrict__ deg){
  int i = blockIdx.x * 256 + threadIdx.x;
  if (i < NNODES) deg[i] = 1;               // self loop
}

__global__ void k_count(const int* __restrict__ dst, int E, int* __restrict__ deg){
  int e = blockIdx.x * 256 + threadIdx.x;
  if (e < E) atomicAdd(&deg[dst[e]], 1);
}

__global__ __launch_bounds__(1024) void k_scan(const int* __restrict__ deg,
                                               int* __restrict__ off,
                                               int* __restrict__ cursor){
  __shared__ int sh[1024];
  __shared__ int carry;
  int tid = threadIdx.x;
  if (tid == 0) carry = 0;
  __syncthreads();
  for (int base = 0; base < NNODES; base += 1024){
    int i = base + tid;
    int v = (i < NNODES) ? deg[i] : 0;
    sh[tid] = v;
    __syncthreads();
    for (int d = 1; d < 1024; d <<= 1){
      int t = (tid >= d) ? sh[tid - d] : 0;
      __syncthreads();
      sh[tid] += t;
      __syncthreads();
    }
    int excl = sh[tid] - v;
    int c = carry;
    if (i < NNODES){ off[i] = c + excl; cursor[i] = c + excl; }
    int tot = sh[1023];
    __syncthreads();
    if (tid == 0) carry += tot;
    __syncthreads();
  }
  if (tid == 0) off[NNODES] = carry;
}

__global__ void k_fill(const int* __restrict__ src, const int* __restrict__ dst, int E,
                       int* __restrict__ cursor, int* __restrict__ csr){
  int t = blockIdx.x * 256 + threadIdx.x;
  if (t < NNODES){
    int p = atomicAdd(&cursor[t], 1);
    csr[p] = t;                              // self loop src = node
  } else if (t < NNODES + E){
    int e = t - NNODES;
    int p = atomicAdd(&cursor[dst[e]], 1);
    csr[p] = src[e];
  }
}

// ---------------- proj GEMM with embedding gather: X = relu([emb[id], feat] @ W + b) ----------------
__global__ __launch_bounds__(256) void k_proj(const float* __restrict__ xp, const float* __restrict__ emb,
                                              const float* __restrict__ W, const float* __restrict__ b,
                                              float* __restrict__ X){
  __shared__ float As[16][132];
  __shared__ float Bs[16][128];
  int tid = threadIdx.x;
  int bm = blockIdx.x * 128;
  int tr = tid >> 4, tc = tid & 15;
  int a_r = tid >> 1;
  int a_c = (tid & 1) * 8;
  int b_r = tid >> 4;
  int b_c = (tid & 15) * 8;
  int gm = bm + a_r;
  bool mv = gm < NNODES;
  int id = 0;
  if (mv) id = (int)xp[(size_t)gm * XP_COLS];
  float acc[8][8];
  #pragma unroll
  for (int i = 0; i < 8; i++)
    #pragma unroll
    for (int j = 0; j < 8; j++) acc[i][j] = 0.f;

  for (int k0 = 0; k0 < 192; k0 += 16){
    #pragma unroll
    for (int i = 0; i < 8; i++){
      int k = k0 + a_c + i;
      float v = 0.f;
      if (mv) v = (k < 128) ? emb[(size_t)id * 128 + k]
                            : xp[(size_t)gm * XP_COLS + 1 + (k - 128)];
      As[a_c + i][a_r] = v;
    }
    const float* bp = W + (size_t)(k0 + b_r) * 128 + b_c;
    *(float4*)&Bs[b_r][b_c]     = *(const float4*)bp;
    *(float4*)&Bs[b_r][b_c + 4] = *(const float4*)(bp + 4);
    __syncthreads();
    #pragma unroll
    for (int kk = 0; kk < 16; kk++){
      float4 a0 = *(const float4*)&As[kk][tr * 8];
      float4 a1 = *(const float4*)&As[kk][tr * 8 + 4];
      float4 b0 = *(const float4*)&Bs[kk][tc * 8];
      float4 b1 = *(const float4*)&Bs[kk][tc * 8 + 4];
      float av[8] = {a0.x,a0.y,a0.z,a0.w,a1.x,a1.y,a1.z,a1.w};
      float bv[8] = {b0.x,b0.y,b0.z,b0.w,b1.x,b1.y,b1.z,b1.w};
      #pragma unroll
      for (int i = 0; i < 8; i++)
        #pragma unroll
        for (int j = 0; j < 8; j++)
          acc[i][j] = fmaf(av[i], bv[j], acc[i][j]);
    }
    __syncthreads();
  }
  #pragma unroll
  for (int i = 0; i < 8; i++){
    int m = bm + tr * 8 + i;
    if (m >= NNODES) continue;
    #pragma unroll
    for (int j = 0; j < 8; j++){
      int c = tc * 8 + j;
      float v = acc[i][j] + b[c];
      X[(size_t)m * 128 + c] = fmaxf(v, 0.f);
    }
  }
}

// ---------------- generic fp32 GEMM, z in {0,1} picks (B0,C0)/(B1,C1) ----------------
__global__ __launch_bounds__(256) void k_gemm2(const float* __restrict__ A,
                                               const float* __restrict__ B0, const float* __restrict__ B1,
                                               float* __restrict__ C0, float* __restrict__ C1,
                                               int K, int Nn){
  const float* B = blockIdx.z ? B1 : B0;
  float* C = blockIdx.z ? C1 : C0;
  __shared__ float As[16][132];
  __shared__ float Bs[16][128];
  int tid = threadIdx.x;
  int bm = blockIdx.y * 128;
  int bn = blockIdx.x * 128;
  int tr = tid >> 4, tc = tid & 15;
  int a_r = tid >> 1, a_c = (tid & 1) * 8;
  int b_r = tid >> 4, b_c = (tid & 15) * 8;
  int gm = bm + a_r;
  bool mv = gm < NNODES;
  const float* Ap = A + (size_t)gm * K;
  float acc[8][8];
  #pragma unroll
  for (int i = 0; i < 8; i++)
    #pragma unroll
    for (int j = 0; j < 8; j++) acc[i][j] = 0.f;

  for (int k0 = 0; k0 < K; k0 += 16){
    float4 av0 = {0,0,0,0}, av1 = {0,0,0,0};
    if (mv){
      av0 = *(const float4*)(Ap + k0 + a_c);
      av1 = *(const float4*)(Ap + k0 + a_c + 4);
    }
    As[a_c + 0][a_r] = av0.x; As[a_c + 1][a_r] = av0.y;
    As[a_c + 2][a_r] = av0.z; As[a_c + 3][a_r] = av0.w;
    As[a_c + 4][a_r] = av1.x; As[a_c + 5][a_r] = av1.y;
    As[a_c + 6][a_r] = av1.z; As[a_c + 7][a_r] = av1.w;
    const float* bp = B + (size_t)(k0 + b_r) * Nn + bn + b_c;
    *(float4*)&Bs[b_r][b_c]     = *(const float4*)bp;
    *(float4*)&Bs[b_r][b_c + 4] = *(const float4*)(bp + 4);
    __syncthreads();
    #pragma unroll
    for (int kk = 0; kk < 16; kk++){
      float4 a0 = *(const float4*)&As[kk][tr * 8];
      float4 a1 = *(const float4*)&As[kk][tr * 8 + 4];
      float4 b0 = *(const float4*)&Bs[kk][tc * 8];
      float4 b1 = *(const float4*)&Bs[kk][tc * 8 + 4];
      float av[8] = {a0.x,a0.y,a0.z,a0.w,a1.x,a1.y,a1.z,a1.w};
      float bv[8] = {b0.x,b0.y,b0.z,b0.w,b1.x,b1.y,b1.z,b1.w};
      #pragma unroll
      for (int i = 0; i < 8; i++)
        #pragma unroll
        for (int j = 0; j < 8; j++)
          acc[i][j] = fmaf(av[i], bv[j], acc[i][j]);
    }
    __syncthreads();
  }
  #pragma unroll
  for (int i = 0; i < 8; i++){
    int m = bm + tr * 8 + i;
    if (m >= NNODES) continue;
    float4 o0 = {acc[i][0], acc[i][1], acc[i][2], acc[i][3]};
    float4 o1 = {acc[i][4], acc[i][5], acc[i][6], acc[i][7]};
    float* cp = C + (size_t)m * Nn + bn + tc * 8;
    *(float4*)cp       = o0;
    *(float4*)(cp + 4) = o1;
  }
}

// ---------------- layer-1 GATv2 attention+aggregate (4 heads x 128 ch), block per node ----------------
__global__ __launch_bounds__(256) void k_attn1(const float* __restrict__ xl, const float* __restrict__ xr,
                                               const float* __restrict__ att, const float* __restrict__ bias,
                                               const int* __restrict__ off, const int* __restrict__ csr,
                                               float* __restrict__ out){
  int n = blockIdx.x;
  int tid = threadIdx.x;
  int w = tid >> 6, lane = tid & 63;
  int h = lane >> 4;
  const float* xrp = xr + (size_t)n * 512 + lane * 8;
  float4 r0 = *(const float4*)xrp, r1 = *(const float4*)(xrp + 4);
  const float* ap = att + lane * 8;
  float4 A0 = *(const float4*)ap, A1 = *(const float4*)(ap + 4);
  int beg = off[n], end = off[n + 1];

  float m = -INFINITY, s = 0.f;
  float acc[8] = {0,0,0,0,0,0,0,0};
  for (int j = beg + w; j < end; j += 4){
    int sn = csr[j];
    const float* xlp = xl + (size_t)sn * 512 + lane * 8;
    float4 x0 = *(const float4*)xlp, x1 = *(const float4*)(xlp + 4);
    float p;
    p  = A0.x * lrelu(x0.x + r0.x);
    p += A0.y * lrelu(x0.y + r0.y);
    p += A0.z * lrelu(x0.z + r0.z);
    p += A0.w * lrelu(x0.w + r0.w);
    p += A1.x * lrelu(x1.x + r1.x);
    p += A1.y * lrelu(x1.y + r1.y);
    p += A1.z * lrelu(x1.z + r1.z);
    p += A1.w * lrelu(x1.w + r1.w);
    p += __shfl_xor(p, 1);
    p += __shfl_xor(p, 2);
    p += __shfl_xor(p, 4);
    p += __shfl_xor(p, 8);          // all 16 lanes of head group hold e
    float nm = fmaxf(m, p);
    float al = __expf(m - nm);
    float ex = __expf(p - nm);
    m = nm;
    s = s * al + ex;
    acc[0] = acc[0] * al + ex * x0.x;
    acc[1] = acc[1] * al + ex * x0.y;
    acc[2] = acc[2] * al + ex * x0.z;
    acc[3] = acc[3] * al + ex * x0.w;
    acc[4] = acc[4] * al + ex * x1.x;
    acc[5] = acc[5] * al + ex * x1.y;
    acc[6] = acc[6] * al + ex * x1.z;
    acc[7] = acc[7] * al + ex * x1.w;
  }
  __shared__ float msh[4][4];
  __shared__ float ssh[4][4];
  __shared__ float accsh[4][512];
  if ((lane & 15) == 0) msh[w][h] = m;
  __syncthreads();
  float mg = fmaxf(fmaxf(msh[0][h], msh[1][h]), fmaxf(msh[2][h], msh[3][h]));
  float f = __expf(m - mg);        // 0 if this wave saw no edges
  if ((lane & 15) == 0) ssh[w][h] = s * f;
  #pragma unroll
  for (int i = 0; i < 8; i++) accsh[w][lane * 8 + i] = acc[i] * f;
  __syncthreads();
  for (int c = tid; c < 512; c += 256){
    float v = accsh[0][c] + accsh[1][c] + accsh[2][c] + accsh[3][c];
    int hh = c >> 7;
    float sv = ssh[0][hh] + ssh[1][hh] + ssh[2][hh] + ssh[3][hh];
    float o = v / (sv + 1e-16f) + bias[c];
    out[(size_t)n * 512 + c] = fmaxf(o, 0.f);   // relu after layer 1
  }
}

// ---------------- layer-2 GATv2 attention+aggregate (1 head x 128 ch), wave per node ----------------
__global__ __launch_bounds__(256) void k_attn2(const float* __restrict__ xl, const float* __restrict__ xr,
                                               const float* __restrict__ att, const float* __restrict__ bias,
                                               const int* __restrict__ off, const int* __restrict__ csr,
                                               float* __restrict__ out){
  int lane = threadIdx.x & 63;
  int n = blockIdx.x * 4 + (threadIdx.x >> 6);
  float2 rv = *(const float2*)(xr + (size_t)n * 128 + lane * 2);
  float2 av = *(const float2*)(att + lane * 2);
  int beg = off[n], end = off[n + 1];
  float m = -INFINITY, s = 0.f;
  float a0 = 0.f, a1 = 0.f;
  for (int j = beg; j < end; j++){
    int sn = csr[j];
    float2 xv = *(const float2*)(xl + (size_t)sn * 128 + lane * 2);
    float p = av.x * lrelu(xv.x + rv.x) + av.y * lrelu(xv.y + rv.y);
    p += __shfl_xor(p, 1);
    p += __shfl_xor(p, 2);
    p += __shfl_xor(p, 4);
    p += __shfl_xor(p, 8);
    p += __shfl_xor(p, 16);
    p += __shfl_xor(p, 32);         // all 64 lanes hold e
    float nm = fmaxf(m, p);
    float al = __expf(m - nm);
    float ex = __expf(p - nm);
    m = nm;
    s = s * al + ex;
    a0 = a0 * al + ex * xv.x;
    a1 = a1 * al + ex * xv.y;
  }
  float inv = 1.f / (s + 1e-16f);
  int c = lane * 2;
  out[(size_t)n * 128 + c]     = a0 * inv + bias[c];       // no relu on layer-2 output
  out[(size_t)n * 128 + c + 1] = a1 * inv + bias[c + 1];
}

// ---------------- output GEMM [N,128]@[128,10] + b, wave per node ----------------
__global__ __launch_bounds__(256) void k_out(const float* __restrict__ x2, const float* __restrict__ W,
                                             const float* __restrict__ b, float* __restrict__ out){
  __shared__ float Wsh[1280];
  int tid = threadIdx.x;
  for (int i = tid; i < 1280; i += 256) Wsh[i] = W[i];
  __syncthreads();
  int lane = tid & 63;
  int n = blockIdx.x * 4 + (tid >> 6);
  float v0 = x2[(size_t)n * 128 + lane];
  float v1 = x2[(size_t)n * 128 + 64 + lane];
  #pragma unroll
  for (int o = 0; o < 10; o++){
    float p = v0 * Wsh[lane * 10 + o] + v1 * Wsh[(64 + lane) * 10 + o];
    p += __shfl_xor(p, 1);
    p += __shfl_xor(p, 2);
    p += __shfl_xor(p, 4);
    p += __shfl_xor(p, 8);
    p += __shfl_xor(p, 16);
    p += __shfl_xor(p, 32);
    if (lane == 0) out[(size_t)n * 10 + o] = p + b[o];
  }
}

extern "C" void kernel_launch(void* const* d_in, const int* in_sizes, int n_in,
                              void* d_out, int out_size, void* d_ws, size_t ws_size,
                              hipStream_t stream){
  const float* xp    = (const float*)d_in[0];
  const int*   ei    = (const int*)  d_in[1];
  const float* emb   = (const float*)d_in[2];
  const float* projW = (const float*)d_in[3];
  const float* projb = (const float*)d_in[4];
  const float* W1l   = (const float*)d_in[5];
  const float* W1r   = (const float*)d_in[6];
  const float* att1  = (const float*)d_in[7];
  const float* b1    = (const float*)d_in[8];
  const float* W2l   = (const float*)d_in[9];
  const float* W2r   = (const float*)d_in[10];
  const float* att2  = (const float*)d_in[11];
  const float* b2    = (const float*)d_in[12];
  const float* outW  = (const float*)d_in[13];
  const float* outb  = (const float*)d_in[14];
  float* out = (float*)d_out;

  int E = in_sizes[1] / 2;
  const int* esrc = ei;
  const int* edst = ei + E;

  char* w = (char*)d_ws;
  int* deg  = (int*)w; w += (size_t)NNODES * 4;
  int* off  = (int*)w; w += (size_t)(NNODES + 4) * 4;
  int* cur  = (int*)w; w += (size_t)NNODES * 4;
  int* csr  = (int*)w; w += (size_t)(NNODES + E) * 4;
  float* X   = (float*)w; w += (size_t)NNODES * 128 * 4;
  float* xl1 = (float*)w; w += (size_t)NNODES * 512 * 4;
  float* xr1 = (float*)w; w += (size_t)NNODES * 512 * 4;
  float* X1  = (float*)w; w += (size_t)NNODES * 512 * 4;
  float* xl2 = X;    // X dead after layer-1 GEMMs
  float* xr2 = xr1;  // xr1 dead after attn1
  float* x2  = xl1;  // xl1 dead after attn1

  k_init_deg<<<(NNODES + 255) / 256, 256, 0, stream>>>(deg);
  k_count<<<(E + 255) / 256, 256, 0, stream>>>(edst, E, deg);
  k_scan<<<1, 1024, 0, stream>>>(deg, off, cur);
  k_fill<<<(NNODES + E + 255) / 256, 256, 0, stream>>>(esrc, edst, E, cur, csr);

  k_proj<<<dim3((NNODES + 127) / 128), 256, 0, stream>>>(xp, emb, projW, projb, X);
  k_gemm2<<<dim3(4, (NNODES + 127) / 128, 2), 256, 0, stream>>>(X, W1l, W1r, xl1, xr1, 128, 512);
  k_attn1<<<NNODES, 256, 0, stream>>>(xl1, xr1, att1, b1, off, csr, X1);
  k_gemm2<<<dim3(1, (NNODES + 127) / 128, 2), 256, 0, stream>>>(X1, W2l, W2r, xl2, xr2, 512, 128);
  k_attn2<<<NNODES / 4, 256, 0, stream>>>(xl2, xr2, att2, b2, off, csr, x2);
  k_out<<<NNODES / 4, 256, 0, stream>>>(x2, outW, outb, out);
}

// Round 2
// 521.101 us; speedup vs baseline: 1.0831x; 1.0831x over previous
//
#include <hip/hip_runtime.h>
#include <math.h>

#define NNODES 20000
#define XP_COLS 65
#define NEG 0.2f
#define BM 64
#define BN 128
#define BK 16

__device__ __forceinline__ float lrelu(float v){ return v > 0.f ? v : NEG * v; }

// ---------------- CSR build ----------------
__global__ void k_init_deg(int* __restrict__ deg){
  int i = blockIdx.x * 256 + threadIdx.x;
  if (i < NNODES) deg[i] = 1;               // self loop
}

__global__ void k_count(const int* __restrict__ dst, int E, int* __restrict__ deg){
  int e = blockIdx.x * 256 + threadIdx.x;
  if (e < E) atomicAdd(&deg[dst[e]], 1);
}

// chunked scan: 256 threads, each owns a contiguous chunk; 1 barrier.
__global__ __launch_bounds__(256) void k_scan(const int* __restrict__ deg,
                                              int* __restrict__ off,
                                              int* __restrict__ cursor){
  const int CH = (NNODES + 255) / 256;      // 79
  int tid = threadIdx.x;
  int lane = tid & 63, w = tid >> 6;
  int beg = tid * CH;
  int lim = beg + CH; if (lim > NNODES) lim = NNODES;
  int sum = 0;
  for (int i = beg; i < lim; i++) sum += deg[i];
  int inc = sum;                             // inclusive wave scan
  #pragma unroll
  for (int d = 1; d < 64; d <<= 1){
    int t = __shfl_up(inc, d, 64);
    if (lane >= d) inc += t;
  }
  __shared__ int wtot[4];
  if (lane == 63) wtot[w] = inc;
  __syncthreads();
  int wbase = 0;
  for (int i = 0; i < w; i++) wbase += wtot[i];
  int run = wbase + inc - sum;               // exclusive prefix of this chunk
  for (int i = beg; i < lim; i++){
    off[i] = run; cursor[i] = run;
    run += deg[i];
  }
  if (tid == 255) off[NNODES] = run;
}

__global__ void k_fill(const int* __restrict__ src, const int* __restrict__ dst, int E,
                       int* __restrict__ cursor, int* __restrict__ csr){
  int t = blockIdx.x * 256 + threadIdx.x;
  if (t < NNODES){
    int p = atomicAdd(&cursor[t], 1);
    csr[p] = t;                              // self loop src = node
  } else if (t < NNODES + E){
    int e = t - NNODES;
    int p = atomicAdd(&cursor[dst[e]], 1);
    csr[p] = src[e];
  }
}

// ---------------- proj GEMM with embedding gather: X = relu([emb[id], feat] @ W + b) ----------------
// BM=64, BN=128 tile, microtile 8x4
__global__ __launch_bounds__(256) void k_proj(const float* __restrict__ xp, const float* __restrict__ emb,
                                              const float* __restrict__ W, const float* __restrict__ b,
                                              float* __restrict__ X){
  __shared__ float As[BK][BM + 4];
  __shared__ float Bs[BK][BN + 4];
  int tid = threadIdx.x;
  int bm = blockIdx.x * BM;
  int tr = tid >> 5;          // 0..7 -> rows tr*8..tr*8+7
  int tc = tid & 31;          // cols tc*4
  int a_r = tid >> 2;         // 0..63
  int a_c = (tid & 3) * 4;
  int b_r = tid >> 4;         // 0..15
  int b_c = (tid & 15) * 8;
  int gm = bm + a_r;
  bool mv = gm < NNODES;
  int id = 0;
  if (mv) id = (int)xp[(size_t)gm * XP_COLS];
  float acc[8][4];
  #pragma unroll
  for (int i = 0; i < 8; i++)
    #pragma unroll
    for (int j = 0; j < 4; j++) acc[i][j] = 0.f;

  for (int k0 = 0; k0 < 192; k0 += BK){
    #pragma unroll
    for (int i = 0; i < 4; i++){
      int k = k0 + a_c + i;
      float v = 0.f;
      if (mv) v = (k < 128) ? emb[(size_t)id * 128 + k]
                            : xp[(size_t)gm * XP_COLS + 1 + (k - 128)];
      As[a_c + i][a_r] = v;
    }
    const float* bp = W + (size_t)(k0 + b_r) * 128 + b_c;
    *(float4*)&Bs[b_r][b_c]     = *(const float4*)bp;
    *(float4*)&Bs[b_r][b_c + 4] = *(const float4*)(bp + 4);
    __syncthreads();
    #pragma unroll
    for (int kk = 0; kk < BK; kk++){
      float4 a0 = *(const float4*)&As[kk][tr * 8];
      float4 a1 = *(const float4*)&As[kk][tr * 8 + 4];
      float4 bv = *(const float4*)&Bs[kk][tc * 4];
      float av[8] = {a0.x,a0.y,a0.z,a0.w,a1.x,a1.y,a1.z,a1.w};
      float bw[4] = {bv.x,bv.y,bv.z,bv.w};
      #pragma unroll
      for (int i = 0; i < 8; i++)
        #pragma unroll
        for (int j = 0; j < 4; j++)
          acc[i][j] = fmaf(av[i], bw[j], acc[i][j]);
    }
    __syncthreads();
  }
  #pragma unroll
  for (int i = 0; i < 8; i++){
    int m = bm + tr * 8 + i;
    if (m >= NNODES) continue;
    int c = tc * 4;
    float4 o = {fmaxf(acc[i][0] + b[c], 0.f), fmaxf(acc[i][1] + b[c+1], 0.f),
                fmaxf(acc[i][2] + b[c+2], 0.f), fmaxf(acc[i][3] + b[c+3], 0.f)};
    *(float4*)(X + (size_t)m * 128 + c) = o;
  }
}

// ---------------- generic fp32 GEMM, z picks (B0,C0)/(B1,C1); BM=64 BN=128 microtile 8x4 ----------------
__global__ __launch_bounds__(256) void k_gemm2(const float* __restrict__ A,
                                               const float* __restrict__ B0, const float* __restrict__ B1,
                                               float* __restrict__ C0, float* __restrict__ C1,
                                               int K, int Nn){
  const float* B = blockIdx.z ? B1 : B0;
  float* C = blockIdx.z ? C1 : C0;
  __shared__ float As[BK][BM + 4];
  __shared__ float Bs[BK][BN + 4];
  int tid = threadIdx.x;
  int bm = blockIdx.y * BM;
  int bn = blockIdx.x * BN;
  int tr = tid >> 5;          // 0..7
  int tc = tid & 31;          // 0..31
  int a_r = tid >> 2;         // 0..63
  int a_c = (tid & 3) * 4;
  int b_r = tid >> 4;         // 0..15
  int b_c = (tid & 15) * 8;
  int gm = bm + a_r;
  bool mv = gm < NNODES;
  const float* Ap = A + (size_t)gm * K;
  float acc[8][4];
  #pragma unroll
  for (int i = 0; i < 8; i++)
    #pragma unroll
    for (int j = 0; j < 4; j++) acc[i][j] = 0.f;

  for (int k0 = 0; k0 < K; k0 += BK){
    float4 av = {0,0,0,0};
    if (mv) av = *(const float4*)(Ap + k0 + a_c);
    As[a_c + 0][a_r] = av.x; As[a_c + 1][a_r] = av.y;
    As[a_c + 2][a_r] = av.z; As[a_c + 3][a_r] = av.w;
    const float* bp = B + (size_t)(k0 + b_r) * Nn + bn + b_c;
    *(float4*)&Bs[b_r][b_c]     = *(const float4*)bp;
    *(float4*)&Bs[b_r][b_c + 4] = *(const float4*)(bp + 4);
    __syncthreads();
    #pragma unroll
    for (int kk = 0; kk < BK; kk++){
      float4 a0 = *(const float4*)&As[kk][tr * 8];
      float4 a1 = *(const float4*)&As[kk][tr * 8 + 4];
      float4 bv = *(const float4*)&Bs[kk][tc * 4];
      float av8[8] = {a0.x,a0.y,a0.z,a0.w,a1.x,a1.y,a1.z,a1.w};
      float bw[4] = {bv.x,bv.y,bv.z,bv.w};
      #pragma unroll
      for (int i = 0; i < 8; i++)
        #pragma unroll
        for (int j = 0; j < 4; j++)
          acc[i][j] = fmaf(av8[i], bw[j], acc[i][j]);
    }
    __syncthreads();
  }
  #pragma unroll
  for (int i = 0; i < 8; i++){
    int m = bm + tr * 8 + i;
    if (m >= NNODES) continue;
    float4 o = {acc[i][0], acc[i][1], acc[i][2], acc[i][3]};
    *(float4*)(C + (size_t)m * Nn + bn + tc * 4) = o;
  }
}

// ---------------- layer-1 GATv2 attention+aggregate (4 heads x 128 ch), block per node ----------------
__global__ __launch_bounds__(256) void k_attn1(const float* __restrict__ xl, const float* __restrict__ xr,
                                               const float* __restrict__ att, const float* __restrict__ bias,
                                               const int* __restrict__ off, const int* __restrict__ csr,
                                               float* __restrict__ out){
  int n = blockIdx.x;
  int tid = threadIdx.x;
  int w = tid >> 6, lane = tid & 63;
  int h = lane >> 4;
  const float* xrp = xr + (size_t)n * 512 + lane * 8;
  float4 r0 = *(const float4*)xrp, r1 = *(const float4*)(xrp + 4);
  const float* ap = att + lane * 8;
  float4 A0 = *(const float4*)ap, A1 = *(const float4*)(ap + 4);
  int beg = off[n], end = off[n + 1];

  float m = -INFINITY, s = 0.f;
  float acc[8] = {0,0,0,0,0,0,0,0};
  for (int j = beg + w; j < end; j += 4){
    int sn = csr[j];
    const float* xlp = xl + (size_t)sn * 512 + lane * 8;
    float4 x0 = *(const float4*)xlp, x1 = *(const float4*)(xlp + 4);
    float p;
    p  = A0.x * lrelu(x0.x + r0.x);
    p += A0.y * lrelu(x0.y + r0.y);
    p += A0.z * lrelu(x0.z + r0.z);
    p += A0.w * lrelu(x0.w + r0.w);
    p += A1.x * lrelu(x1.x + r1.x);
    p += A1.y * lrelu(x1.y + r1.y);
    p += A1.z * lrelu(x1.z + r1.z);
    p += A1.w * lrelu(x1.w + r1.w);
    p += __shfl_xor(p, 1);
    p += __shfl_xor(p, 2);
    p += __shfl_xor(p, 4);
    p += __shfl_xor(p, 8);          // all 16 lanes of head group hold e
    float nm = fmaxf(m, p);
    float al = __expf(m - nm);
    float ex = __expf(p - nm);
    m = nm;
    s = s * al + ex;
    acc[0] = acc[0] * al + ex * x0.x;
    acc[1] = acc[1] * al + ex * x0.y;
    acc[2] = acc[2] * al + ex * x0.z;
    acc[3] = acc[3] * al + ex * x0.w;
    acc[4] = acc[4] * al + ex * x1.x;
    acc[5] = acc[5] * al + ex * x1.y;
    acc[6] = acc[6] * al + ex * x1.z;
    acc[7] = acc[7] * al + ex * x1.w;
  }
  __shared__ float msh[4][4];
  __shared__ float ssh[4][4];
  __shared__ float accsh[4][512];
  if ((lane & 15) == 0) msh[w][h] = m;
  __syncthreads();
  float mg = fmaxf(fmaxf(msh[0][h], msh[1][h]), fmaxf(msh[2][h], msh[3][h]));
  float f = __expf(m - mg);        // 0 if this wave saw no edges
  if ((lane & 15) == 0) ssh[w][h] = s * f;
  #pragma unroll
  for (int i = 0; i < 8; i++) accsh[w][lane * 8 + i] = acc[i] * f;
  __syncthreads();
  for (int c = tid; c < 512; c += 256){
    float v = accsh[0][c] + accsh[1][c] + accsh[2][c] + accsh[3][c];
    int hh = c >> 7;
    float sv = ssh[0][hh] + ssh[1][hh] + ssh[2][hh] + ssh[3][hh];
    float o = v / (sv + 1e-16f) + bias[c];
    out[(size_t)n * 512 + c] = fmaxf(o, 0.f);   // relu after layer 1
  }
}

// ---------------- layer-2 GATv2 attention+aggregate (1 head x 128 ch), wave per node ----------------
__global__ __launch_bounds__(256) void k_attn2(const float* __restrict__ xl, const float* __restrict__ xr,
                                               const float* __restrict__ att, const float* __restrict__ bias,
                                               const int* __restrict__ off, const int* __restrict__ csr,
                                               float* __restrict__ out){
  int lane = threadIdx.x & 63;
  int n = blockIdx.x * 4 + (threadIdx.x >> 6);
  float2 rv = *(const float2*)(xr + (size_t)n * 128 + lane * 2);
  float2 av = *(const float2*)(att + lane * 2);
  int beg = off[n], end = off[n + 1];
  float m = -INFINITY, s = 0.f;
  float a0 = 0.f, a1 = 0.f;
  for (int j = beg; j < end; j++){
    int sn = csr[j];
    float2 xv = *(const float2*)(xl + (size_t)sn * 128 + lane * 2);
    float p = av.x * lrelu(xv.x + rv.x) + av.y * lrelu(xv.y + rv.y);
    p += __shfl_xor(p, 1);
    p += __shfl_xor(p, 2);
    p += __shfl_xor(p, 4);
    p += __shfl_xor(p, 8);
    p += __shfl_xor(p, 16);
    p += __shfl_xor(p, 32);         // all 64 lanes hold e
    float nm = fmaxf(m, p);
    float al = __expf(m - nm);
    float ex = __expf(p - nm);
    m = nm;
    s = s * al + ex;
    a0 = a0 * al + ex * xv.x;
    a1 = a1 * al + ex * xv.y;
  }
  float inv = 1.f / (s + 1e-16f);
  int c = lane * 2;
  out[(size_t)n * 128 + c]     = a0 * inv + bias[c];       // no relu on layer-2 output
  out[(size_t)n * 128 + c + 1] = a1 * inv + bias[c + 1];
}

// ---------------- output GEMM [N,128]@[128,10] + b, wave per node ----------------
__global__ __launch_bounds__(256) void k_out(const float* __restrict__ x2, const float* __restrict__ W,
                                             const float* __restrict__ b, float* __restrict__ out){
  __shared__ float Wsh[1280];
  int tid = threadIdx.x;
  for (int i = tid; i < 1280; i += 256) Wsh[i] = W[i];
  __syncthreads();
  int lane = tid & 63;
  int n = blockIdx.x * 4 + (tid >> 6);
  float v0 = x2[(size_t)n * 128 + lane];
  float v1 = x2[(size_t)n * 128 + 64 + lane];
  #pragma unroll
  for (int o = 0; o < 10; o++){
    float p = v0 * Wsh[lane * 10 + o] + v1 * Wsh[(64 + lane) * 10 + o];
    p += __shfl_xor(p, 1);
    p += __shfl_xor(p, 2);
    p += __shfl_xor(p, 4);
    p += __shfl_xor(p, 8);
    p += __shfl_xor(p, 16);
    p += __shfl_xor(p, 32);
    if (lane == 0) out[(size_t)n * 10 + o] = p + b[o];
  }
}

extern "C" void kernel_launch(void* const* d_in, const int* in_sizes, int n_in,
                              void* d_out, int out_size, void* d_ws, size_t ws_size,
                              hipStream_t stream){
  const float* xp    = (const float*)d_in[0];
  const int*   ei    = (const int*)  d_in[1];
  const float* emb   = (const float*)d_in[2];
  const float* projW = (const float*)d_in[3];
  const float* projb = (const float*)d_in[4];
  const float* W1l   = (const float*)d_in[5];
  const float* W1r   = (const float*)d_in[6];
  const float* att1  = (const float*)d_in[7];
  const float* b1    = (const float*)d_in[8];
  const float* W2l   = (const float*)d_in[9];
  const float* W2r   = (const float*)d_in[10];
  const float* att2  = (const float*)d_in[11];
  const float* b2    = (const float*)d_in[12];
  const float* outW  = (const float*)d_in[13];
  const float* outb  = (const float*)d_in[14];
  float* out = (float*)d_out;

  int E = in_sizes[1] / 2;
  const int* esrc = ei;
  const int* edst = ei + E;

  char* w = (char*)d_ws;
  int* deg  = (int*)w; w += (size_t)NNODES * 4;
  int* off  = (int*)w; w += (size_t)(NNODES + 4) * 4;
  int* cur  = (int*)w; w += (size_t)NNODES * 4;
  int* csr  = (int*)w; w += (size_t)(NNODES + E) * 4;
  float* X   = (float*)w; w += (size_t)NNODES * 128 * 4;
  float* xl1 = (float*)w; w += (size_t)NNODES * 512 * 4;
  float* xr1 = (float*)w; w += (size_t)NNODES * 512 * 4;
  float* X1  = (float*)w; w += (size_t)NNODES * 512 * 4;
  float* xl2 = X;    // X dead after layer-1 GEMMs
  float* xr2 = xr1;  // xr1 dead after attn1
  float* x2  = xl1;  // xl1 dead after attn1

  k_init_deg<<<(NNODES + 255) / 256, 256, 0, stream>>>(deg);
  k_count<<<(E + 255) / 256, 256, 0, stream>>>(edst, E, deg);
  k_scan<<<1, 256, 0, stream>>>(deg, off, cur);
  k_fill<<<(NNODES + E + 255) / 256, 256, 0, stream>>>(esrc, edst, E, cur, csr);

  k_proj<<<dim3((NNODES + BM - 1) / BM), 256, 0, stream>>>(xp, emb, projW, projb, X);
  k_gemm2<<<dim3(4, (NNODES + BM - 1) / BM, 2), 256, 0, stream>>>(X, W1l, W1r, xl1, xr1, 128, 512);
  k_attn1<<<NNODES, 256, 0, stream>>>(xl1, xr1, att1, b1, off, csr, X1);
  k_gemm2<<<dim3(1, (NNODES + BM - 1) / BM, 2), 256, 0, stream>>>(X1, W2l, W2r, xl2, xr2, 512, 128);
  k_attn2<<<NNODES / 4, 256, 0, stream>>>(xl2, xr2, att2, b2, off, csr, x2);
  k_out<<<NNODES / 4, 256, 0, stream>>>(x2, outW, outb, out);
}

// Round 3
// 439.441 us; speedup vs baseline: 1.2844x; 1.1858x over previous
//
#include <hip/hip_runtime.h>
#include <math.h>

#define NNODES 20000
#define XP_COLS 65
#define NEG 0.2f
#define BM 64
#define BN 128
#define BK 16

typedef unsigned int uint32;
typedef __attribute__((ext_vector_type(8))) short short8;
typedef __attribute__((ext_vector_type(4))) float float4v;

__device__ __forceinline__ float lrelu(float v){ return v > 0.f ? v : NEG * v; }
__device__ __forceinline__ float bflo(uint32 u){ return __uint_as_float(u << 16); }
__device__ __forceinline__ float bfhi(uint32 u){ return __uint_as_float(u & 0xffff0000u); }
__device__ __forceinline__ unsigned short f2bf(float f){
  uint32 u = __float_as_uint(f);
  uint32 r = (u + 0x7fffu + ((u >> 16) & 1u)) >> 16;
  return (unsigned short)r;
}

// ---------------- CSR build ----------------
__global__ void k_init_deg(int* __restrict__ deg){
  int i = blockIdx.x * 256 + threadIdx.x;
  if (i < NNODES) deg[i] = 1;               // self loop
}

__global__ void k_count(const int* __restrict__ dst, int E, int* __restrict__ deg){
  int e = blockIdx.x * 256 + threadIdx.x;
  if (e < E) atomicAdd(&deg[dst[e]], 1);
}

// chunked scan: 256 threads, each owns a contiguous chunk; 1 barrier.
__global__ __launch_bounds__(256) void k_scan(const int* __restrict__ deg,
                                              int* __restrict__ off,
                                              int* __restrict__ cursor){
  const int CH = (NNODES + 255) / 256;      // 79
  int tid = threadIdx.x;
  int lane = tid & 63, w = tid >> 6;
  int beg = tid * CH;
  int lim = beg + CH; if (lim > NNODES) lim = NNODES;
  int sum = 0;
  for (int i = beg; i < lim; i++) sum += deg[i];
  int inc = sum;                             // inclusive wave scan
  #pragma unroll
  for (int d = 1; d < 64; d <<= 1){
    int t = __shfl_up(inc, d, 64);
    if (lane >= d) inc += t;
  }
  __shared__ int wtot[4];
  if (lane == 63) wtot[w] = inc;
  __syncthreads();
  int wbase = 0;
  for (int i = 0; i < w; i++) wbase += wtot[i];
  int run = wbase + inc - sum;               // exclusive prefix of this chunk
  for (int i = beg; i < lim; i++){
    off[i] = run; cursor[i] = run;
    run += deg[i];
  }
  if (tid == 255) off[NNODES] = run;
}

__global__ void k_fill(const int* __restrict__ src, const int* __restrict__ dst, int E,
                       int* __restrict__ cursor, int* __restrict__ csr){
  int t = blockIdx.x * 256 + threadIdx.x;
  if (t < NNODES){
    int p = atomicAdd(&cursor[t], 1);
    csr[p] = t;                              // self loop src = node
  } else if (t < NNODES + E){
    int e = t - NNODES;
    int p = atomicAdd(&cursor[dst[e]], 1);
    csr[p] = src[e];
  }
}

// ---------------- transpose+cast W1l/W1r [128][512] f32 -> [512][128] bf16 ----------------
__global__ void k_cvtW(const float* __restrict__ W0, const float* __restrict__ W1,
                       unsigned short* __restrict__ T0, unsigned short* __restrict__ T1){
  int idx = blockIdx.x * 256 + threadIdx.x;   // 0..131071
  const float* W = (idx < 65536) ? W0 : W1;
  unsigned short* T = (idx < 65536) ? T0 : T1;
  int i = idx & 65535;
  int k = i >> 9, n = i & 511;
  T[n * 128 + k] = f2bf(W[i]);
}

// ---------------- proj GEMM with embedding gather: Xb = bf16(relu([emb[id], feat] @ W + b)) ----------------
__global__ __launch_bounds__(256) void k_proj(const float* __restrict__ xp, const float* __restrict__ emb,
                                              const float* __restrict__ W, const float* __restrict__ b,
                                              unsigned short* __restrict__ Xb){
  __shared__ float As[BK][BM + 4];
  __shared__ float Bs[BK][BN + 4];
  int tid = threadIdx.x;
  int bm = blockIdx.x * BM;
  int tr = tid >> 5;          // 0..7
  int tc = tid & 31;          // 0..31
  int a_r = tid >> 2;         // 0..63
  int a_c = (tid & 3) * 4;
  int b_r = tid >> 4;         // 0..15
  int b_c = (tid & 15) * 8;
  int gm = bm + a_r;
  bool mv = gm < NNODES;
  int id = 0;
  if (mv) id = (int)xp[(size_t)gm * XP_COLS];
  float acc[8][4];
  #pragma unroll
  for (int i = 0; i < 8; i++)
    #pragma unroll
    for (int j = 0; j < 4; j++) acc[i][j] = 0.f;

  for (int k0 = 0; k0 < 192; k0 += BK){
    #pragma unroll
    for (int i = 0; i < 4; i++){
      int k = k0 + a_c + i;
      float v = 0.f;
      if (mv) v = (k < 128) ? emb[(size_t)id * 128 + k]
                            : xp[(size_t)gm * XP_COLS + 1 + (k - 128)];
      As[a_c + i][a_r] = v;
    }
    const float* bp = W + (size_t)(k0 + b_r) * 128 + b_c;
    *(float4*)&Bs[b_r][b_c]     = *(const float4*)bp;
    *(float4*)&Bs[b_r][b_c + 4] = *(const float4*)(bp + 4);
    __syncthreads();
    #pragma unroll
    for (int kk = 0; kk < BK; kk++){
      float4 a0 = *(const float4*)&As[kk][tr * 8];
      float4 a1 = *(const float4*)&As[kk][tr * 8 + 4];
      float4 bv = *(const float4*)&Bs[kk][tc * 4];
      float av[8] = {a0.x,a0.y,a0.z,a0.w,a1.x,a1.y,a1.z,a1.w};
      float bw[4] = {bv.x,bv.y,bv.z,bv.w};
      #pragma unroll
      for (int i = 0; i < 8; i++)
        #pragma unroll
        for (int j = 0; j < 4; j++)
          acc[i][j] = fmaf(av[i], bw[j], acc[i][j]);
    }
    __syncthreads();
  }
  #pragma unroll
  for (int i = 0; i < 8; i++){
    int m = bm + tr * 8 + i;
    if (m >= NNODES) continue;
    int c = tc * 4;
    ushort4 o;
    o.x = f2bf(fmaxf(acc[i][0] + b[c],     0.f));
    o.y = f2bf(fmaxf(acc[i][1] + b[c + 1], 0.f));
    o.z = f2bf(fmaxf(acc[i][2] + b[c + 2], 0.f));
    o.w = f2bf(fmaxf(acc[i][3] + b[c + 3], 0.f));
    *(ushort4*)(Xb + (size_t)m * 128 + c) = o;
  }
}

// ---------------- L1 GEMM via MFMA bf16: C[z] = Xb @ W[z], M=20000 K=128 N=512, C bf16 ----------------
__global__ __launch_bounds__(256) void k_gemm_mfma(const unsigned short* __restrict__ A,
                                                   const unsigned short* __restrict__ B0t,
                                                   const unsigned short* __restrict__ B1t,
                                                   unsigned short* __restrict__ C0,
                                                   unsigned short* __restrict__ C1){
  const unsigned short* Bt = blockIdx.z ? B1t : B0t;
  unsigned short* C = blockIdx.z ? C1 : C0;
  __shared__ unsigned short As[128][40];   // 80B rows: 20-bank stride, balanced b128 reads
  __shared__ unsigned short Bs[128][40];   // B stored n-major (from pre-transposed Wt)
  int tid = threadIdx.x;
  int bm = blockIdx.y * 128;
  int bn = blockIdx.x * 128;
  int w = tid >> 6, lane = tid & 63;
  int wm = (w >> 1) * 64, wn = (w & 1) * 64;
  int quad = lane >> 4, l16 = lane & 15;

  float4v acc[4][4];
  #pragma unroll
  for (int i = 0; i < 4; i++)
    #pragma unroll
    for (int j = 0; j < 4; j++) acc[i][j] = (float4v){0.f,0.f,0.f,0.f};

  int am = tid >> 2;            // 0..63
  int ak = (tid & 3) * 8;       // 0,8,16,24

  for (int k0 = 0; k0 < 128; k0 += 32){
    #pragma unroll
    for (int p = 0; p < 2; p++){
      int m = am + p * 64;
      int gm = bm + m;
      uint4 v = {0u,0u,0u,0u};
      if (gm < NNODES) v = *(const uint4*)(A + (size_t)gm * 128 + k0 + ak);
      *(uint4*)&As[m][ak] = v;
      uint4 bv = *(const uint4*)(Bt + (size_t)(bn + m) * 128 + k0 + ak);
      *(uint4*)&Bs[m][ak] = bv;
    }
    __syncthreads();
    short8 af[4], bf[4];
    #pragma unroll
    for (int t = 0; t < 4; t++){
      af[t] = *(const short8*)&As[wm + t * 16 + l16][quad * 8];
      bf[t] = *(const short8*)&Bs[wn + t * 16 + l16][quad * 8];
    }
    #pragma unroll
    for (int tm = 0; tm < 4; tm++)
      #pragma unroll
      for (int tn = 0; tn < 4; tn++)
        acc[tm][tn] = __builtin_amdgcn_mfma_f32_16x16x32_bf16(af[tm], bf[tn], acc[tm][tn], 0, 0, 0);
    __syncthreads();
  }
  #pragma unroll
  for (int tm = 0; tm < 4; tm++){
    #pragma unroll
    for (int r = 0; r < 4; r++){
      int row = bm + wm + tm * 16 + quad * 4 + r;
      if (row >= NNODES) continue;
      #pragma unroll
      for (int tn = 0; tn < 4; tn++){
        int col = bn + wn + tn * 16 + l16;
        C[(size_t)row * 512 + col] = f2bf(acc[tm][tn][r]);
      }
    }
  }
}

// ---------------- fp32 GEMM (layer 2): C0 bf16, C1 fp32 ----------------
__global__ __launch_bounds__(256) void k_gemm2(const float* __restrict__ A,
                                               const float* __restrict__ B0, const float* __restrict__ B1,
                                               unsigned short* __restrict__ C0b, float* __restrict__ C1,
                                               int K, int Nn){
  const float* B = blockIdx.z ? B1 : B0;
  __shared__ float As[BK][BM + 4];
  __shared__ float Bs[BK][BN + 4];
  int tid = threadIdx.x;
  int bm = blockIdx.y * BM;
  int bn = blockIdx.x * BN;
  int tr = tid >> 5;
  int tc = tid & 31;
  int a_r = tid >> 2, a_c = (tid & 3) * 4;
  int b_r = tid >> 4, b_c = (tid & 15) * 8;
  int gm = bm + a_r;
  bool mv = gm < NNODES;
  const float* Ap = A + (size_t)gm * K;
  float acc[8][4];
  #pragma unroll
  for (int i = 0; i < 8; i++)
    #pragma unroll
    for (int j = 0; j < 4; j++) acc[i][j] = 0.f;

  for (int k0 = 0; k0 < K; k0 += BK){
    float4 av = {0,0,0,0};
    if (mv) av = *(const float4*)(Ap + k0 + a_c);
    As[a_c + 0][a_r] = av.x; As[a_c + 1][a_r] = av.y;
    As[a_c + 2][a_r] = av.z; As[a_c + 3][a_r] = av.w;
    const float* bp = B + (size_t)(k0 + b_r) * Nn + bn + b_c;
    *(float4*)&Bs[b_r][b_c]     = *(const float4*)bp;
    *(float4*)&Bs[b_r][b_c + 4] = *(const float4*)(bp + 4);
    __syncthreads();
    #pragma unroll
    for (int kk = 0; kk < BK; kk++){
      float4 a0 = *(const float4*)&As[kk][tr * 8];
      float4 a1 = *(const float4*)&As[kk][tr * 8 + 4];
      float4 bv = *(const float4*)&Bs[kk][tc * 4];
      float av8[8] = {a0.x,a0.y,a0.z,a0.w,a1.x,a1.y,a1.z,a1.w};
      float bw[4] = {bv.x,bv.y,bv.z,bv.w};
      #pragma unroll
      for (int i = 0; i < 8; i++)
        #pragma unroll
        for (int j = 0; j < 4; j++)
          acc[i][j] = fmaf(av8[i], bw[j], acc[i][j]);
    }
    __syncthreads();
  }
  #pragma unroll
  for (int i = 0; i < 8; i++){
    int m = bm + tr * 8 + i;
    if (m >= NNODES) continue;
    if (blockIdx.z == 0){
      ushort4 o;
      o.x = f2bf(acc[i][0]); o.y = f2bf(acc[i][1]);
      o.z = f2bf(acc[i][2]); o.w = f2bf(acc[i][3]);
      *(ushort4*)(C0b + (size_t)m * Nn + bn + tc * 4) = o;
    } else {
      float4 o = {acc[i][0], acc[i][1], acc[i][2], acc[i][3]};
      *(float4*)(C1 + (size_t)m * Nn + bn + tc * 4) = o;
    }
  }
}

// ---------------- layer-1 GATv2 attention+aggregate (4 heads x 128 ch), bf16 inputs ----------------
__global__ __launch_bounds__(256) void k_attn1(const unsigned short* __restrict__ xl,
                                               const unsigned short* __restrict__ xr,
                                               const float* __restrict__ att, const float* __restrict__ bias,
                                               const int* __restrict__ off, const int* __restrict__ csr,
                                               float* __restrict__ out){
  int n = blockIdx.x;
  int tid = threadIdx.x;
  int w = tid >> 6, lane = tid & 63;
  int h = lane >> 4;
  uint4 ur = *(const uint4*)(xr + (size_t)n * 512 + lane * 8);
  float r[8] = {bflo(ur.x), bfhi(ur.x), bflo(ur.y), bfhi(ur.y),
                bflo(ur.z), bfhi(ur.z), bflo(ur.w), bfhi(ur.w)};
  const float* ap = att + lane * 8;
  float4 A0 = *(const float4*)ap, A1 = *(const float4*)(ap + 4);
  float a[8] = {A0.x,A0.y,A0.z,A0.w,A1.x,A1.y,A1.z,A1.w};
  int beg = off[n], end = off[n + 1];

  float m = -INFINITY, s = 0.f;
  float acc[8] = {0,0,0,0,0,0,0,0};
  for (int j = beg + w; j < end; j += 4){
    int sn = csr[j];
    uint4 ux = *(const uint4*)(xl + (size_t)sn * 512 + lane * 8);
    float x[8] = {bflo(ux.x), bfhi(ux.x), bflo(ux.y), bfhi(ux.y),
                  bflo(ux.z), bfhi(ux.z), bflo(ux.w), bfhi(ux.w)};
    float p = 0.f;
    #pragma unroll
    for (int i = 0; i < 8; i++) p += a[i] * lrelu(x[i] + r[i]);
    p += __shfl_xor(p, 1);
    p += __shfl_xor(p, 2);
    p += __shfl_xor(p, 4);
    p += __shfl_xor(p, 8);          // all 16 lanes of head group hold e
    if (__any(p > m)){
      float nm = fmaxf(m, p);
      float al = __expf(m - nm);
      float ex = __expf(p - nm);
      m = nm;
      s = s * al + ex;
      #pragma unroll
      for (int i = 0; i < 8; i++) acc[i] = acc[i] * al + ex * x[i];
    } else {
      float ex = __expf(p - m);
      s += ex;
      #pragma unroll
      for (int i = 0; i < 8; i++) acc[i] = fmaf(ex, x[i], acc[i]);
    }
  }
  __shared__ float msh[4][4];
  __shared__ float ssh[4][4];
  __shared__ float accsh[4][512];
  if ((lane & 15) == 0) msh[w][h] = m;
  __syncthreads();
  float mg = fmaxf(fmaxf(msh[0][h], msh[1][h]), fmaxf(msh[2][h], msh[3][h]));
  float f = __expf(m - mg);        // 0 if this wave saw no edges
  if ((lane & 15) == 0) ssh[w][h] = s * f;
  #pragma unroll
  for (int i = 0; i < 8; i++) accsh[w][lane * 8 + i] = acc[i] * f;
  __syncthreads();
  for (int c = tid; c < 512; c += 256){
    float v = accsh[0][c] + accsh[1][c] + accsh[2][c] + accsh[3][c];
    int hh = c >> 7;
    float sv = ssh[0][hh] + ssh[1][hh] + ssh[2][hh] + ssh[3][hh];
    float o = v / (sv + 1e-16f) + bias[c];
    out[(size_t)n * 512 + c] = fmaxf(o, 0.f);   // relu after layer 1
  }
}

// ---------------- layer-2 GATv2 attention+aggregate (1 head x 128 ch), bf16 xl ----------------
__global__ __launch_bounds__(256) void k_attn2(const unsigned short* __restrict__ xl,
                                               const float* __restrict__ xr,
                                               const float* __restrict__ att, const float* __restrict__ bias,
                                               const int* __restrict__ off, const int* __restrict__ csr,
                                               float* __restrict__ out){
  int lane = threadIdx.x & 63;
  int n = blockIdx.x * 4 + (threadIdx.x >> 6);
  float2 rv = *(const float2*)(xr + (size_t)n * 128 + lane * 2);
  float2 av = *(const float2*)(att + lane * 2);
  int beg = off[n], end = off[n + 1];
  float m = -INFINITY, s = 0.f;
  float a0 = 0.f, a1 = 0.f;
  for (int j = beg; j < end; j++){
    int sn = csr[j];
    uint32 u = *(const uint32*)(xl + (size_t)sn * 128 + lane * 2);
    float x0 = bflo(u), x1 = bfhi(u);
    float p = av.x * lrelu(x0 + rv.x) + av.y * lrelu(x1 + rv.y);
    p += __shfl_xor(p, 1);
    p += __shfl_xor(p, 2);
    p += __shfl_xor(p, 4);
    p += __shfl_xor(p, 8);
    p += __shfl_xor(p, 16);
    p += __shfl_xor(p, 32);         // all 64 lanes hold e
    if (p > m){
      float al = __expf(m - p);
      float ex = 1.f;
      m = p;
      s = s * al + ex;
      a0 = a0 * al + ex * x0;
      a1 = a1 * al + ex * x1;
    } else {
      float ex = __expf(p - m);
      s += ex;
      a0 = fmaf(ex, x0, a0);
      a1 = fmaf(ex, x1, a1);
    }
  }
  float inv = 1.f / (s + 1e-16f);
  int c = lane * 2;
  out[(size_t)n * 128 + c]     = a0 * inv + bias[c];       // no relu on layer-2 output
  out[(size_t)n * 128 + c + 1] = a1 * inv + bias[c + 1];
}

// ---------------- output GEMM [N,128]@[128,10] + b, wave per node ----------------
__global__ __launch_bounds__(256) void k_out(const float* __restrict__ x2, const float* __restrict__ W,
                                             const float* __restrict__ b, float* __restrict__ out){
  __shared__ float Wsh[1280];
  int tid = threadIdx.x;
  for (int i = tid; i < 1280; i += 256) Wsh[i] = W[i];
  __syncthreads();
  int lane = tid & 63;
  int n = blockIdx.x * 4 + (tid >> 6);
  float v0 = x2[(size_t)n * 128 + lane];
  float v1 = x2[(size_t)n * 128 + 64 + lane];
  #pragma unroll
  for (int o = 0; o < 10; o++){
    float p = v0 * Wsh[lane * 10 + o] + v1 * Wsh[(64 + lane) * 10 + o];
    p += __shfl_xor(p, 1);
    p += __shfl_xor(p, 2);
    p += __shfl_xor(p, 4);
    p += __shfl_xor(p, 8);
    p += __shfl_xor(p, 16);
    p += __shfl_xor(p, 32);
    if (lane == 0) out[(size_t)n * 10 + o] = p + b[o];
  }
}

extern "C" void kernel_launch(void* const* d_in, const int* in_sizes, int n_in,
                              void* d_out, int out_size, void* d_ws, size_t ws_size,
                              hipStream_t stream){
  const float* xp    = (const float*)d_in[0];
  const int*   ei    = (const int*)  d_in[1];
  const float* emb   = (const float*)d_in[2];
  const float* projW = (const float*)d_in[3];
  const float* projb = (const float*)d_in[4];
  const float* W1l   = (const float*)d_in[5];
  const float* W1r   = (const float*)d_in[6];
  const float* att1  = (const float*)d_in[7];
  const float* b1    = (const float*)d_in[8];
  const float* W2l   = (const float*)d_in[9];
  const float* W2r   = (const float*)d_in[10];
  const float* att2  = (const float*)d_in[11];
  const float* b2    = (const float*)d_in[12];
  const float* outW  = (const float*)d_in[13];
  const float* outb  = (const float*)d_in[14];
  float* out = (float*)d_out;

  int E = in_sizes[1] / 2;
  const int* esrc = ei;
  const int* edst = ei + E;

  char* w = (char*)d_ws;
  int* deg  = (int*)w; w += (size_t)NNODES * 4;
  int* off  = (int*)w; w += (size_t)(NNODES + 4) * 4;
  int* cur  = (int*)w; w += (size_t)NNODES * 4;
  int* csr  = (int*)w; w += (size_t)(NNODES + E) * 4;
  unsigned short* Xb   = (unsigned short*)w; w += (size_t)NNODES * 128 * 2;
  unsigned short* Wt0  = (unsigned short*)w; w += (size_t)512 * 128 * 2;
  unsigned short* Wt1  = (unsigned short*)w; w += (size_t)512 * 128 * 2;
  unsigned short* xl1b = (unsigned short*)w; w += (size_t)NNODES * 512 * 2;
  unsigned short* xr1b = (unsigned short*)w; w += (size_t)NNODES * 512 * 2;
  float* X1  = (float*)w; w += (size_t)NNODES * 512 * 4;
  unsigned short* xl2b = (unsigned short*)w; w += (size_t)NNODES * 128 * 2;
  float* xr2 = (float*)w; w += (size_t)NNODES * 128 * 4;
  float* x2  = (float*)w; w += (size_t)NNODES * 128 * 4;

  k_init_deg<<<(NNODES + 255) / 256, 256, 0, stream>>>(deg);
  k_count<<<(E + 255) / 256, 256, 0, stream>>>(edst, E, deg);
  k_scan<<<1, 256, 0, stream>>>(deg, off, cur);
  k_fill<<<(NNODES + E + 255) / 256, 256, 0, stream>>>(esrc, edst, E, cur, csr);

  k_cvtW<<<512, 256, 0, stream>>>(W1l, W1r, Wt0, Wt1);
  k_proj<<<dim3((NNODES + BM - 1) / BM), 256, 0, stream>>>(xp, emb, projW, projb, Xb);
  k_gemm_mfma<<<dim3(4, (NNODES + 127) / 128, 2), 256, 0, stream>>>(Xb, Wt0, Wt1, xl1b, xr1b);
  k_attn1<<<NNODES, 256, 0, stream>>>(xl1b, xr1b, att1, b1, off, csr, X1);
  k_gemm2<<<dim3(1, (NNODES + BM - 1) / BM, 2), 256, 0, stream>>>(X1, W2l, W2r, xl2b, xr2, 512, 128);
  k_attn2<<<NNODES / 4, 256, 0, stream>>>(xl2b, xr2, att2, b2, off, csr, x2);
  k_out<<<NNODES / 4, 256, 0, stream>>>(x2, outW, outb, out);
}

// Round 4
// 372.346 us; speedup vs baseline: 1.5158x; 1.1802x over previous
//
#include <hip/hip_runtime.h>
#include <math.h>

#define NNODES 20000
#define XP_COLS 65
#define NEG 0.2f

typedef unsigned int uint32;
typedef __attribute__((ext_vector_type(8))) short short8;
typedef __attribute__((ext_vector_type(4))) float float4v;

__device__ __forceinline__ float lrelu(float v){ return v > 0.f ? v : NEG * v; }
__device__ __forceinline__ float bflo(uint32 u){ return __uint_as_float(u << 16); }
__device__ __forceinline__ float bfhi(uint32 u){ return __uint_as_float(u & 0xffff0000u); }
__device__ __forceinline__ unsigned short f2bf(float f){
  uint32 u = __float_as_uint(f);
  uint32 r = (u + 0x7fffu + ((u >> 16) & 1u)) >> 16;
  return (unsigned short)r;
}

// ---------------- CSR build ----------------
__global__ void k_init_deg(int* __restrict__ deg){
  int i = blockIdx.x * 256 + threadIdx.x;
  if (i < NNODES) deg[i] = 1;               // self loop
}

__global__ void k_count(const int* __restrict__ dst, int E, int* __restrict__ deg){
  int e = blockIdx.x * 256 + threadIdx.x;
  if (e < E) atomicAdd(&deg[dst[e]], 1);
}

__global__ __launch_bounds__(256) void k_scan(const int* __restrict__ deg,
                                              int* __restrict__ off,
                                              int* __restrict__ cursor){
  const int CH = (NNODES + 255) / 256;      // 79
  int tid = threadIdx.x;
  int lane = tid & 63, w = tid >> 6;
  int beg = tid * CH;
  int lim = beg + CH; if (lim > NNODES) lim = NNODES;
  int sum = 0;
  for (int i = beg; i < lim; i++) sum += deg[i];
  int inc = sum;
  #pragma unroll
  for (int d = 1; d < 64; d <<= 1){
    int t = __shfl_up(inc, d, 64);
    if (lane >= d) inc += t;
  }
  __shared__ int wtot[4];
  if (lane == 63) wtot[w] = inc;
  __syncthreads();
  int wbase = 0;
  for (int i = 0; i < w; i++) wbase += wtot[i];
  int run = wbase + inc - sum;
  for (int i = beg; i < lim; i++){
    off[i] = run; cursor[i] = run;
    run += deg[i];
  }
  if (tid == 255) off[NNODES] = run;
}

__global__ void k_fill(const int* __restrict__ src, const int* __restrict__ dst, int E,
                       int* __restrict__ cursor, int* __restrict__ csr){
  int t = blockIdx.x * 256 + threadIdx.x;
  if (t < NNODES){
    int p = atomicAdd(&cursor[t], 1);
    csr[p] = t;
  } else if (t < NNODES + E){
    int e = t - NNODES;
    int p = atomicAdd(&cursor[dst[e]], 1);
    csr[p] = src[e];
  }
}

// ---------------- transpose+cast all weights to bf16 n-major [N][K] ----------------
// W1l/W1r [128][512] -> [512][128]; W2l/W2r [512][128] -> [128][512]; projW [192][128] -> [128][192]
__global__ void k_cvt(const float* __restrict__ W1l, const float* __restrict__ W1r,
                      const float* __restrict__ W2l, const float* __restrict__ W2r,
                      const float* __restrict__ projW,
                      unsigned short* __restrict__ T1l, unsigned short* __restrict__ T1r,
                      unsigned short* __restrict__ T2l, unsigned short* __restrict__ T2r,
                      unsigned short* __restrict__ Tp){
  int idx = blockIdx.x * 256 + threadIdx.x;
  if (idx < 65536){
    int k = idx >> 9, n = idx & 511;
    T1l[n * 128 + k] = f2bf(W1l[idx]);
  } else if (idx < 131072){
    int i = idx - 65536; int k = i >> 9, n = i & 511;
    T1r[n * 128 + k] = f2bf(W1r[i]);
  } else if (idx < 196608){
    int i = idx - 131072; int k = i >> 7, n = i & 127;
    T2l[n * 512 + k] = f2bf(W2l[i]);
  } else if (idx < 262144){
    int i = idx - 196608; int k = i >> 7, n = i & 127;
    T2r[n * 512 + k] = f2bf(W2r[i]);
  } else if (idx < 286720){
    int i = idx - 262144; int k = i >> 7, n = i & 127;
    Tp[n * 192 + k] = f2bf(projW[i]);
  }
}

// ---------------- proj via MFMA with fused gather: Xb = bf16(relu([emb[id],feat] @ W + b)) ----------------
// K=192 (tiles of 32 are purely emb (k<128) or purely feat), N=128, BM=64
__global__ __launch_bounds__(256) void k_proj_mfma(const float* __restrict__ xp,
                                                   const float* __restrict__ emb,
                                                   const unsigned short* __restrict__ Bt,
                                                   const float* __restrict__ bias,
                                                   unsigned short* __restrict__ Xb){
  __shared__ unsigned short As[64][40];
  __shared__ unsigned short Bs[128][40];
  __shared__ int ids[64];
  int tid = threadIdx.x;
  int bm = blockIdx.x * 64;
  int w = tid >> 6, lane = tid & 63;
  int wm = (w >> 1) * 32, wn = (w & 1) * 64;
  int quad = lane >> 4, l16 = lane & 15;
  if (tid < 64){
    int g = bm + tid;
    ids[tid] = (g < NNODES) ? (int)xp[(size_t)g * XP_COLS] : 0;
  }
  float4v acc[2][4];
  #pragma unroll
  for (int i = 0; i < 2; i++)
    #pragma unroll
    for (int j = 0; j < 4; j++) acc[i][j] = (float4v){0.f,0.f,0.f,0.f};
  int am = tid >> 2, ak = (tid & 3) * 8;
  int gm = bm + am;
  bool mv = gm < NNODES;
  int brow = tid >> 1, bk = (tid & 1) * 16;
  __syncthreads();

  for (int k0 = 0; k0 < 192; k0 += 32){
    float v[8];
    if (k0 < 128){
      const float* ep = emb + (size_t)ids[am] * 128 + k0 + ak;
      float4 e0 = *(const float4*)ep;
      float4 e1 = *(const float4*)(ep + 4);
      v[0]=e0.x; v[1]=e0.y; v[2]=e0.z; v[3]=e0.w;
      v[4]=e1.x; v[5]=e1.y; v[6]=e1.z; v[7]=e1.w;
    } else {
      const float* fp = xp + (size_t)gm * XP_COLS + 1 + (k0 - 128) + ak;
      #pragma unroll
      for (int i = 0; i < 8; i++) v[i] = mv ? fp[i] : 0.f;
    }
    ushort4 o0, o1;
    o0.x=f2bf(v[0]); o0.y=f2bf(v[1]); o0.z=f2bf(v[2]); o0.w=f2bf(v[3]);
    o1.x=f2bf(v[4]); o1.y=f2bf(v[5]); o1.z=f2bf(v[6]); o1.w=f2bf(v[7]);
    *(ushort4*)&As[am][ak]     = o0;
    *(ushort4*)&As[am][ak + 4] = o1;
    const unsigned short* bp = Bt + (size_t)brow * 192 + k0 + bk;
    *(uint4*)&Bs[brow][bk]     = *(const uint4*)bp;
    *(uint4*)&Bs[brow][bk + 8] = *(const uint4*)(bp + 8);
    __syncthreads();
    short8 af[2], bf[4];
    #pragma unroll
    for (int t = 0; t < 2; t++) af[t] = *(const short8*)&As[wm + t * 16 + l16][quad * 8];
    #pragma unroll
    for (int t = 0; t < 4; t++) bf[t] = *(const short8*)&Bs[wn + t * 16 + l16][quad * 8];
    #pragma unroll
    for (int tm = 0; tm < 2; tm++)
      #pragma unroll
      for (int tn = 0; tn < 4; tn++)
        acc[tm][tn] = __builtin_amdgcn_mfma_f32_16x16x32_bf16(af[tm], bf[tn], acc[tm][tn], 0, 0, 0);
    __syncthreads();
  }
  #pragma unroll
  for (int tm = 0; tm < 2; tm++){
    #pragma unroll
    for (int r = 0; r < 4; r++){
      int row = bm + wm + tm * 16 + quad * 4 + r;
      if (row >= NNODES) continue;
      #pragma unroll
      for (int tn = 0; tn < 4; tn++){
        int col = wn + tn * 16 + l16;
        float val = fmaxf(acc[tm][tn][r] + bias[col], 0.f);
        Xb[(size_t)row * 128 + col] = f2bf(val);
      }
    }
  }
}

// ---------------- generic MFMA GEMM: C[z] = A @ B[z]^T-layout, A bf16 [M][K], Bt bf16 [N][K] ----------------
// BM=64, BN=128; MODE 0: both outputs bf16; MODE 1: z0 bf16, z1 fp32
template<int K, int N, int MODE>
__global__ __launch_bounds__(256) void k_mfma(const unsigned short* __restrict__ A,
                                              const unsigned short* __restrict__ B0t,
                                              const unsigned short* __restrict__ B1t,
                                              void* __restrict__ C0, void* __restrict__ C1){
  const unsigned short* Bt = blockIdx.z ? B1t : B0t;
  __shared__ unsigned short As[64][40];
  __shared__ unsigned short Bs[128][40];
  int tid = threadIdx.x;
  int bm = blockIdx.y * 64;
  int bn = blockIdx.x * 128;
  int w = tid >> 6, lane = tid & 63;
  int wm = (w >> 1) * 32, wn = (w & 1) * 64;
  int quad = lane >> 4, l16 = lane & 15;
  float4v acc[2][4];
  #pragma unroll
  for (int i = 0; i < 2; i++)
    #pragma unroll
    for (int j = 0; j < 4; j++) acc[i][j] = (float4v){0.f,0.f,0.f,0.f};
  int am = tid >> 2, ak = (tid & 3) * 8;
  int gm = bm + am;
  bool mv = gm < NNODES;
  int brow = tid >> 1, bk = (tid & 1) * 16;

  for (int k0 = 0; k0 < K; k0 += 32){
    uint4 va = {0u,0u,0u,0u};
    if (mv) va = *(const uint4*)(A + (size_t)gm * K + k0 + ak);
    *(uint4*)&As[am][ak] = va;
    const unsigned short* bp = Bt + (size_t)(bn + brow) * K + k0 + bk;
    *(uint4*)&Bs[brow][bk]     = *(const uint4*)bp;
    *(uint4*)&Bs[brow][bk + 8] = *(const uint4*)(bp + 8);
    __syncthreads();
    short8 af[2], bf[4];
    #pragma unroll
    for (int t = 0; t < 2; t++) af[t] = *(const short8*)&As[wm + t * 16 + l16][quad * 8];
    #pragma unroll
    for (int t = 0; t < 4; t++) bf[t] = *(const short8*)&Bs[wn + t * 16 + l16][quad * 8];
    #pragma unroll
    for (int tm = 0; tm < 2; tm++)
      #pragma unroll
      for (int tn = 0; tn < 4; tn++)
        acc[tm][tn] = __builtin_amdgcn_mfma_f32_16x16x32_bf16(af[tm], bf[tn], acc[tm][tn], 0, 0, 0);
    __syncthreads();
  }
  #pragma unroll
  for (int tm = 0; tm < 2; tm++){
    #pragma unroll
    for (int r = 0; r < 4; r++){
      int row = bm + wm + tm * 16 + quad * 4 + r;
      if (row >= NNODES) continue;
      #pragma unroll
      for (int tn = 0; tn < 4; tn++){
        int col = bn + wn + tn * 16 + l16;
        float val = acc[tm][tn][r];
        if (MODE == 0 || blockIdx.z == 0){
          unsigned short* C = (unsigned short*)(blockIdx.z ? C1 : C0);
          C[(size_t)row * N + col] = f2bf(val);
        } else {
          ((float*)C1)[(size_t)row * N + col] = val;
        }
      }
    }
  }
}

// ---------------- layer-1 GATv2 attention+aggregate (4 heads x 128 ch), bf16 in/out ----------------
__global__ __launch_bounds__(256) void k_attn1(const unsigned short* __restrict__ xl,
                                               const unsigned short* __restrict__ xr,
                                               const float* __restrict__ att, const float* __restrict__ bias,
                                               const int* __restrict__ off, const int* __restrict__ csr,
                                               unsigned short* __restrict__ out){
  int n = blockIdx.x;
  int tid = threadIdx.x;
  int w = tid >> 6, lane = tid & 63;
  int h = lane >> 4;
  uint4 ur = *(const uint4*)(xr + (size_t)n * 512 + lane * 8);
  float r[8] = {bflo(ur.x), bfhi(ur.x), bflo(ur.y), bfhi(ur.y),
                bflo(ur.z), bfhi(ur.z), bflo(ur.w), bfhi(ur.w)};
  const float* ap = att + lane * 8;
  float4 A0 = *(const float4*)ap, A1 = *(const float4*)(ap + 4);
  float a[8] = {A0.x,A0.y,A0.z,A0.w,A1.x,A1.y,A1.z,A1.w};
  int beg = off[n], end = off[n + 1];

  float m = -INFINITY, s = 0.f;
  float acc[8] = {0,0,0,0,0,0,0,0};
  for (int j = beg + w; j < end; j += 4){
    int sn = csr[j];
    uint4 ux = *(const uint4*)(xl + (size_t)sn * 512 + lane * 8);
    float x[8] = {bflo(ux.x), bfhi(ux.x), bflo(ux.y), bfhi(ux.y),
                  bflo(ux.z), bfhi(ux.z), bflo(ux.w), bfhi(ux.w)};
    float p = 0.f;
    #pragma unroll
    for (int i = 0; i < 8; i++) p += a[i] * lrelu(x[i] + r[i]);
    p += __shfl_xor(p, 1);
    p += __shfl_xor(p, 2);
    p += __shfl_xor(p, 4);
    p += __shfl_xor(p, 8);
    if (__any(p > m)){
      float nm = fmaxf(m, p);
      float al = __expf(m - nm);
      float ex = __expf(p - nm);
      m = nm;
      s = s * al + ex;
      #pragma unroll
      for (int i = 0; i < 8; i++) acc[i] = acc[i] * al + ex * x[i];
    } else {
      float ex = __expf(p - m);
      s += ex;
      #pragma unroll
      for (int i = 0; i < 8; i++) acc[i] = fmaf(ex, x[i], acc[i]);
    }
  }
  __shared__ float msh[4][4];
  __shared__ float ssh[4][4];
  __shared__ float accsh[4][512];
  if ((lane & 15) == 0) msh[w][h] = m;
  __syncthreads();
  float mg = fmaxf(fmaxf(msh[0][h], msh[1][h]), fmaxf(msh[2][h], msh[3][h]));
  float f = __expf(m - mg);
  if ((lane & 15) == 0) ssh[w][h] = s * f;
  #pragma unroll
  for (int i = 0; i < 8; i++) accsh[w][lane * 8 + i] = acc[i] * f;
  __syncthreads();
  for (int c = tid; c < 512; c += 256){
    float v = accsh[0][c] + accsh[1][c] + accsh[2][c] + accsh[3][c];
    int hh = c >> 7;
    float sv = ssh[0][hh] + ssh[1][hh] + ssh[2][hh] + ssh[3][hh];
    float o = v / (sv + 1e-16f) + bias[c];
    out[(size_t)n * 512 + c] = f2bf(fmaxf(o, 0.f));   // relu after layer 1
  }
}

// ---------------- layer-2 GATv2 attention+aggregate (1 head x 128 ch), bf16 xl ----------------
__global__ __launch_bounds__(256) void k_attn2(const unsigned short* __restrict__ xl,
                                               const float* __restrict__ xr,
                                               const float* __restrict__ att, const float* __restrict__ bias,
                                               const int* __restrict__ off, const int* __restrict__ csr,
                                               float* __restrict__ out){
  int lane = threadIdx.x & 63;
  int n = blockIdx.x * 4 + (threadIdx.x >> 6);
  float2 rv = *(const float2*)(xr + (size_t)n * 128 + lane * 2);
  float2 av = *(const float2*)(att + lane * 2);
  int beg = off[n], end = off[n + 1];
  float m = -INFINITY, s = 0.f;
  float a0 = 0.f, a1 = 0.f;
  for (int j = beg; j < end; j++){
    int sn = csr[j];
    uint32 u = *(const uint32*)(xl + (size_t)sn * 128 + lane * 2);
    float x0 = bflo(u), x1 = bfhi(u);
    float p = av.x * lrelu(x0 + rv.x) + av.y * lrelu(x1 + rv.y);
    p += __shfl_xor(p, 1);
    p += __shfl_xor(p, 2);
    p += __shfl_xor(p, 4);
    p += __shfl_xor(p, 8);
    p += __shfl_xor(p, 16);
    p += __shfl_xor(p, 32);
    if (p > m){
      float al = __expf(m - p);
      m = p;
      s = s * al + 1.f;
      a0 = a0 * al + x0;
      a1 = a1 * al + x1;
    } else {
      float ex = __expf(p - m);
      s += ex;
      a0 = fmaf(ex, x0, a0);
      a1 = fmaf(ex, x1, a1);
    }
  }
  float inv = 1.f / (s + 1e-16f);
  int c = lane * 2;
  out[(size_t)n * 128 + c]     = a0 * inv + bias[c];
  out[(size_t)n * 128 + c + 1] = a1 * inv + bias[c + 1];
}

// ---------------- output GEMM [N,128]@[128,10] + b, wave per node ----------------
__global__ __launch_bounds__(256) void k_out(const float* __restrict__ x2, const float* __restrict__ W,
                                             const float* __restrict__ b, float* __restrict__ out){
  __shared__ float Wsh[1280];
  int tid = threadIdx.x;
  for (int i = tid; i < 1280; i += 256) Wsh[i] = W[i];
  __syncthreads();
  int lane = tid & 63;
  int n = blockIdx.x * 4 + (tid >> 6);
  float v0 = x2[(size_t)n * 128 + lane];
  float v1 = x2[(size_t)n * 128 + 64 + lane];
  #pragma unroll
  for (int o = 0; o < 10; o++){
    float p = v0 * Wsh[lane * 10 + o] + v1 * Wsh[(64 + lane) * 10 + o];
    p += __shfl_xor(p, 1);
    p += __shfl_xor(p, 2);
    p += __shfl_xor(p, 4);
    p += __shfl_xor(p, 8);
    p += __shfl_xor(p, 16);
    p += __shfl_xor(p, 32);
    if (lane == 0) out[(size_t)n * 10 + o] = p + b[o];
  }
}

extern "C" void kernel_launch(void* const* d_in, const int* in_sizes, int n_in,
                              void* d_out, int out_size, void* d_ws, size_t ws_size,
                              hipStream_t stream){
  const float* xp    = (const float*)d_in[0];
  const int*   ei    = (const int*)  d_in[1];
  const float* emb   = (const float*)d_in[2];
  const float* projW = (const float*)d_in[3];
  const float* projb = (const float*)d_in[4];
  const float* W1l   = (const float*)d_in[5];
  const float* W1r   = (const float*)d_in[6];
  const float* att1  = (const float*)d_in[7];
  const float* b1    = (const float*)d_in[8];
  const float* W2l   = (const float*)d_in[9];
  const float* W2r   = (const float*)d_in[10];
  const float* att2  = (const float*)d_in[11];
  const float* b2    = (const float*)d_in[12];
  const float* outW  = (const float*)d_in[13];
  const float* outb  = (const float*)d_in[14];
  float* out = (float*)d_out;

  int E = in_sizes[1] / 2;
  const int* esrc = ei;
  const int* edst = ei + E;

  char* w = (char*)d_ws;
  int* deg  = (int*)w; w += (size_t)NNODES * 4;
  int* off  = (int*)w; w += (size_t)(NNODES + 4) * 4;
  int* cur  = (int*)w; w += (size_t)NNODES * 4;
  int* csr  = (int*)w; w += (size_t)(NNODES + E) * 4;
  unsigned short* Xb   = (unsigned short*)w; w += (size_t)NNODES * 128 * 2;
  unsigned short* Wt1l = (unsigned short*)w; w += (size_t)512 * 128 * 2;
  unsigned short* Wt1r = (unsigned short*)w; w += (size_t)512 * 128 * 2;
  unsigned short* Wt2l = (unsigned short*)w; w += (size_t)128 * 512 * 2;
  unsigned short* Wt2r = (unsigned short*)w; w += (size_t)128 * 512 * 2;
  unsigned short* Wtp  = (unsigned short*)w; w += (size_t)128 * 192 * 2;
  unsigned short* xl1b = (unsigned short*)w; w += (size_t)NNODES * 512 * 2;
  unsigned short* xr1b = (unsigned short*)w; w += (size_t)NNODES * 512 * 2;
  unsigned short* X1b  = (unsigned short*)w; w += (size_t)NNODES * 512 * 2;
  unsigned short* xl2b = (unsigned short*)w; w += (size_t)NNODES * 128 * 2;
  float* xr2 = (float*)w; w += (size_t)NNODES * 128 * 4;
  float* x2  = (float*)w; w += (size_t)NNODES * 128 * 4;

  k_init_deg<<<(NNODES + 255) / 256, 256, 0, stream>>>(deg);
  k_count<<<(E + 255) / 256, 256, 0, stream>>>(edst, E, deg);
  k_scan<<<1, 256, 0, stream>>>(deg, off, cur);
  k_fill<<<(NNODES + E + 255) / 256, 256, 0, stream>>>(esrc, edst, E, cur, csr);

  k_cvt<<<1120, 256, 0, stream>>>(W1l, W1r, W2l, W2r, projW, Wt1l, Wt1r, Wt2l, Wt2r, Wtp);
  k_proj_mfma<<<dim3((NNODES + 63) / 64), 256, 0, stream>>>(xp, emb, Wtp, projb, Xb);
  k_mfma<128, 512, 0><<<dim3(4, (NNODES + 63) / 64, 2), 256, 0, stream>>>(Xb, Wt1l, Wt1r, xl1b, xr1b);
  k_attn1<<<NNODES, 256, 0, stream>>>(xl1b, xr1b, att1, b1, off, csr, X1b);
  k_mfma<512, 128, 1><<<dim3(1, (NNODES + 63) / 64, 2), 256, 0, stream>>>(X1b, Wt2l, Wt2r, xl2b, xr2);
  k_attn2<<<NNODES / 4, 256, 0, stream>>>(xl2b, xr2, att2, b2, off, csr, x2);
  k_out<<<NNODES / 4, 256, 0, stream>>>(x2, outW, outb, out);
}

// Round 5
// 346.113 us; speedup vs baseline: 1.6307x; 1.0758x over previous
//
#include <hip/hip_runtime.h>
#include <math.h>

#define NNODES 20000
#define XP_COLS 65

typedef unsigned int uint32;
typedef __attribute__((ext_vector_type(8))) short short8;
typedef __attribute__((ext_vector_type(4))) float float4v;

__device__ __forceinline__ float bflo(uint32 u){ return __uint_as_float(u << 16); }
__device__ __forceinline__ float bfhi(uint32 u){ return __uint_as_float(u & 0xffff0000u); }
__device__ __forceinline__ unsigned short f2bf(float f){
  uint32 u = __float_as_uint(f);
  uint32 r = (u + 0x7fffu + ((u >> 16) & 1u)) >> 16;
  return (unsigned short)r;
}

// ---------------- CSR build ----------------
__global__ void k_count(const int* __restrict__ dst, int E, int* __restrict__ deg){
  int e = blockIdx.x * 256 + threadIdx.x;
  if (e < E) atomicAdd(&deg[dst[e]], 1);
}

// chunked scan; deg[i]+1 accounts for the self loop (deg memset to 0 by hipMemsetAsync)
__global__ __launch_bounds__(256) void k_scan(const int* __restrict__ deg,
                                              int* __restrict__ off,
                                              int* __restrict__ cursor){
  const int CH = (NNODES + 255) / 256;      // 79
  int tid = threadIdx.x;
  int lane = tid & 63, w = tid >> 6;
  int beg = tid * CH;
  int lim = beg + CH; if (lim > NNODES) lim = NNODES;
  int sum = 0;
  for (int i = beg; i < lim; i++) sum += deg[i] + 1;
  int inc = sum;
  #pragma unroll
  for (int d = 1; d < 64; d <<= 1){
    int t = __shfl_up(inc, d, 64);
    if (lane >= d) inc += t;
  }
  __shared__ int wtot[4];
  if (lane == 63) wtot[w] = inc;
  __syncthreads();
  int wbase = 0;
  for (int i = 0; i < w; i++) wbase += wtot[i];
  int run = wbase + inc - sum;
  for (int i = beg; i < lim; i++){
    off[i] = run; cursor[i] = run;
    run += deg[i] + 1;
  }
  if (tid == 255) off[NNODES] = run;
}

__global__ void k_fill(const int* __restrict__ src, const int* __restrict__ dst, int E,
                       int* __restrict__ cursor, int* __restrict__ csr){
  int t = blockIdx.x * 256 + threadIdx.x;
  if (t < NNODES){
    int p = atomicAdd(&cursor[t], 1);
    csr[p] = t;
  } else if (t < NNODES + E){
    int e = t - NNODES;
    int p = atomicAdd(&cursor[dst[e]], 1);
    csr[p] = src[e];
  }
}

// ---------------- transpose+cast all weights to bf16 n-major [N][K] ----------------
__global__ void k_cvt(const float* __restrict__ W1l, const float* __restrict__ W1r,
                      const float* __restrict__ W2l, const float* __restrict__ W2r,
                      const float* __restrict__ projW,
                      unsigned short* __restrict__ T1l, unsigned short* __restrict__ T1r,
                      unsigned short* __restrict__ T2l, unsigned short* __restrict__ T2r,
                      unsigned short* __restrict__ Tp){
  int idx = blockIdx.x * 256 + threadIdx.x;
  if (idx < 65536){
    int k = idx >> 9, n = idx & 511;
    T1l[n * 128 + k] = f2bf(W1l[idx]);
  } else if (idx < 131072){
    int i = idx - 65536; int k = i >> 9, n = i & 511;
    T1r[n * 128 + k] = f2bf(W1r[i]);
  } else if (idx < 196608){
    int i = idx - 131072; int k = i >> 7, n = i & 127;
    T2l[n * 512 + k] = f2bf(W2l[i]);
  } else if (idx < 262144){
    int i = idx - 196608; int k = i >> 7, n = i & 127;
    T2r[n * 512 + k] = f2bf(W2r[i]);
  } else if (idx < 286720){
    int i = idx - 262144; int k = i >> 7, n = i & 127;
    Tp[n * 192 + k] = f2bf(projW[i]);
  }
}

// ---------------- proj via MFMA with fused gather ----------------
__global__ __launch_bounds__(256) void k_proj_mfma(const float* __restrict__ xp,
                                                   const float* __restrict__ emb,
                                                   const unsigned short* __restrict__ Bt,
                                                   const float* __restrict__ bias,
                                                   unsigned short* __restrict__ Xb){
  __shared__ unsigned short As[64][40];
  __shared__ unsigned short Bs[128][40];
  __shared__ int ids[64];
  int tid = threadIdx.x;
  int bm = blockIdx.x * 64;
  int w = tid >> 6, lane = tid & 63;
  int wm = (w >> 1) * 32, wn = (w & 1) * 64;
  int quad = lane >> 4, l16 = lane & 15;
  if (tid < 64){
    int g = bm + tid;
    ids[tid] = (g < NNODES) ? (int)xp[(size_t)g * XP_COLS] : 0;
  }
  float4v acc[2][4];
  #pragma unroll
  for (int i = 0; i < 2; i++)
    #pragma unroll
    for (int j = 0; j < 4; j++) acc[i][j] = (float4v){0.f,0.f,0.f,0.f};
  int am = tid >> 2, ak = (tid & 3) * 8;
  int gm = bm + am;
  bool mv = gm < NNODES;
  int brow = tid >> 1, bk = (tid & 1) * 16;
  __syncthreads();

  for (int k0 = 0; k0 < 192; k0 += 32){
    float v[8];
    if (k0 < 128){
      const float* ep = emb + (size_t)ids[am] * 128 + k0 + ak;
      float4 e0 = *(const float4*)ep;
      float4 e1 = *(const float4*)(ep + 4);
      v[0]=e0.x; v[1]=e0.y; v[2]=e0.z; v[3]=e0.w;
      v[4]=e1.x; v[5]=e1.y; v[6]=e1.z; v[7]=e1.w;
    } else {
      const float* fp = xp + (size_t)gm * XP_COLS + 1 + (k0 - 128) + ak;
      #pragma unroll
      for (int i = 0; i < 8; i++) v[i] = mv ? fp[i] : 0.f;
    }
    ushort4 o0, o1;
    o0.x=f2bf(v[0]); o0.y=f2bf(v[1]); o0.z=f2bf(v[2]); o0.w=f2bf(v[3]);
    o1.x=f2bf(v[4]); o1.y=f2bf(v[5]); o1.z=f2bf(v[6]); o1.w=f2bf(v[7]);
    *(ushort4*)&As[am][ak]     = o0;
    *(ushort4*)&As[am][ak + 4] = o1;
    const unsigned short* bp = Bt + (size_t)brow * 192 + k0 + bk;
    *(uint4*)&Bs[brow][bk]     = *(const uint4*)bp;
    *(uint4*)&Bs[brow][bk + 8] = *(const uint4*)(bp + 8);
    __syncthreads();
    short8 af[2], bf[4];
    #pragma unroll
    for (int t = 0; t < 2; t++) af[t] = *(const short8*)&As[wm + t * 16 + l16][quad * 8];
    #pragma unroll
    for (int t = 0; t < 4; t++) bf[t] = *(const short8*)&Bs[wn + t * 16 + l16][quad * 8];
    #pragma unroll
    for (int tm = 0; tm < 2; tm++)
      #pragma unroll
      for (int tn = 0; tn < 4; tn++)
        acc[tm][tn] = __builtin_amdgcn_mfma_f32_16x16x32_bf16(af[tm], bf[tn], acc[tm][tn], 0, 0, 0);
    __syncthreads();
  }
  #pragma unroll
  for (int tm = 0; tm < 2; tm++){
    #pragma unroll
    for (int r = 0; r < 4; r++){
      int row = bm + wm + tm * 16 + quad * 4 + r;
      if (row >= NNODES) continue;
      #pragma unroll
      for (int tn = 0; tn < 4; tn++){
        int col = wn + tn * 16 + l16;
        float val = fmaxf(acc[tm][tn][r] + bias[col], 0.f);
        Xb[(size_t)row * 128 + col] = f2bf(val);
      }
    }
  }
}

// ---------------- MFMA GEMM with fused per-row attention dot ----------------
// C[z] = A @ B[z]t; also D[z][row] = sum_col C[row,col]*att[head,col]
// BM=64, BN=128 (=head width); MODE 0: both C bf16; MODE 1: z0 bf16, z1 fp32
template<int K, int N, int MODE, int NH>
__global__ __launch_bounds__(256) void k_mfma(const unsigned short* __restrict__ A,
                                              const unsigned short* __restrict__ B0t,
                                              const unsigned short* __restrict__ B1t,
                                              void* __restrict__ C0, void* __restrict__ C1,
                                              const float* __restrict__ att,
                                              float* __restrict__ dl, float* __restrict__ dr){
  const unsigned short* Bt = blockIdx.z ? B1t : B0t;
  __shared__ unsigned short As[64][40];
  __shared__ unsigned short Bs[128][40];
  __shared__ float red[4][32];
  int tid = threadIdx.x;
  int bm = blockIdx.y * 64;
  int bn = blockIdx.x * 128;
  int head = (NH == 1) ? 0 : blockIdx.x;
  int w = tid >> 6, lane = tid & 63;
  int wm = (w >> 1) * 32, wn = (w & 1) * 64;
  int quad = lane >> 4, l16 = lane & 15;
  float av[4];
  #pragma unroll
  for (int tn = 0; tn < 4; tn++) av[tn] = att[head * 128 + wn + tn * 16 + l16];
  float4v acc[2][4];
  #pragma unroll
  for (int i = 0; i < 2; i++)
    #pragma unroll
    for (int j = 0; j < 4; j++) acc[i][j] = (float4v){0.f,0.f,0.f,0.f};
  int am = tid >> 2, ak = (tid & 3) * 8;
  int gm = bm + am;
  bool mv = gm < NNODES;
  int brow = tid >> 1, bk = (tid & 1) * 16;

  for (int k0 = 0; k0 < K; k0 += 32){
    uint4 va = {0u,0u,0u,0u};
    if (mv) va = *(const uint4*)(A + (size_t)gm * K + k0 + ak);
    *(uint4*)&As[am][ak] = va;
    const unsigned short* bp = Bt + (size_t)(bn + brow) * K + k0 + bk;
    *(uint4*)&Bs[brow][bk]     = *(const uint4*)bp;
    *(uint4*)&Bs[brow][bk + 8] = *(const uint4*)(bp + 8);
    __syncthreads();
    short8 af[2], bf[4];
    #pragma unroll
    for (int t = 0; t < 2; t++) af[t] = *(const short8*)&As[wm + t * 16 + l16][quad * 8];
    #pragma unroll
    for (int t = 0; t < 4; t++) bf[t] = *(const short8*)&Bs[wn + t * 16 + l16][quad * 8];
    #pragma unroll
    for (int tm = 0; tm < 2; tm++)
      #pragma unroll
      for (int tn = 0; tn < 4; tn++)
        acc[tm][tn] = __builtin_amdgcn_mfma_f32_16x16x32_bf16(af[tm], bf[tn], acc[tm][tn], 0, 0, 0);
    __syncthreads();
  }
  // C write + per-row dot partials
  #pragma unroll
  for (int tm = 0; tm < 2; tm++){
    #pragma unroll
    for (int r = 0; r < 4; r++){
      int row = bm + wm + tm * 16 + quad * 4 + r;
      if (row < NNODES){
        #pragma unroll
        for (int tn = 0; tn < 4; tn++){
          int col = bn + wn + tn * 16 + l16;
          float val = acc[tm][tn][r];
          if (MODE == 0 || blockIdx.z == 0){
            unsigned short* C = (unsigned short*)(blockIdx.z ? C1 : C0);
            C[(size_t)row * N + col] = f2bf(val);
          } else {
            ((float*)C1)[(size_t)row * N + col] = val;
          }
        }
      }
      float pd = acc[tm][0][r] * av[0];
      pd = fmaf(acc[tm][1][r], av[1], pd);
      pd = fmaf(acc[tm][2][r], av[2], pd);
      pd = fmaf(acc[tm][3][r], av[3], pd);
      pd += __shfl_xor(pd, 1);
      pd += __shfl_xor(pd, 2);
      pd += __shfl_xor(pd, 4);
      pd += __shfl_xor(pd, 8);
      if (l16 == 0) red[w][tm * 16 + quad * 4 + r] = pd;
    }
  }
  __syncthreads();
  if (tid < 64){
    float v = (tid < 32) ? red[0][tid] + red[1][tid] : red[2][tid & 31] + red[3][tid & 31];
    int row = bm + tid;
    if (row < NNODES){
      float* D = blockIdx.z ? dr : dl;
      D[row * NH + head] = v;
    }
  }
}

// ---------------- layer-1 GATv2 attention+aggregate (4 heads x 128 ch) ----------------
// e = 0.6*(dl[src]+dr[dst]) + 0.4*sum_c a_c*|x_c + r_c|
__global__ __launch_bounds__(256) void k_attn1(const unsigned short* __restrict__ xl,
                                               const unsigned short* __restrict__ xr,
                                               const float* __restrict__ dl, const float* __restrict__ dr,
                                               const float* __restrict__ att, const float* __restrict__ bias,
                                               const int* __restrict__ off, const int* __restrict__ csr,
                                               unsigned short* __restrict__ out){
  int n = blockIdx.x;
  int tid = threadIdx.x;
  int w = tid >> 6, lane = tid & 63;
  int h = lane >> 4;
  uint4 ur = *(const uint4*)(xr + (size_t)n * 512 + lane * 8);
  float r[8] = {bflo(ur.x), bfhi(ur.x), bflo(ur.y), bfhi(ur.y),
                bflo(ur.z), bfhi(ur.z), bflo(ur.w), bfhi(ur.w)};
  const float* ap = att + lane * 8;
  float4 A0 = *(const float4*)ap, A1 = *(const float4*)(ap + 4);
  float a[8] = {A0.x,A0.y,A0.z,A0.w,A1.x,A1.y,A1.z,A1.w};
  float c0 = 0.6f * dr[n * 4 + h];
  int beg = off[n], end = off[n + 1];

  float m = -INFINITY, s = 0.f;
  float acc[8] = {0,0,0,0,0,0,0,0};
  int j = beg + w;
  for (; j + 4 < end; j += 8){
    int sn1 = csr[j], sn2 = csr[j + 4];
    float dls1 = dl[sn1 * 4 + h], dls2 = dl[sn2 * 4 + h];
    uint4 u1 = *(const uint4*)(xl + (size_t)sn1 * 512 + lane * 8);
    uint4 u2 = *(const uint4*)(xl + (size_t)sn2 * 512 + lane * 8);
    float x1[8] = {bflo(u1.x), bfhi(u1.x), bflo(u1.y), bfhi(u1.y),
                   bflo(u1.z), bfhi(u1.z), bflo(u1.w), bfhi(u1.w)};
    float x2[8] = {bflo(u2.x), bfhi(u2.x), bflo(u2.y), bfhi(u2.y),
                   bflo(u2.z), bfhi(u2.z), bflo(u2.w), bfhi(u2.w)};
    float p1 = 0.f, p2 = 0.f;
    #pragma unroll
    for (int i = 0; i < 8; i++){
      p1 = fmaf(a[i], fabsf(x1[i] + r[i]), p1);
      p2 = fmaf(a[i], fabsf(x2[i] + r[i]), p2);
    }
    p1 += __shfl_xor(p1, 1); p2 += __shfl_xor(p2, 1);
    p1 += __shfl_xor(p1, 2); p2 += __shfl_xor(p2, 2);
    p1 += __shfl_xor(p1, 4); p2 += __shfl_xor(p2, 4);
    p1 += __shfl_xor(p1, 8); p2 += __shfl_xor(p2, 8);
    float e1 = fmaf(0.6f, dls1, fmaf(0.4f, p1, c0));
    float e2 = fmaf(0.6f, dls2, fmaf(0.4f, p2, c0));
    float emax = fmaxf(e1, e2);
    if (__any(emax > m)){
      float nm = fmaxf(m, emax);
      float al  = __expf(m - nm);
      float ex1 = __expf(e1 - nm);
      float ex2 = __expf(e2 - nm);
      m = nm;
      s = fmaf(s, al, ex1 + ex2);
      #pragma unroll
      for (int i = 0; i < 8; i++)
        acc[i] = fmaf(acc[i], al, fmaf(ex1, x1[i], ex2 * x2[i]));
    } else {
      float ex1 = __expf(e1 - m);
      float ex2 = __expf(e2 - m);
      s += ex1 + ex2;
      #pragma unroll
      for (int i = 0; i < 8; i++)
        acc[i] = fmaf(ex1, x1[i], fmaf(ex2, x2[i], acc[i]));
    }
  }
  if (j < end){
    int sn = csr[j];
    float dls = dl[sn * 4 + h];
    uint4 ux = *(const uint4*)(xl + (size_t)sn * 512 + lane * 8);
    float x[8] = {bflo(ux.x), bfhi(ux.x), bflo(ux.y), bfhi(ux.y),
                  bflo(ux.z), bfhi(ux.z), bflo(ux.w), bfhi(ux.w)};
    float p = 0.f;
    #pragma unroll
    for (int i = 0; i < 8; i++) p = fmaf(a[i], fabsf(x[i] + r[i]), p);
    p += __shfl_xor(p, 1);
    p += __shfl_xor(p, 2);
    p += __shfl_xor(p, 4);
    p += __shfl_xor(p, 8);
    float e = fmaf(0.6f, dls, fmaf(0.4f, p, c0));
    if (__any(e > m)){
      float nm = fmaxf(m, e);
      float al = __expf(m - nm);
      float ex = __expf(e - nm);
      m = nm;
      s = fmaf(s, al, ex);
      #pragma unroll
      for (int i = 0; i < 8; i++) acc[i] = fmaf(acc[i], al, ex * x[i]);
    } else {
      float ex = __expf(e - m);
      s += ex;
      #pragma unroll
      for (int i = 0; i < 8; i++) acc[i] = fmaf(ex, x[i], acc[i]);
    }
  }
  __shared__ float msh[4][4];
  __shared__ float ssh[4][4];
  __shared__ float accsh[4][512];
  if ((lane & 15) == 0) msh[w][h] = m;
  __syncthreads();
  float mg = fmaxf(fmaxf(msh[0][h], msh[1][h]), fmaxf(msh[2][h], msh[3][h]));
  float f = __expf(m - mg);
  if ((lane & 15) == 0) ssh[w][h] = s * f;
  #pragma unroll
  for (int i = 0; i < 8; i++) accsh[w][lane * 8 + i] = acc[i] * f;
  __syncthreads();
  for (int c = tid; c < 512; c += 256){
    float v = accsh[0][c] + accsh[1][c] + accsh[2][c] + accsh[3][c];
    int hh = c >> 7;
    float sv = ssh[0][hh] + ssh[1][hh] + ssh[2][hh] + ssh[3][hh];
    float o = v / (sv + 1e-16f) + bias[c];
    out[(size_t)n * 512 + c] = f2bf(fmaxf(o, 0.f));
  }
}

// ---------------- layer-2 GATv2 attention+aggregate (1 head x 128 ch) ----------------
__global__ __launch_bounds__(256) void k_attn2(const unsigned short* __restrict__ xl,
                                               const float* __restrict__ xr,
                                               const float* __restrict__ dl, const float* __restrict__ dr,
                                               const float* __restrict__ att, const float* __restrict__ bias,
                                               const int* __restrict__ off, const int* __restrict__ csr,
                                               float* __restrict__ out){
  int lane = threadIdx.x & 63;
  int n = blockIdx.x * 4 + (threadIdx.x >> 6);
  float2 rv = *(const float2*)(xr + (size_t)n * 128 + lane * 2);
  float2 av = *(const float2*)(att + lane * 2);
  float c0 = 0.6f * dr[n];
  int beg = off[n], end = off[n + 1];
  float m = -INFINITY, s = 0.f;
  float a0 = 0.f, a1 = 0.f;
  int j = beg;
  for (; j + 1 < end; j += 2){
    int sn1 = csr[j], sn2 = csr[j + 1];
    float dls1 = dl[sn1], dls2 = dl[sn2];
    uint32 u1 = *(const uint32*)(xl + (size_t)sn1 * 128 + lane * 2);
    uint32 u2 = *(const uint32*)(xl + (size_t)sn2 * 128 + lane * 2);
    float x10 = bflo(u1), x11 = bfhi(u1);
    float x20 = bflo(u2), x21 = bfhi(u2);
    float p1 = fmaf(av.x, fabsf(x10 + rv.x), av.y * fabsf(x11 + rv.y));
    float p2 = fmaf(av.x, fabsf(x20 + rv.x), av.y * fabsf(x21 + rv.y));
    p1 += __shfl_xor(p1, 1);  p2 += __shfl_xor(p2, 1);
    p1 += __shfl_xor(p1, 2);  p2 += __shfl_xor(p2, 2);
    p1 += __shfl_xor(p1, 4);  p2 += __shfl_xor(p2, 4);
    p1 += __shfl_xor(p1, 8);  p2 += __shfl_xor(p2, 8);
    p1 += __shfl_xor(p1, 16); p2 += __shfl_xor(p2, 16);
    p1 += __shfl_xor(p1, 32); p2 += __shfl_xor(p2, 32);
    float e1 = fmaf(0.6f, dls1, fmaf(0.4f, p1, c0));
    float e2 = fmaf(0.6f, dls2, fmaf(0.4f, p2, c0));
    float emax = fmaxf(e1, e2);
    if (emax > m){
      float al  = __expf(m - emax);
      float ex1 = __expf(e1 - emax);
      float ex2 = __expf(e2 - emax);
      m = emax;
      s  = fmaf(s,  al, ex1 + ex2);
      a0 = fmaf(a0, al, fmaf(ex1, x10, ex2 * x20));
      a1 = fmaf(a1, al, fmaf(ex1, x11, ex2 * x21));
    } else {
      float ex1 = __expf(e1 - m);
      float ex2 = __expf(e2 - m);
      s += ex1 + ex2;
      a0 = fmaf(ex1, x10, fmaf(ex2, x20, a0));
      a1 = fmaf(ex1, x11, fmaf(ex2, x21, a1));
    }
  }
  if (j < end){
    int sn = csr[j];
    float dls = dl[sn];
    uint32 u = *(const uint32*)(xl + (size_t)sn * 128 + lane * 2);
    float x0 = bflo(u), x1 = bfhi(u);
    float p = fmaf(av.x, fabsf(x0 + rv.x), av.y * fabsf(x1 + rv.y));
    p += __shfl_xor(p, 1);
    p += __shfl_xor(p, 2);
    p += __shfl_xor(p, 4);
    p += __shfl_xor(p, 8);
    p += __shfl_xor(p, 16);
    p += __shfl_xor(p, 32);
    float e = fmaf(0.6f, dls, fmaf(0.4f, p, c0));
    if (e > m){
      float al = __expf(m - e);
      m = e;
      s  = fmaf(s,  al, 1.f);
      a0 = fmaf(a0, al, x0);
      a1 = fmaf(a1, al, x1);
    } else {
      float ex = __expf(e - m);
      s += ex;
      a0 = fmaf(ex, x0, a0);
      a1 = fmaf(ex, x1, a1);
    }
  }
  float inv = 1.f / (s + 1e-16f);
  int c = lane * 2;
  out[(size_t)n * 128 + c]     = a0 * inv + bias[c];
  out[(size_t)n * 128 + c + 1] = a1 * inv + bias[c + 1];
}

// ---------------- output GEMM [N,128]@[128,10] + b, wave per node ----------------
__global__ __launch_bounds__(256) void k_out(const float* __restrict__ x2, const float* __restrict__ W,
                                             const float* __restrict__ b, float* __restrict__ out){
  __shared__ float Wsh[1280];
  int tid = threadIdx.x;
  for (int i = tid; i < 1280; i += 256) Wsh[i] = W[i];
  __syncthreads();
  int lane = tid & 63;
  int n = blockIdx.x * 4 + (tid >> 6);
  float v0 = x2[(size_t)n * 128 + lane];
  float v1 = x2[(size_t)n * 128 + 64 + lane];
  #pragma unroll
  for (int o = 0; o < 10; o++){
    float p = v0 * Wsh[lane * 10 + o] + v1 * Wsh[(64 + lane) * 10 + o];
    p += __shfl_xor(p, 1);
    p += __shfl_xor(p, 2);
    p += __shfl_xor(p, 4);
    p += __shfl_xor(p, 8);
    p += __shfl_xor(p, 16);
    p += __shfl_xor(p, 32);
    if (lane == 0) out[(size_t)n * 10 + o] = p + b[o];
  }
}

extern "C" void kernel_launch(void* const* d_in, const int* in_sizes, int n_in,
                              void* d_out, int out_size, void* d_ws, size_t ws_size,
                              hipStream_t stream){
  const float* xp    = (const float*)d_in[0];
  const int*   ei    = (const int*)  d_in[1];
  const float* emb   = (const float*)d_in[2];
  const float* projW = (const float*)d_in[3];
  const float* projb = (const float*)d_in[4];
  const float* W1l   = (const float*)d_in[5];
  const float* W1r   = (const float*)d_in[6];
  const float* att1  = (const float*)d_in[7];
  const float* b1    = (const float*)d_in[8];
  const float* W2l   = (const float*)d_in[9];
  const float* W2r   = (const float*)d_in[10];
  const float* att2  = (const float*)d_in[11];
  const float* b2    = (const float*)d_in[12];
  const float* outW  = (const float*)d_in[13];
  const float* outb  = (const float*)d_in[14];
  float* out = (float*)d_out;

  int E = in_sizes[1] / 2;
  const int* esrc = ei;
  const int* edst = ei + E;

  char* w = (char*)d_ws;
  int* deg  = (int*)w; w += (size_t)NNODES * 4;
  int* off  = (int*)w; w += (size_t)(NNODES + 4) * 4;
  int* cur  = (int*)w; w += (size_t)NNODES * 4;
  int* csr  = (int*)w; w += (size_t)(NNODES + E) * 4;
  unsigned short* Xb   = (unsigned short*)w; w += (size_t)NNODES * 128 * 2;
  unsigned short* Wt1l = (unsigned short*)w; w += (size_t)512 * 128 * 2;
  unsigned short* Wt1r = (unsigned short*)w; w += (size_t)512 * 128 * 2;
  unsigned short* Wt2l = (unsigned short*)w; w += (size_t)128 * 512 * 2;
  unsigned short* Wt2r = (unsigned short*)w; w += (size_t)128 * 512 * 2;
  unsigned short* Wtp  = (unsigned short*)w; w += (size_t)128 * 192 * 2;
  unsigned short* xl1b = (unsigned short*)w; w += (size_t)NNODES * 512 * 2;
  unsigned short* xr1b = (unsigned short*)w; w += (size_t)NNODES * 512 * 2;
  unsigned short* X1b  = (unsigned short*)w; w += (size_t)NNODES * 512 * 2;
  unsigned short* xl2b = (unsigned short*)w; w += (size_t)NNODES * 128 * 2;
  float* xr2 = (float*)w; w += (size_t)NNODES * 128 * 4;
  float* x2  = (float*)w; w += (size_t)NNODES * 128 * 4;
  float* dl1 = (float*)w; w += (size_t)NNODES * 4 * 4;
  float* dr1 = (float*)w; w += (size_t)NNODES * 4 * 4;
  float* dl2 = (float*)w; w += (size_t)NNODES * 4;
  float* dr2 = (float*)w; w += (size_t)NNODES * 4;

  hipMemsetAsync(deg, 0, (size_t)NNODES * 4, stream);
  k_count<<<(E + 255) / 256, 256, 0, stream>>>(edst, E, deg);
  k_scan<<<1, 256, 0, stream>>>(deg, off, cur);
  k_fill<<<(NNODES + E + 255) / 256, 256, 0, stream>>>(esrc, edst, E, cur, csr);

  k_cvt<<<1120, 256, 0, stream>>>(W1l, W1r, W2l, W2r, projW, Wt1l, Wt1r, Wt2l, Wt2r, Wtp);
  k_proj_mfma<<<dim3((NNODES + 63) / 64), 256, 0, stream>>>(xp, emb, Wtp, projb, Xb);
  k_mfma<128, 512, 0, 4><<<dim3(4, (NNODES + 63) / 64, 2), 256, 0, stream>>>(
      Xb, Wt1l, Wt1r, xl1b, xr1b, att1, dl1, dr1);
  k_attn1<<<NNODES, 256, 0, stream>>>(xl1b, xr1b, dl1, dr1, att1, b1, off, csr, X1b);
  k_mfma<512, 128, 1, 1><<<dim3(1, (NNODES + 63) / 64, 2), 256, 0, stream>>>(
      X1b, Wt2l, Wt2r, xl2b, xr2, att2, dl2, dr2);
  k_attn2<<<NNODES / 4, 256, 0, stream>>>(xl2b, xr2, dl2, dr2, att2, b2, off, csr, x2);
  k_out<<<NNODES / 4, 256, 0, stream>>>(x2, outW, outb, out);
}

// Round 6
// 339.099 us; speedup vs baseline: 1.6644x; 1.0207x over previous
//
#include <hip/hip_runtime.h>
#include <math.h>

#define NNODES 20000
#define XP_COLS 65

typedef unsigned int uint32;
typedef __attribute__((ext_vector_type(8))) short short8;
typedef __attribute__((ext_vector_type(4))) float float4v;

__device__ __forceinline__ float bflo(uint32 u){ return __uint_as_float(u << 16); }
__device__ __forceinline__ float bfhi(uint32 u){ return __uint_as_float(u & 0xffff0000u); }
__device__ __forceinline__ unsigned short f2bf(float f){
  uint32 u = __float_as_uint(f);
  uint32 r = (u + 0x7fffu + ((u >> 16) & 1u)) >> 16;
  return (unsigned short)r;
}

// ---------------- CSR build ----------------
__global__ void k_count(const int* __restrict__ dst, int E, int* __restrict__ deg){
  int e = blockIdx.x * 256 + threadIdx.x;
  if (e < E) atomicAdd(&deg[dst[e]], 1);
}

// chunked scan; deg[i]+1 accounts for the self loop (deg memset to 0)
__global__ __launch_bounds__(256) void k_scan(const int* __restrict__ deg,
                                              int* __restrict__ off,
                                              int* __restrict__ cursor){
  const int CH = (NNODES + 255) / 256;      // 79
  int tid = threadIdx.x;
  int lane = tid & 63, w = tid >> 6;
  int beg = tid * CH;
  int lim = beg + CH; if (lim > NNODES) lim = NNODES;
  int sum = 0;
  for (int i = beg; i < lim; i++) sum += deg[i] + 1;
  int inc = sum;
  #pragma unroll
  for (int d = 1; d < 64; d <<= 1){
    int t = __shfl_up(inc, d, 64);
    if (lane >= d) inc += t;
  }
  __shared__ int wtot[4];
  if (lane == 63) wtot[w] = inc;
  __syncthreads();
  int wbase = 0;
  for (int i = 0; i < w; i++) wbase += wtot[i];
  int run = wbase + inc - sum;
  for (int i = beg; i < lim; i++){
    off[i] = run; cursor[i] = run;
    run += deg[i] + 1;
  }
  if (tid == 255) off[NNODES] = run;
}

__global__ void k_fill(const int* __restrict__ src, const int* __restrict__ dst, int E,
                       int* __restrict__ cursor, int* __restrict__ csr){
  int t = blockIdx.x * 256 + threadIdx.x;
  if (t < NNODES){
    int p = atomicAdd(&cursor[t], 1);
    csr[p] = t;
  } else if (t < NNODES + E){
    int e = t - NNODES;
    int p = atomicAdd(&cursor[dst[e]], 1);
    csr[p] = src[e];
  }
}

// ---------------- transpose+cast all weights to bf16 n-major [N][K] ----------------
__global__ void k_cvt(const float* __restrict__ W1l, const float* __restrict__ W1r,
                      const float* __restrict__ W2l, const float* __restrict__ W2r,
                      const float* __restrict__ projW,
                      unsigned short* __restrict__ T1l, unsigned short* __restrict__ T1r,
                      unsigned short* __restrict__ T2l, unsigned short* __restrict__ T2r,
                      unsigned short* __restrict__ Tp){
  int idx = blockIdx.x * 256 + threadIdx.x;
  if (idx < 65536){
    int k = idx >> 9, n = idx & 511;
    T1l[n * 128 + k] = f2bf(W1l[idx]);
  } else if (idx < 131072){
    int i = idx - 65536; int k = i >> 9, n = i & 511;
    T1r[n * 128 + k] = f2bf(W1r[i]);
  } else if (idx < 196608){
    int i = idx - 131072; int k = i >> 7, n = i & 127;
    T2l[n * 512 + k] = f2bf(W2l[i]);
  } else if (idx < 262144){
    int i = idx - 196608; int k = i >> 7, n = i & 127;
    T2r[n * 512 + k] = f2bf(W2r[i]);
  } else if (idx < 286720){
    int i = idx - 262144; int k = i >> 7, n = i & 127;
    Tp[n * 192 + k] = f2bf(projW[i]);
  }
}

// ---------------- proj via MFMA with fused gather ----------------
__global__ __launch_bounds__(256) void k_proj_mfma(const float* __restrict__ xp,
                                                   const float* __restrict__ emb,
                                                   const unsigned short* __restrict__ Bt,
                                                   const float* __restrict__ bias,
                                                   unsigned short* __restrict__ Xb){
  __shared__ unsigned short As[64][40];
  __shared__ unsigned short Bs[128][40];
  __shared__ int ids[64];
  int tid = threadIdx.x;
  int bm = blockIdx.x * 64;
  int w = tid >> 6, lane = tid & 63;
  int wm = (w >> 1) * 32, wn = (w & 1) * 64;
  int quad = lane >> 4, l16 = lane & 15;
  if (tid < 64){
    int g = bm + tid;
    ids[tid] = (g < NNODES) ? (int)xp[(size_t)g * XP_COLS] : 0;
  }
  float4v acc[2][4];
  #pragma unroll
  for (int i = 0; i < 2; i++)
    #pragma unroll
    for (int j = 0; j < 4; j++) acc[i][j] = (float4v){0.f,0.f,0.f,0.f};
  int am = tid >> 2, ak = (tid & 3) * 8;
  int gm = bm + am;
  bool mv = gm < NNODES;
  int brow = tid >> 1, bk = (tid & 1) * 16;
  __syncthreads();

  for (int k0 = 0; k0 < 192; k0 += 32){
    float v[8];
    if (k0 < 128){
      const float* ep = emb + (size_t)ids[am] * 128 + k0 + ak;
      float4 e0 = *(const float4*)ep;
      float4 e1 = *(const float4*)(ep + 4);
      v[0]=e0.x; v[1]=e0.y; v[2]=e0.z; v[3]=e0.w;
      v[4]=e1.x; v[5]=e1.y; v[6]=e1.z; v[7]=e1.w;
    } else {
      const float* fp = xp + (size_t)gm * XP_COLS + 1 + (k0 - 128) + ak;
      #pragma unroll
      for (int i = 0; i < 8; i++) v[i] = mv ? fp[i] : 0.f;
    }
    ushort4 o0, o1;
    o0.x=f2bf(v[0]); o0.y=f2bf(v[1]); o0.z=f2bf(v[2]); o0.w=f2bf(v[3]);
    o1.x=f2bf(v[4]); o1.y=f2bf(v[5]); o1.z=f2bf(v[6]); o1.w=f2bf(v[7]);
    *(ushort4*)&As[am][ak]     = o0;
    *(ushort4*)&As[am][ak + 4] = o1;
    const unsigned short* bp = Bt + (size_t)brow * 192 + k0 + bk;
    *(uint4*)&Bs[brow][bk]     = *(const uint4*)bp;
    *(uint4*)&Bs[brow][bk + 8] = *(const uint4*)(bp + 8);
    __syncthreads();
    short8 af[2], bf[4];
    #pragma unroll
    for (int t = 0; t < 2; t++) af[t] = *(const short8*)&As[wm + t * 16 + l16][quad * 8];
    #pragma unroll
    for (int t = 0; t < 4; t++) bf[t] = *(const short8*)&Bs[wn + t * 16 + l16][quad * 8];
    #pragma unroll
    for (int tm = 0; tm < 2; tm++)
      #pragma unroll
      for (int tn = 0; tn < 4; tn++)
        acc[tm][tn] = __builtin_amdgcn_mfma_f32_16x16x32_bf16(af[tm], bf[tn], acc[tm][tn], 0, 0, 0);
    __syncthreads();
  }
  #pragma unroll
  for (int tm = 0; tm < 2; tm++){
    #pragma unroll
    for (int r = 0; r < 4; r++){
      int row = bm + wm + tm * 16 + quad * 4 + r;
      if (row >= NNODES) continue;
      #pragma unroll
      for (int tn = 0; tn < 4; tn++){
        int col = wn + tn * 16 + l16;
        float val = fmaxf(acc[tm][tn][r] + bias[col], 0.f);
        Xb[(size_t)row * 128 + col] = f2bf(val);
      }
    }
  }
}

// ---------------- MFMA GEMM with fused per-row attention dot ----------------
template<int K, int N, int MODE, int NH>
__global__ __launch_bounds__(256) void k_mfma(const unsigned short* __restrict__ A,
                                              const unsigned short* __restrict__ B0t,
                                              const unsigned short* __restrict__ B1t,
                                              void* __restrict__ C0, void* __restrict__ C1,
                                              const float* __restrict__ att,
                                              float* __restrict__ dl, float* __restrict__ dr){
  const unsigned short* Bt = blockIdx.z ? B1t : B0t;
  __shared__ unsigned short As[64][40];
  __shared__ unsigned short Bs[128][40];
  __shared__ float red[4][32];
  int tid = threadIdx.x;
  int bm = blockIdx.y * 64;
  int bn = blockIdx.x * 128;
  int head = (NH == 1) ? 0 : blockIdx.x;
  int w = tid >> 6, lane = tid & 63;
  int wm = (w >> 1) * 32, wn = (w & 1) * 64;
  int quad = lane >> 4, l16 = lane & 15;
  float av[4];
  #pragma unroll
  for (int tn = 0; tn < 4; tn++) av[tn] = att[head * 128 + wn + tn * 16 + l16];
  float4v acc[2][4];
  #pragma unroll
  for (int i = 0; i < 2; i++)
    #pragma unroll
    for (int j = 0; j < 4; j++) acc[i][j] = (float4v){0.f,0.f,0.f,0.f};
  int am = tid >> 2, ak = (tid & 3) * 8;
  int gm = bm + am;
  bool mv = gm < NNODES;
  int brow = tid >> 1, bk = (tid & 1) * 16;

  for (int k0 = 0; k0 < K; k0 += 32){
    uint4 va = {0u,0u,0u,0u};
    if (mv) va = *(const uint4*)(A + (size_t)gm * K + k0 + ak);
    *(uint4*)&As[am][ak] = va;
    const unsigned short* bp = Bt + (size_t)(bn + brow) * K + k0 + bk;
    *(uint4*)&Bs[brow][bk]     = *(const uint4*)bp;
    *(uint4*)&Bs[brow][bk + 8] = *(const uint4*)(bp + 8);
    __syncthreads();
    short8 af[2], bf[4];
    #pragma unroll
    for (int t = 0; t < 2; t++) af[t] = *(const short8*)&As[wm + t * 16 + l16][quad * 8];
    #pragma unroll
    for (int t = 0; t < 4; t++) bf[t] = *(const short8*)&Bs[wn + t * 16 + l16][quad * 8];
    #pragma unroll
    for (int tm = 0; tm < 2; tm++)
      #pragma unroll
      for (int tn = 0; tn < 4; tn++)
        acc[tm][tn] = __builtin_amdgcn_mfma_f32_16x16x32_bf16(af[tm], bf[tn], acc[tm][tn], 0, 0, 0);
    __syncthreads();
  }
  #pragma unroll
  for (int tm = 0; tm < 2; tm++){
    #pragma unroll
    for (int r = 0; r < 4; r++){
      int row = bm + wm + tm * 16 + quad * 4 + r;
      if (row < NNODES){
        #pragma unroll
        for (int tn = 0; tn < 4; tn++){
          int col = bn + wn + tn * 16 + l16;
          float val = acc[tm][tn][r];
          if (MODE == 0 || blockIdx.z == 0){
            unsigned short* C = (unsigned short*)(blockIdx.z ? C1 : C0);
            C[(size_t)row * N + col] = f2bf(val);
          } else {
            ((float*)C1)[(size_t)row * N + col] = val;
          }
        }
      }
      float pd = acc[tm][0][r] * av[0];
      pd = fmaf(acc[tm][1][r], av[1], pd);
      pd = fmaf(acc[tm][2][r], av[2], pd);
      pd = fmaf(acc[tm][3][r], av[3], pd);
      pd += __shfl_xor(pd, 1);
      pd += __shfl_xor(pd, 2);
      pd += __shfl_xor(pd, 4);
      pd += __shfl_xor(pd, 8);
      if (l16 == 0) red[w][tm * 16 + quad * 4 + r] = pd;
    }
  }
  __syncthreads();
  if (tid < 64){
    float v = (tid < 32) ? red[0][tid] + red[1][tid] : red[2][tid & 31] + red[3][tid & 31];
    int row = bm + tid;
    if (row < NNODES){
      float* D = blockIdx.z ? dr : dl;
      D[row * NH + head] = v;
    }
  }
}

// ---------------- layer-1 GATv2 attention+aggregate: ONE WAVE PER NODE ----------------
// e = 0.6*(dl[src]+dr[dst]) + 0.4*sum_c a_c*|x_c + r_c|
// lane -> head (lane>>4), 8 channels (lane*8). e uniform within 16-lane group
// after shfl reduce, so m/s are group-uniform: register-only epilogue, no LDS.
__global__ __launch_bounds__(256) void k_attn1(const unsigned short* __restrict__ xl,
                                               const unsigned short* __restrict__ xr,
                                               const float* __restrict__ dl, const float* __restrict__ dr,
                                               const float* __restrict__ att, const float* __restrict__ bias,
                                               const int* __restrict__ off, const int* __restrict__ csr,
                                               unsigned short* __restrict__ out){
  int lane = threadIdx.x & 63;
  int n = blockIdx.x * 4 + (threadIdx.x >> 6);
  int h = lane >> 4;
  uint4 ur = *(const uint4*)(xr + (size_t)n * 512 + lane * 8);
  float r[8] = {bflo(ur.x), bfhi(ur.x), bflo(ur.y), bfhi(ur.y),
                bflo(ur.z), bfhi(ur.z), bflo(ur.w), bfhi(ur.w)};
  const float* ap = att + lane * 8;
  float4 A0 = *(const float4*)ap, A1 = *(const float4*)(ap + 4);
  float a[8] = {A0.x,A0.y,A0.z,A0.w,A1.x,A1.y,A1.z,A1.w};
  float c0 = 0.6f * dr[n * 4 + h];
  int beg = off[n], end = off[n + 1];

  float m = -INFINITY, s = 0.f;
  float acc[8] = {0,0,0,0,0,0,0,0};
  int j = beg;
  for (; j + 1 < end; j += 2){
    int sn1 = csr[j], sn2 = csr[j + 1];
    float dls1 = dl[sn1 * 4 + h], dls2 = dl[sn2 * 4 + h];
    uint4 u1 = *(const uint4*)(xl + (size_t)sn1 * 512 + lane * 8);
    uint4 u2 = *(const uint4*)(xl + (size_t)sn2 * 512 + lane * 8);
    float x1[8] = {bflo(u1.x), bfhi(u1.x), bflo(u1.y), bfhi(u1.y),
                   bflo(u1.z), bfhi(u1.z), bflo(u1.w), bfhi(u1.w)};
    float x2[8] = {bflo(u2.x), bfhi(u2.x), bflo(u2.y), bfhi(u2.y),
                   bflo(u2.z), bfhi(u2.z), bflo(u2.w), bfhi(u2.w)};
    float p1a = 0.f, p1b = 0.f, p2a = 0.f, p2b = 0.f;
    #pragma unroll
    for (int i = 0; i < 4; i++){
      p1a = fmaf(a[i],     fabsf(x1[i]     + r[i]),     p1a);
      p1b = fmaf(a[i + 4], fabsf(x1[i + 4] + r[i + 4]), p1b);
      p2a = fmaf(a[i],     fabsf(x2[i]     + r[i]),     p2a);
      p2b = fmaf(a[i + 4], fabsf(x2[i + 4] + r[i + 4]), p2b);
    }
    float p1 = p1a + p1b, p2 = p2a + p2b;
    p1 += __shfl_xor(p1, 1); p2 += __shfl_xor(p2, 1);
    p1 += __shfl_xor(p1, 2); p2 += __shfl_xor(p2, 2);
    p1 += __shfl_xor(p1, 4); p2 += __shfl_xor(p2, 4);
    p1 += __shfl_xor(p1, 8); p2 += __shfl_xor(p2, 8);
    float e1 = fmaf(0.6f, dls1, fmaf(0.4f, p1, c0));
    float e2 = fmaf(0.6f, dls2, fmaf(0.4f, p2, c0));
    float emax = fmaxf(e1, e2);
    if (__any(emax > m)){
      float nm = fmaxf(m, emax);
      float al  = __expf(m - nm);
      float ex1 = __expf(e1 - nm);
      float ex2 = __expf(e2 - nm);
      m = nm;
      s = fmaf(s, al, ex1 + ex2);
      #pragma unroll
      for (int i = 0; i < 8; i++)
        acc[i] = fmaf(acc[i], al, fmaf(ex1, x1[i], ex2 * x2[i]));
    } else {
      float ex1 = __expf(e1 - m);
      float ex2 = __expf(e2 - m);
      s += ex1 + ex2;
      #pragma unroll
      for (int i = 0; i < 8; i++)
        acc[i] = fmaf(ex1, x1[i], fmaf(ex2, x2[i], acc[i]));
    }
  }
  if (j < end){
    int sn = csr[j];
    float dls = dl[sn * 4 + h];
    uint4 ux = *(const uint4*)(xl + (size_t)sn * 512 + lane * 8);
    float x[8] = {bflo(ux.x), bfhi(ux.x), bflo(ux.y), bfhi(ux.y),
                  bflo(ux.z), bfhi(ux.z), bflo(ux.w), bfhi(ux.w)};
    float pa = 0.f, pb = 0.f;
    #pragma unroll
    for (int i = 0; i < 4; i++){
      pa = fmaf(a[i],     fabsf(x[i]     + r[i]),     pa);
      pb = fmaf(a[i + 4], fabsf(x[i + 4] + r[i + 4]), pb);
    }
    float p = pa + pb;
    p += __shfl_xor(p, 1);
    p += __shfl_xor(p, 2);
    p += __shfl_xor(p, 4);
    p += __shfl_xor(p, 8);
    float e = fmaf(0.6f, dls, fmaf(0.4f, p, c0));
    if (__any(e > m)){
      float nm = fmaxf(m, e);
      float al = __expf(m - nm);
      float ex = __expf(e - nm);
      m = nm;
      s = fmaf(s, al, ex);
      #pragma unroll
      for (int i = 0; i < 8; i++) acc[i] = fmaf(acc[i], al, ex * x[i]);
    } else {
      float ex = __expf(e - m);
      s += ex;
      #pragma unroll
      for (int i = 0; i < 8; i++) acc[i] = fmaf(ex, x[i], acc[i]);
    }
  }
  float inv = 1.f / (s + 1e-16f);
  const float* bp = bias + lane * 8;
  float4 B0 = *(const float4*)bp, B1 = *(const float4*)(bp + 4);
  float bb[8] = {B0.x,B0.y,B0.z,B0.w,B1.x,B1.y,B1.z,B1.w};
  unsigned short o[8];
  #pragma unroll
  for (int i = 0; i < 8; i++)
    o[i] = f2bf(fmaxf(fmaf(acc[i], inv, bb[i]), 0.f));
  uint4 ov;
  ov.x = (uint32)o[0] | ((uint32)o[1] << 16);
  ov.y = (uint32)o[2] | ((uint32)o[3] << 16);
  ov.z = (uint32)o[4] | ((uint32)o[5] << 16);
  ov.w = (uint32)o[6] | ((uint32)o[7] << 16);
  *(uint4*)(out + (size_t)n * 512 + lane * 8) = ov;
}

// ---------------- layer-2 GATv2 attention + fused output GEMM ----------------
__global__ __launch_bounds__(256) void k_attn2(const unsigned short* __restrict__ xl,
                                               const float* __restrict__ xr,
                                               const float* __restrict__ dl, const float* __restrict__ dr,
                                               const float* __restrict__ att, const float* __restrict__ bias,
                                               const float* __restrict__ outW, const float* __restrict__ outb,
                                               const int* __restrict__ off, const int* __restrict__ csr,
                                               float* __restrict__ out){
  __shared__ float Wsh[1280];
  int tid = threadIdx.x;
  for (int i = tid; i < 1280; i += 256) Wsh[i] = outW[i];
  __syncthreads();
  int lane = tid & 63;
  int n = blockIdx.x * 4 + (tid >> 6);
  float2 rv = *(const float2*)(xr + (size_t)n * 128 + lane * 2);
  float2 av = *(const float2*)(att + lane * 2);
  float c0 = 0.6f * dr[n];
  int beg = off[n], end = off[n + 1];
  float m = -INFINITY, s = 0.f;
  float a0 = 0.f, a1 = 0.f;
  int j = beg;
  for (; j + 1 < end; j += 2){
    int sn1 = csr[j], sn2 = csr[j + 1];
    float dls1 = dl[sn1], dls2 = dl[sn2];
    uint32 u1 = *(const uint32*)(xl + (size_t)sn1 * 128 + lane * 2);
    uint32 u2 = *(const uint32*)(xl + (size_t)sn2 * 128 + lane * 2);
    float x10 = bflo(u1), x11 = bfhi(u1);
    float x20 = bflo(u2), x21 = bfhi(u2);
    float p1 = fmaf(av.x, fabsf(x10 + rv.x), av.y * fabsf(x11 + rv.y));
    float p2 = fmaf(av.x, fabsf(x20 + rv.x), av.y * fabsf(x21 + rv.y));
    p1 += __shfl_xor(p1, 1);  p2 += __shfl_xor(p2, 1);
    p1 += __shfl_xor(p1, 2);  p2 += __shfl_xor(p2, 2);
    p1 += __shfl_xor(p1, 4);  p2 += __shfl_xor(p2, 4);
    p1 += __shfl_xor(p1, 8);  p2 += __shfl_xor(p2, 8);
    p1 += __shfl_xor(p1, 16); p2 += __shfl_xor(p2, 16);
    p1 += __shfl_xor(p1, 32); p2 += __shfl_xor(p2, 32);
    float e1 = fmaf(0.6f, dls1, fmaf(0.4f, p1, c0));
    float e2 = fmaf(0.6f, dls2, fmaf(0.4f, p2, c0));
    float emax = fmaxf(e1, e2);
    if (emax > m){
      float al  = __expf(m - emax);
      float ex1 = __expf(e1 - emax);
      float ex2 = __expf(e2 - emax);
      m = emax;
      s  = fmaf(s,  al, ex1 + ex2);
      a0 = fmaf(a0, al, fmaf(ex1, x10, ex2 * x20));
      a1 = fmaf(a1, al, fmaf(ex1, x11, ex2 * x21));
    } else {
      float ex1 = __expf(e1 - m);
      float ex2 = __expf(e2 - m);
      s += ex1 + ex2;
      a0 = fmaf(ex1, x10, fmaf(ex2, x20, a0));
      a1 = fmaf(ex1, x11, fmaf(ex2, x21, a1));
    }
  }
  if (j < end){
    int sn = csr[j];
    float dls = dl[sn];
    uint32 u = *(const uint32*)(xl + (size_t)sn * 128 + lane * 2);
    float x0 = bflo(u), x1 = bfhi(u);
    float p = fmaf(av.x, fabsf(x0 + rv.x), av.y * fabsf(x1 + rv.y));
    p += __shfl_xor(p, 1);
    p += __shfl_xor(p, 2);
    p += __shfl_xor(p, 4);
    p += __shfl_xor(p, 8);
    p += __shfl_xor(p, 16);
    p += __shfl_xor(p, 32);
    float e = fmaf(0.6f, dls, fmaf(0.4f, p, c0));
    if (e > m){
      float al = __expf(m - e);
      m = e;
      s  = fmaf(s,  al, 1.f);
      a0 = fmaf(a0, al, x0);
      a1 = fmaf(a1, al, x1);
    } else {
      float ex = __expf(e - m);
      s += ex;
      a0 = fmaf(ex, x0, a0);
      a1 = fmaf(ex, x1, a1);
    }
  }
  float inv = 1.f / (s + 1e-16f);
  int c = lane * 2;
  float x2_0 = fmaf(a0, inv, bias[c]);
  float x2_1 = fmaf(a1, inv, bias[c + 1]);
  // fused output GEMM: out[n,o] = sum_c x2_c * outW[c,o] + outb[o]
  #pragma unroll
  for (int o = 0; o < 10; o++){
    float p = fmaf(x2_0, Wsh[c * 10 + o], x2_1 * Wsh[(c + 1) * 10 + o]);
    p += __shfl_xor(p, 1);
    p += __shfl_xor(p, 2);
    p += __shfl_xor(p, 4);
    p += __shfl_xor(p, 8);
    p += __shfl_xor(p, 16);
    p += __shfl_xor(p, 32);
    if (lane == 0) out[(size_t)n * 10 + o] = p + outb[o];
  }
}

extern "C" void kernel_launch(void* const* d_in, const int* in_sizes, int n_in,
                              void* d_out, int out_size, void* d_ws, size_t ws_size,
                              hipStream_t stream){
  const float* xp    = (const float*)d_in[0];
  const int*   ei    = (const int*)  d_in[1];
  const float* emb   = (const float*)d_in[2];
  const float* projW = (const float*)d_in[3];
  const float* projb = (const float*)d_in[4];
  const float* W1l   = (const float*)d_in[5];
  const float* W1r   = (const float*)d_in[6];
  const float* att1  = (const float*)d_in[7];
  const float* b1    = (const float*)d_in[8];
  const float* W2l   = (const float*)d_in[9];
  const float* W2r   = (const float*)d_in[10];
  const float* att2  = (const float*)d_in[11];
  const float* b2    = (const float*)d_in[12];
  const float* outW  = (const float*)d_in[13];
  const float* outb  = (const float*)d_in[14];
  float* out = (float*)d_out;

  int E = in_sizes[1] / 2;
  const int* esrc = ei;
  const int* edst = ei + E;

  char* w = (char*)d_ws;
  int* deg  = (int*)w; w += (size_t)NNODES * 4;
  int* off  = (int*)w; w += (size_t)(NNODES + 4) * 4;
  int* cur  = (int*)w; w += (size_t)NNODES * 4;
  int* csr  = (int*)w; w += (size_t)(NNODES + E) * 4;
  unsigned short* Xb   = (unsigned short*)w; w += (size_t)NNODES * 128 * 2;
  unsigned short* Wt1l = (unsigned short*)w; w += (size_t)512 * 128 * 2;
  unsigned short* Wt1r = (unsigned short*)w; w += (size_t)512 * 128 * 2;
  unsigned short* Wt2l = (unsigned short*)w; w += (size_t)128 * 512 * 2;
  unsigned short* Wt2r = (unsigned short*)w; w += (size_t)128 * 512 * 2;
  unsigned short* Wtp  = (unsigned short*)w; w += (size_t)128 * 192 * 2;
  unsigned short* xl1b = (unsigned short*)w; w += (size_t)NNODES * 512 * 2;
  unsigned short* xr1b = (unsigned short*)w; w += (size_t)NNODES * 512 * 2;
  unsigned short* X1b  = (unsigned short*)w; w += (size_t)NNODES * 512 * 2;
  unsigned short* xl2b = (unsigned short*)w; w += (size_t)NNODES * 128 * 2;
  float* xr2 = (float*)w; w += (size_t)NNODES * 128 * 4;
  float* dl1 = (float*)w; w += (size_t)NNODES * 4 * 4;
  float* dr1 = (float*)w; w += (size_t)NNODES * 4 * 4;
  float* dl2 = (float*)w; w += (size_t)NNODES * 4;
  float* dr2 = (float*)w; w += (size_t)NNODES * 4;

  hipMemsetAsync(deg, 0, (size_t)NNODES * 4, stream);
  k_count<<<(E + 255) / 256, 256, 0, stream>>>(edst, E, deg);
  k_scan<<<1, 256, 0, stream>>>(deg, off, cur);
  k_fill<<<(NNODES + E + 255) / 256, 256, 0, stream>>>(esrc, edst, E, cur, csr);

  k_cvt<<<1120, 256, 0, stream>>>(W1l, W1r, W2l, W2r, projW, Wt1l, Wt1r, Wt2l, Wt2r, Wtp);
  k_proj_mfma<<<dim3((NNODES + 63) / 64), 256, 0, stream>>>(xp, emb, Wtp, projb, Xb);
  k_mfma<128, 512, 0, 4><<<dim3(4, (NNODES + 63) / 64, 2), 256, 0, stream>>>(
      Xb, Wt1l, Wt1r, xl1b, xr1b, att1, dl1, dr1);
  k_attn1<<<NNODES / 4, 256, 0, stream>>>(xl1b, xr1b, dl1, dr1, att1, b1, off, csr, X1b);
  k_mfma<512, 128, 1, 1><<<dim3(1, (NNODES + 63) / 64, 2), 256, 0, stream>>>(
      X1b, Wt2l, Wt2r, xl2b, xr2, att2, dl2, dr2);
  k_attn2<<<NNODES / 4, 256, 0, stream>>>(xl2b, xr2, dl2, dr2, att2, b2, outW, outb, off, csr, out);
}

// Round 7
// 300.126 us; speedup vs baseline: 1.8805x; 1.1299x over previous
//
#include <hip/hip_runtime.h>
#include <math.h>

#define NNODES 20000
#define XP_COLS 65

typedef unsigned int uint32;
typedef __attribute__((ext_vector_type(8))) short short8;
typedef __attribute__((ext_vector_type(4))) float float4v;

__device__ __forceinline__ float bflo(uint32 u){ return __uint_as_float(u << 16); }
__device__ __forceinline__ float bfhi(uint32 u){ return __uint_as_float(u & 0xffff0000u); }
__device__ __forceinline__ unsigned short f2bf(float f){
  uint32 u = __float_as_uint(f);
  uint32 r = (u + 0x7fffu + ((u >> 16) & 1u)) >> 16;
  return (unsigned short)r;
}
__device__ __forceinline__ void unpack8(uint4 u, float* x){
  x[0]=bflo(u.x); x[1]=bfhi(u.x); x[2]=bflo(u.y); x[3]=bfhi(u.y);
  x[4]=bflo(u.z); x[5]=bfhi(u.z); x[6]=bflo(u.w); x[7]=bfhi(u.w);
}

// ---------------- CSR build ----------------
__global__ void k_count(const int* __restrict__ dst, int E, int* __restrict__ deg){
  int e = blockIdx.x * 256 + threadIdx.x;
  if (e < E) atomicAdd(&deg[dst[e]], 1);
}

// chunked scan, int4-vectorized; deg[i]+1 accounts for self loop (deg pre-memset to 0)
__global__ __launch_bounds__(256) void k_scan(const int* __restrict__ deg,
                                              int* __restrict__ off,
                                              int* __restrict__ cursor){
  const int CH = 80;                        // 250 * 80 = 20000 exactly
  int tid = threadIdx.x;
  int lane = tid & 63, w = tid >> 6;
  int beg = tid * CH;
  bool act = beg < NNODES;
  int sum = 0;
  if (act){
    const int4* p = (const int4*)(deg + beg);
    #pragma unroll
    for (int i = 0; i < 20; i++){
      int4 v = p[i];
      sum += v.x + v.y + v.z + v.w + 4;
    }
  }
  int inc = sum;
  #pragma unroll
  for (int d = 1; d < 64; d <<= 1){
    int t = __shfl_up(inc, d, 64);
    if (lane >= d) inc += t;
  }
  __shared__ int wtot[4];
  if (lane == 63) wtot[w] = inc;
  __syncthreads();
  int wbase = 0;
  for (int i = 0; i < w; i++) wbase += wtot[i];
  int run = wbase + inc - sum;
  if (act){
    const int4* p = (const int4*)(deg + beg);
    int4* po = (int4*)(off + beg);
    int4* pc = (int4*)(cursor + beg);
    #pragma unroll
    for (int i = 0; i < 20; i++){
      int4 v = p[i];
      int4 o;
      o.x = run; run += v.x + 1;
      o.y = run; run += v.y + 1;
      o.z = run; run += v.z + 1;
      o.w = run; run += v.w + 1;
      po[i] = o; pc[i] = o;
    }
  }
  if (tid == 249) off[NNODES] = run;
}

__global__ void k_fill(const int* __restrict__ src, const int* __restrict__ dst, int E,
                       int* __restrict__ cursor, int* __restrict__ csr){
  int t = blockIdx.x * 256 + threadIdx.x;
  if (t < NNODES){
    int p = atomicAdd(&cursor[t], 1);
    csr[p] = t;
  } else if (t < NNODES + E){
    int e = t - NNODES;
    int p = atomicAdd(&cursor[dst[e]], 1);
    csr[p] = src[e];
  }
}

// ---------------- transpose+cast weights -> bf16 n-major [N][K]; coalesced WRITES ----------------
__global__ void k_cvt(const float* __restrict__ W1l, const float* __restrict__ W1r,
                      const float* __restrict__ W2l, const float* __restrict__ W2r,
                      const float* __restrict__ projW,
                      unsigned short* __restrict__ T1l, unsigned short* __restrict__ T1r,
                      unsigned short* __restrict__ T2l, unsigned short* __restrict__ T2r,
                      unsigned short* __restrict__ Tp){
  int idx = blockIdx.x * 256 + threadIdx.x;
  if (idx < 65536){
    int o = idx;                 // T1l[o], o = n*128 + k   (n<512, k<128)
    int n = o >> 7, k = o & 127;
    T1l[o] = f2bf(W1l[k * 512 + n]);
  } else if (idx < 131072){
    int o = idx - 65536;
    int n = o >> 7, k = o & 127;
    T1r[o] = f2bf(W1r[k * 512 + n]);
  } else if (idx < 196608){
    int o = idx - 131072;        // T2l[o], o = n*512 + k   (n<128, k<512)
    int n = o >> 9, k = o & 511;
    T2l[o] = f2bf(W2l[k * 128 + n]);
  } else if (idx < 262144){
    int o = idx - 196608;
    int n = o >> 9, k = o & 511;
    T2r[o] = f2bf(W2r[k * 128 + n]);
  } else if (idx < 286720){
    int o = idx - 262144;        // Tp[o], o = n*192 + k    (n<128, k<192)
    int n = o / 192, k = o - n * 192;
    Tp[o] = f2bf(projW[k * 128 + n]);
  }
}

// ---------------- proj via MFMA with fused gather ----------------
__global__ __launch_bounds__(256) void k_proj_mfma(const float* __restrict__ xp,
                                                   const float* __restrict__ emb,
                                                   const unsigned short* __restrict__ Bt,
                                                   const float* __restrict__ bias,
                                                   unsigned short* __restrict__ Xb){
  __shared__ unsigned short As[64][40];
  __shared__ unsigned short Bs[128][40];
  __shared__ int ids[64];
  int tid = threadIdx.x;
  int bm = blockIdx.x * 64;
  int w = tid >> 6, lane = tid & 63;
  int wm = (w >> 1) * 32, wn = (w & 1) * 64;
  int quad = lane >> 4, l16 = lane & 15;
  if (tid < 64){
    int g = bm + tid;
    ids[tid] = (g < NNODES) ? (int)xp[(size_t)g * XP_COLS] : 0;
  }
  float4v acc[2][4];
  #pragma unroll
  for (int i = 0; i < 2; i++)
    #pragma unroll
    for (int j = 0; j < 4; j++) acc[i][j] = (float4v){0.f,0.f,0.f,0.f};
  int am = tid >> 2, ak = (tid & 3) * 8;
  int gm = bm + am;
  bool mv = gm < NNODES;
  int brow = tid >> 1, bk = (tid & 1) * 16;
  __syncthreads();

  for (int k0 = 0; k0 < 192; k0 += 32){
    float v[8];
    if (k0 < 128){
      const float* ep = emb + (size_t)ids[am] * 128 + k0 + ak;
      float4 e0 = *(const float4*)ep;
      float4 e1 = *(const float4*)(ep + 4);
      v[0]=e0.x; v[1]=e0.y; v[2]=e0.z; v[3]=e0.w;
      v[4]=e1.x; v[5]=e1.y; v[6]=e1.z; v[7]=e1.w;
    } else {
      const float* fp = xp + (size_t)gm * XP_COLS + 1 + (k0 - 128) + ak;
      #pragma unroll
      for (int i = 0; i < 8; i++) v[i] = mv ? fp[i] : 0.f;
    }
    ushort4 o0, o1;
    o0.x=f2bf(v[0]); o0.y=f2bf(v[1]); o0.z=f2bf(v[2]); o0.w=f2bf(v[3]);
    o1.x=f2bf(v[4]); o1.y=f2bf(v[5]); o1.z=f2bf(v[6]); o1.w=f2bf(v[7]);
    *(ushort4*)&As[am][ak]     = o0;
    *(ushort4*)&As[am][ak + 4] = o1;
    const unsigned short* bp = Bt + (size_t)brow * 192 + k0 + bk;
    *(uint4*)&Bs[brow][bk]     = *(const uint4*)bp;
    *(uint4*)&Bs[brow][bk + 8] = *(const uint4*)(bp + 8);
    __syncthreads();
    short8 af[2], bf[4];
    #pragma unroll
    for (int t = 0; t < 2; t++) af[t] = *(const short8*)&As[wm + t * 16 + l16][quad * 8];
    #pragma unroll
    for (int t = 0; t < 4; t++) bf[t] = *(const short8*)&Bs[wn + t * 16 + l16][quad * 8];
    #pragma unroll
    for (int tm = 0; tm < 2; tm++)
      #pragma unroll
      for (int tn = 0; tn < 4; tn++)
        acc[tm][tn] = __builtin_amdgcn_mfma_f32_16x16x32_bf16(af[tm], bf[tn], acc[tm][tn], 0, 0, 0);
    __syncthreads();
  }
  #pragma unroll
  for (int tm = 0; tm < 2; tm++){
    #pragma unroll
    for (int r = 0; r < 4; r++){
      int row = bm + wm + tm * 16 + quad * 4 + r;
      if (row >= NNODES) continue;
      #pragma unroll
      for (int tn = 0; tn < 4; tn++){
        int col = wn + tn * 16 + l16;
        float val = fmaxf(acc[tm][tn][r] + bias[col], 0.f);
        Xb[(size_t)row * 128 + col] = f2bf(val);
      }
    }
  }
}

// ---------------- MFMA GEMM with fused per-row attention dot ----------------
template<int K, int N, int MODE, int NH>
__global__ __launch_bounds__(256) void k_mfma(const unsigned short* __restrict__ A,
                                              const unsigned short* __restrict__ B0t,
                                              const unsigned short* __restrict__ B1t,
                                              void* __restrict__ C0, void* __restrict__ C1,
                                              const float* __restrict__ att,
                                              float* __restrict__ dl, float* __restrict__ dr){
  const unsigned short* Bt = blockIdx.z ? B1t : B0t;
  __shared__ unsigned short As[64][40];
  __shared__ unsigned short Bs[128][40];
  __shared__ float red[4][32];
  int tid = threadIdx.x;
  int bm = blockIdx.y * 64;
  int bn = blockIdx.x * 128;
  int head = (NH == 1) ? 0 : blockIdx.x;
  int w = tid >> 6, lane = tid & 63;
  int wm = (w >> 1) * 32, wn = (w & 1) * 64;
  int quad = lane >> 4, l16 = lane & 15;
  float av[4];
  #pragma unroll
  for (int tn = 0; tn < 4; tn++) av[tn] = att[head * 128 + wn + tn * 16 + l16];
  float4v acc[2][4];
  #pragma unroll
  for (int i = 0; i < 2; i++)
    #pragma unroll
    for (int j = 0; j < 4; j++) acc[i][j] = (float4v){0.f,0.f,0.f,0.f};
  int am = tid >> 2, ak = (tid & 3) * 8;
  int gm = bm + am;
  bool mv = gm < NNODES;
  int brow = tid >> 1, bk = (tid & 1) * 16;

  for (int k0 = 0; k0 < K; k0 += 32){
    uint4 va = {0u,0u,0u,0u};
    if (mv) va = *(const uint4*)(A + (size_t)gm * K + k0 + ak);
    *(uint4*)&As[am][ak] = va;
    const unsigned short* bp = Bt + (size_t)(bn + brow) * K + k0 + bk;
    *(uint4*)&Bs[brow][bk]     = *(const uint4*)bp;
    *(uint4*)&Bs[brow][bk + 8] = *(const uint4*)(bp + 8);
    __syncthreads();
    short8 af[2], bf[4];
    #pragma unroll
    for (int t = 0; t < 2; t++) af[t] = *(const short8*)&As[wm + t * 16 + l16][quad * 8];
    #pragma unroll
    for (int t = 0; t < 4; t++) bf[t] = *(const short8*)&Bs[wn + t * 16 + l16][quad * 8];
    #pragma unroll
    for (int tm = 0; tm < 2; tm++)
      #pragma unroll
      for (int tn = 0; tn < 4; tn++)
        acc[tm][tn] = __builtin_amdgcn_mfma_f32_16x16x32_bf16(af[tm], bf[tn], acc[tm][tn], 0, 0, 0);
    __syncthreads();
  }
  #pragma unroll
  for (int tm = 0; tm < 2; tm++){
    #pragma unroll
    for (int r = 0; r < 4; r++){
      int row = bm + wm + tm * 16 + quad * 4 + r;
      if (row < NNODES){
        #pragma unroll
        for (int tn = 0; tn < 4; tn++){
          int col = bn + wn + tn * 16 + l16;
          float val = acc[tm][tn][r];
          if (MODE == 0 || blockIdx.z == 0){
            unsigned short* C = (unsigned short*)(blockIdx.z ? C1 : C0);
            C[(size_t)row * N + col] = f2bf(val);
          } else {
            ((float*)C1)[(size_t)row * N + col] = val;
          }
        }
      }
      float pd = acc[tm][0][r] * av[0];
      pd = fmaf(acc[tm][1][r], av[1], pd);
      pd = fmaf(acc[tm][2][r], av[2], pd);
      pd = fmaf(acc[tm][3][r], av[3], pd);
      pd += __shfl_xor(pd, 1);
      pd += __shfl_xor(pd, 2);
      pd += __shfl_xor(pd, 4);
      pd += __shfl_xor(pd, 8);
      if (l16 == 0) red[w][tm * 16 + quad * 4 + r] = pd;
    }
  }
  __syncthreads();
  if (tid < 64){
    float v = (tid < 32) ? red[0][tid] + red[1][tid] : red[2][tid & 31] + red[3][tid & 31];
    int row = bm + tid;
    if (row < NNODES){
      float* D = blockIdx.z ? dr : dl;
      D[row * NH + head] = v;
    }
  }
}

// ---------------- layer-1 GATv2: one wave per node, 4-edge software pipeline ----------------
// e = 0.6*(dl[src]+dr[dst]) + 0.4*sum_c a_c*|x_c + r_c|
__global__ __launch_bounds__(256) void k_attn1(const unsigned short* __restrict__ xl,
                                               const unsigned short* __restrict__ xr,
                                               const float* __restrict__ dl, const float* __restrict__ dr,
                                               const float* __restrict__ att, const float* __restrict__ bias,
                                               const int* __restrict__ off, const int* __restrict__ csr,
                                               unsigned short* __restrict__ out){
  int lane = threadIdx.x & 63;
  int n = blockIdx.x * 4 + (threadIdx.x >> 6);
  int h = lane >> 4;
  uint4 ur = *(const uint4*)(xr + (size_t)n * 512 + lane * 8);
  float r[8]; unpack8(ur, r);
  const float* ap = att + lane * 8;
  float4 A0 = *(const float4*)ap, A1 = *(const float4*)(ap + 4);
  float a[8] = {A0.x,A0.y,A0.z,A0.w,A1.x,A1.y,A1.z,A1.w};
  float c0 = 0.6f * dr[n * 4 + h];
  int beg = off[n], end = off[n + 1];

  float m = -INFINITY, s = 0.f;
  float acc[8] = {0,0,0,0,0,0,0,0};
  int j = beg;
  for (; j + 3 < end; j += 4){
    int sn0 = csr[j], sn1 = csr[j + 1], sn2 = csr[j + 2], sn3 = csr[j + 3];
    uint4 u0 = *(const uint4*)(xl + (size_t)sn0 * 512 + lane * 8);
    uint4 u1 = *(const uint4*)(xl + (size_t)sn1 * 512 + lane * 8);
    uint4 u2 = *(const uint4*)(xl + (size_t)sn2 * 512 + lane * 8);
    uint4 u3 = *(const uint4*)(xl + (size_t)sn3 * 512 + lane * 8);
    float d0 = dl[sn0 * 4 + h], d1 = dl[sn1 * 4 + h];
    float d2 = dl[sn2 * 4 + h], d3 = dl[sn3 * 4 + h];
    float x0[8], x1[8], x2[8], x3[8];
    unpack8(u0, x0); unpack8(u1, x1); unpack8(u2, x2); unpack8(u3, x3);
    float p0 = 0.f, p1 = 0.f, p2 = 0.f, p3 = 0.f;
    #pragma unroll
    for (int i = 0; i < 8; i++){
      p0 = fmaf(a[i], fabsf(x0[i] + r[i]), p0);
      p1 = fmaf(a[i], fabsf(x1[i] + r[i]), p1);
      p2 = fmaf(a[i], fabsf(x2[i] + r[i]), p2);
      p3 = fmaf(a[i], fabsf(x3[i] + r[i]), p3);
    }
    p0 += __shfl_xor(p0, 1); p1 += __shfl_xor(p1, 1); p2 += __shfl_xor(p2, 1); p3 += __shfl_xor(p3, 1);
    p0 += __shfl_xor(p0, 2); p1 += __shfl_xor(p1, 2); p2 += __shfl_xor(p2, 2); p3 += __shfl_xor(p3, 2);
    p0 += __shfl_xor(p0, 4); p1 += __shfl_xor(p1, 4); p2 += __shfl_xor(p2, 4); p3 += __shfl_xor(p3, 4);
    p0 += __shfl_xor(p0, 8); p1 += __shfl_xor(p1, 8); p2 += __shfl_xor(p2, 8); p3 += __shfl_xor(p3, 8);
    float e0 = fmaf(0.6f, d0, fmaf(0.4f, p0, c0));
    float e1 = fmaf(0.6f, d1, fmaf(0.4f, p1, c0));
    float e2 = fmaf(0.6f, d2, fmaf(0.4f, p2, c0));
    float e3 = fmaf(0.6f, d3, fmaf(0.4f, p3, c0));
    float emax = fmaxf(fmaxf(e0, e1), fmaxf(e2, e3));
    if (__any(emax > m)){
      float nm = fmaxf(m, emax);
      float al  = __expf(m - nm);
      float ex0 = __expf(e0 - nm), ex1 = __expf(e1 - nm);
      float ex2 = __expf(e2 - nm), ex3 = __expf(e3 - nm);
      m = nm;
      s = fmaf(s, al, (ex0 + ex1) + (ex2 + ex3));
      #pragma unroll
      for (int i = 0; i < 8; i++){
        float t = fmaf(ex0, x0[i], ex1 * x1[i]);
        t = fmaf(ex2, x2[i], t);
        t = fmaf(ex3, x3[i], t);
        acc[i] = fmaf(acc[i], al, t);
      }
    } else {
      float ex0 = __expf(e0 - m), ex1 = __expf(e1 - m);
      float ex2 = __expf(e2 - m), ex3 = __expf(e3 - m);
      s += (ex0 + ex1) + (ex2 + ex3);
      #pragma unroll
      for (int i = 0; i < 8; i++){
        float t = fmaf(ex0, x0[i], ex1 * x1[i]);
        t = fmaf(ex2, x2[i], t);
        acc[i] = fmaf(ex3, x3[i], acc[i] + t);
      }
    }
  }
  for (; j < end; j++){
    int sn = csr[j];
    float dls = dl[sn * 4 + h];
    uint4 ux = *(const uint4*)(xl + (size_t)sn * 512 + lane * 8);
    float x[8]; unpack8(ux, x);
    float p = 0.f;
    #pragma unroll
    for (int i = 0; i < 8; i++) p = fmaf(a[i], fabsf(x[i] + r[i]), p);
    p += __shfl_xor(p, 1);
    p += __shfl_xor(p, 2);
    p += __shfl_xor(p, 4);
    p += __shfl_xor(p, 8);
    float e = fmaf(0.6f, dls, fmaf(0.4f, p, c0));
    if (__any(e > m)){
      float nm = fmaxf(m, e);
      float al = __expf(m - nm);
      float ex = __expf(e - nm);
      m = nm;
      s = fmaf(s, al, ex);
      #pragma unroll
      for (int i = 0; i < 8; i++) acc[i] = fmaf(acc[i], al, ex * x[i]);
    } else {
      float ex = __expf(e - m);
      s += ex;
      #pragma unroll
      for (int i = 0; i < 8; i++) acc[i] = fmaf(ex, x[i], acc[i]);
    }
  }
  float inv = 1.f / (s + 1e-16f);
  const float* bp = bias + lane * 8;
  float4 B0 = *(const float4*)bp, B1 = *(const float4*)(bp + 4);
  float bb[8] = {B0.x,B0.y,B0.z,B0.w,B1.x,B1.y,B1.z,B1.w};
  unsigned short o[8];
  #pragma unroll
  for (int i = 0; i < 8; i++)
    o[i] = f2bf(fmaxf(fmaf(acc[i], inv, bb[i]), 0.f));
  uint4 ov;
  ov.x = (uint32)o[0] | ((uint32)o[1] << 16);
  ov.y = (uint32)o[2] | ((uint32)o[3] << 16);
  ov.z = (uint32)o[4] | ((uint32)o[5] << 16);
  ov.w = (uint32)o[6] | ((uint32)o[7] << 16);
  *(uint4*)(out + (size_t)n * 512 + lane * 8) = ov;
}

// ---------------- layer-2 GATv2 + fused output GEMM, 4-edge pipeline ----------------
__global__ __launch_bounds__(256) void k_attn2(const unsigned short* __restrict__ xl,
                                               const float* __restrict__ xr,
                                               const float* __restrict__ dl, const float* __restrict__ dr,
                                               const float* __restrict__ att, const float* __restrict__ bias,
                                               const float* __restrict__ outW, const float* __restrict__ outb,
                                               const int* __restrict__ off, const int* __restrict__ csr,
                                               float* __restrict__ out){
  __shared__ float Wsh[1280];
  int tid = threadIdx.x;
  for (int i = tid; i < 1280; i += 256) Wsh[i] = outW[i];
  __syncthreads();
  int lane = tid & 63;
  int n = blockIdx.x * 4 + (tid >> 6);
  float2 rv = *(const float2*)(xr + (size_t)n * 128 + lane * 2);
  float2 av = *(const float2*)(att + lane * 2);
  float c0 = 0.6f * dr[n];
  int beg = off[n], end = off[n + 1];
  float m = -INFINITY, s = 0.f;
  float a0 = 0.f, a1 = 0.f;
  int j = beg;
  for (; j + 3 < end; j += 4){
    int sn0 = csr[j], sn1 = csr[j + 1], sn2 = csr[j + 2], sn3 = csr[j + 3];
    uint32 u0 = *(const uint32*)(xl + (size_t)sn0 * 128 + lane * 2);
    uint32 u1 = *(const uint32*)(xl + (size_t)sn1 * 128 + lane * 2);
    uint32 u2 = *(const uint32*)(xl + (size_t)sn2 * 128 + lane * 2);
    uint32 u3 = *(const uint32*)(xl + (size_t)sn3 * 128 + lane * 2);
    float d0 = dl[sn0], d1 = dl[sn1], d2 = dl[sn2], d3 = dl[sn3];
    float x00 = bflo(u0), x01 = bfhi(u0);
    float x10 = bflo(u1), x11 = bfhi(u1);
    float x20 = bflo(u2), x21 = bfhi(u2);
    float x30 = bflo(u3), x31 = bfhi(u3);
    float p0 = fmaf(av.x, fabsf(x00 + rv.x), av.y * fabsf(x01 + rv.y));
    float p1 = fmaf(av.x, fabsf(x10 + rv.x), av.y * fabsf(x11 + rv.y));
    float p2 = fmaf(av.x, fabsf(x20 + rv.x), av.y * fabsf(x21 + rv.y));
    float p3 = fmaf(av.x, fabsf(x30 + rv.x), av.y * fabsf(x31 + rv.y));
    p0 += __shfl_xor(p0, 1);  p1 += __shfl_xor(p1, 1);  p2 += __shfl_xor(p2, 1);  p3 += __shfl_xor(p3, 1);
    p0 += __shfl_xor(p0, 2);  p1 += __shfl_xor(p1, 2);  p2 += __shfl_xor(p2, 2);  p3 += __shfl_xor(p3, 2);
    p0 += __shfl_xor(p0, 4);  p1 += __shfl_xor(p1, 4);  p2 += __shfl_xor(p2, 4);  p3 += __shfl_xor(p3, 4);
    p0 += __shfl_xor(p0, 8);  p1 += __shfl_xor(p1, 8);  p2 += __shfl_xor(p2, 8);  p3 += __shfl_xor(p3, 8);
    p0 += __shfl_xor(p0, 16); p1 += __shfl_xor(p1, 16); p2 += __shfl_xor(p2, 16); p3 += __shfl_xor(p3, 16);
    p0 += __shfl_xor(p0, 32); p1 += __shfl_xor(p1, 32); p2 += __shfl_xor(p2, 32); p3 += __shfl_xor(p3, 32);
    float e0 = fmaf(0.6f, d0, fmaf(0.4f, p0, c0));
    float e1 = fmaf(0.6f, d1, fmaf(0.4f, p1, c0));
    float e2 = fmaf(0.6f, d2, fmaf(0.4f, p2, c0));
    float e3 = fmaf(0.6f, d3, fmaf(0.4f, p3, c0));
    float emax = fmaxf(fmaxf(e0, e1), fmaxf(e2, e3));
    if (emax > m){
      float al  = __expf(m - emax);
      float ex0 = __expf(e0 - emax), ex1 = __expf(e1 - emax);
      float ex2 = __expf(e2 - emax), ex3 = __expf(e3 - emax);
      m = emax;
      s  = fmaf(s,  al, (ex0 + ex1) + (ex2 + ex3));
      float t0 = fmaf(ex0, x00, ex1 * x10); t0 = fmaf(ex2, x20, t0); t0 = fmaf(ex3, x30, t0);
      float t1 = fmaf(ex0, x01, ex1 * x11); t1 = fmaf(ex2, x21, t1); t1 = fmaf(ex3, x31, t1);
      a0 = fmaf(a0, al, t0);
      a1 = fmaf(a1, al, t1);
    } else {
      float ex0 = __expf(e0 - m), ex1 = __expf(e1 - m);
      float ex2 = __expf(e2 - m), ex3 = __expf(e3 - m);
      s += (ex0 + ex1) + (ex2 + ex3);
      float t0 = fmaf(ex0, x00, ex1 * x10); t0 = fmaf(ex2, x20, t0);
      float t1 = fmaf(ex0, x01, ex1 * x11); t1 = fmaf(ex2, x21, t1);
      a0 = fmaf(ex3, x30, a0 + t0);
      a1 = fmaf(ex3, x31, a1 + t1);
    }
  }
  for (; j < end; j++){
    int sn = csr[j];
    float dls = dl[sn];
    uint32 u = *(const uint32*)(xl + (size_t)sn * 128 + lane * 2);
    float x0 = bflo(u), x1 = bfhi(u);
    float p = fmaf(av.x, fabsf(x0 + rv.x), av.y * fabsf(x1 + rv.y));
    p += __shfl_xor(p, 1);
    p += __shfl_xor(p, 2);
    p += __shfl_xor(p, 4);
    p += __shfl_xor(p, 8);
    p += __shfl_xor(p, 16);
    p += __shfl_xor(p, 32);
    float e = fmaf(0.6f, dls, fmaf(0.4f, p, c0));
    if (e > m){
      float al = __expf(m - e);
      m = e;
      s  = fmaf(s,  al, 1.f);
      a0 = fmaf(a0, al, x0);
      a1 = fmaf(a1, al, x1);
    } else {
      float ex = __expf(e - m);
      s += ex;
      a0 = fmaf(ex, x0, a0);
      a1 = fmaf(ex, x1, a1);
    }
  }
  float inv = 1.f / (s + 1e-16f);
  int c = lane * 2;
  float x2_0 = fmaf(a0, inv, bias[c]);
  float x2_1 = fmaf(a1, inv, bias[c + 1]);
  #pragma unroll
  for (int o = 0; o < 10; o++){
    float p = fmaf(x2_0, Wsh[c * 10 + o], x2_1 * Wsh[(c + 1) * 10 + o]);
    p += __shfl_xor(p, 1);
    p += __shfl_xor(p, 2);
    p += __shfl_xor(p, 4);
    p += __shfl_xor(p, 8);
    p += __shfl_xor(p, 16);
    p += __shfl_xor(p, 32);
    if (lane == 0) out[(size_t)n * 10 + o] = p + outb[o];
  }
}

extern "C" void kernel_launch(void* const* d_in, const int* in_sizes, int n_in,
                              void* d_out, int out_size, void* d_ws, size_t ws_size,
                              hipStream_t stream){
  const float* xp    = (const float*)d_in[0];
  const int*   ei    = (const int*)  d_in[1];
  const float* emb   = (const float*)d_in[2];
  const float* projW = (const float*)d_in[3];
  const float* projb = (const float*)d_in[4];
  const float* W1l   = (const float*)d_in[5];
  const float* W1r   = (const float*)d_in[6];
  const float* att1  = (const float*)d_in[7];
  const float* b1    = (const float*)d_in[8];
  const float* W2l   = (const float*)d_in[9];
  const float* W2r   = (const float*)d_in[10];
  const float* att2  = (const float*)d_in[11];
  const float* b2    = (const float*)d_in[12];
  const float* outW  = (const float*)d_in[13];
  const float* outb  = (const float*)d_in[14];
  float* out = (float*)d_out;

  int E = in_sizes[1] / 2;
  const int* esrc = ei;
  const int* edst = ei + E;

  char* w = (char*)d_ws;
  int* deg  = (int*)w; w += (size_t)NNODES * 4;
  int* off  = (int*)w; w += (size_t)(NNODES + 4) * 4;
  int* cur  = (int*)w; w += (size_t)NNODES * 4;
  int* csr  = (int*)w; w += (size_t)(NNODES + E) * 4;
  unsigned short* Xb   = (unsigned short*)w; w += (size_t)NNODES * 128 * 2;
  unsigned short* Wt1l = (unsigned short*)w; w += (size_t)512 * 128 * 2;
  unsigned short* Wt1r = (unsigned short*)w; w += (size_t)512 * 128 * 2;
  unsigned short* Wt2l = (unsigned short*)w; w += (size_t)128 * 512 * 2;
  unsigned short* Wt2r = (unsigned short*)w; w += (size_t)128 * 512 * 2;
  unsigned short* Wtp  = (unsigned short*)w; w += (size_t)128 * 192 * 2;
  unsigned short* xl1b = (unsigned short*)w; w += (size_t)NNODES * 512 * 2;
  unsigned short* xr1b = (unsigned short*)w; w += (size_t)NNODES * 512 * 2;
  unsigned short* X1b  = (unsigned short*)w; w += (size_t)NNODES * 512 * 2;
  unsigned short* xl2b = (unsigned short*)w; w += (size_t)NNODES * 128 * 2;
  float* xr2 = (float*)w; w += (size_t)NNODES * 128 * 4;
  float* dl1 = (float*)w; w += (size_t)NNODES * 4 * 4;
  float* dr1 = (float*)w; w += (size_t)NNODES * 4 * 4;
  float* dl2 = (float*)w; w += (size_t)NNODES * 4;
  float* dr2 = (float*)w; w += (size_t)NNODES * 4;

  hipMemsetAsync(deg, 0, (size_t)NNODES * 4, stream);
  k_count<<<(E + 255) / 256, 256, 0, stream>>>(edst, E, deg);
  k_scan<<<1, 256, 0, stream>>>(deg, off, cur);
  k_fill<<<(NNODES + E + 255) / 256, 256, 0, stream>>>(esrc, edst, E, cur, csr);

  k_cvt<<<1120, 256, 0, stream>>>(W1l, W1r, W2l, W2r, projW, Wt1l, Wt1r, Wt2l, Wt2r, Wtp);
  k_proj_mfma<<<dim3((NNODES + 63) / 64), 256, 0, stream>>>(xp, emb, Wtp, projb, Xb);
  k_mfma<128, 512, 0, 4><<<dim3(4, (NNODES + 63) / 64, 2), 256, 0, stream>>>(
      Xb, Wt1l, Wt1r, xl1b, xr1b, att1, dl1, dr1);
  k_attn1<<<NNODES / 4, 256, 0, stream>>>(xl1b, xr1b, dl1, dr1, att1, b1, off, csr, X1b);
  k_mfma<512, 128, 1, 1><<<dim3(1, (NNODES + 63) / 64, 2), 256, 0, stream>>>(
      X1b, Wt2l, Wt2r, xl2b, xr2, att2, dl2, dr2);
  k_attn2<<<NNODES / 4, 256, 0, stream>>>(xl2b, xr2, dl2, dr2, att2, b2, outW, outb, off, csr, out);
}

// Round 8
// 298.038 us; speedup vs baseline: 1.8937x; 1.0070x over previous
//
#include <hip/hip_runtime.h>
#include <math.h>

#define NNODES 20000
#define XP_COLS 65

typedef unsigned int uint32;
typedef __attribute__((ext_vector_type(8))) short short8;
typedef __attribute__((ext_vector_type(4))) float float4v;

__device__ __forceinline__ float bflo(uint32 u){ return __uint_as_float(u << 16); }
__device__ __forceinline__ float bfhi(uint32 u){ return __uint_as_float(u & 0xffff0000u); }
__device__ __forceinline__ unsigned short f2bf(float f){
  uint32 u = __float_as_uint(f);
  uint32 r = (u + 0x7fffu + ((u >> 16) & 1u)) >> 16;
  return (unsigned short)r;
}
__device__ __forceinline__ void unpack8(uint4 u, float* x){
  x[0]=bflo(u.x); x[1]=bfhi(u.x); x[2]=bflo(u.y); x[3]=bfhi(u.y);
  x[4]=bflo(u.z); x[5]=bfhi(u.z); x[6]=bflo(u.w); x[7]=bfhi(u.w);
}

// ---------------- fused: edge-degree count + weight transpose/cast ----------------
__global__ void k_cvt_count(const int* __restrict__ dst, int E, int* __restrict__ deg,
                            const float* __restrict__ W1l, const float* __restrict__ W1r,
                            const float* __restrict__ W2l, const float* __restrict__ W2r,
                            const float* __restrict__ projW,
                            unsigned short* __restrict__ T1l, unsigned short* __restrict__ T1r,
                            unsigned short* __restrict__ T2l, unsigned short* __restrict__ T2r,
                            unsigned short* __restrict__ Tp){
  int gid = blockIdx.x * 256 + threadIdx.x;
  if (gid < E){
    atomicAdd(&deg[dst[gid]], 1);
    return;
  }
  int idx = gid - E;
  if (idx < 65536){
    int o = idx;                 // T1l[o], o = n*128 + k   (n<512, k<128)
    int n = o >> 7, k = o & 127;
    T1l[o] = f2bf(W1l[k * 512 + n]);
  } else if (idx < 131072){
    int o = idx - 65536;
    int n = o >> 7, k = o & 127;
    T1r[o] = f2bf(W1r[k * 512 + n]);
  } else if (idx < 196608){
    int o = idx - 131072;        // T2l[o], o = n*512 + k   (n<128, k<512)
    int n = o >> 9, k = o & 511;
    T2l[o] = f2bf(W2l[k * 128 + n]);
  } else if (idx < 262144){
    int o = idx - 196608;
    int n = o >> 9, k = o & 511;
    T2r[o] = f2bf(W2r[k * 128 + n]);
  } else if (idx < 286720){
    int o = idx - 262144;        // Tp[o], o = n*192 + k    (n<128, k<192)
    int n = o / 192, k = o - n * 192;
    Tp[o] = f2bf(projW[k * 128 + n]);
  }
}

// chunked scan, int4-vectorized; deg[i]+1 accounts for self loop (deg pre-memset to 0)
__global__ __launch_bounds__(256) void k_scan(const int* __restrict__ deg,
                                              int* __restrict__ off,
                                              int* __restrict__ cursor){
  const int CH = 80;                        // 250 * 80 = 20000 exactly
  int tid = threadIdx.x;
  int lane = tid & 63, w = tid >> 6;
  int beg = tid * CH;
  bool act = beg < NNODES;
  int sum = 0;
  if (act){
    const int4* p = (const int4*)(deg + beg);
    #pragma unroll
    for (int i = 0; i < 20; i++){
      int4 v = p[i];
      sum += v.x + v.y + v.z + v.w + 4;
    }
  }
  int inc = sum;
  #pragma unroll
  for (int d = 1; d < 64; d <<= 1){
    int t = __shfl_up(inc, d, 64);
    if (lane >= d) inc += t;
  }
  __shared__ int wtot[4];
  if (lane == 63) wtot[w] = inc;
  __syncthreads();
  int wbase = 0;
  for (int i = 0; i < w; i++) wbase += wtot[i];
  int run = wbase + inc - sum;
  if (act){
    const int4* p = (const int4*)(deg + beg);
    int4* po = (int4*)(off + beg);
    int4* pc = (int4*)(cursor + beg);
    #pragma unroll
    for (int i = 0; i < 20; i++){
      int4 v = p[i];
      int4 o;
      o.x = run; run += v.x + 1;
      o.y = run; run += v.y + 1;
      o.z = run; run += v.z + 1;
      o.w = run; run += v.w + 1;
      po[i] = o; pc[i] = o;
    }
  }
  if (tid == 249) off[NNODES] = run;
}

__global__ void k_fill(const int* __restrict__ src, const int* __restrict__ dst, int E,
                       int* __restrict__ cursor, int* __restrict__ csr){
  int t = blockIdx.x * 256 + threadIdx.x;
  if (t < NNODES){
    int p = atomicAdd(&cursor[t], 1);
    csr[p] = t;
  } else if (t < NNODES + E){
    int e = t - NNODES;
    int p = atomicAdd(&cursor[dst[e]], 1);
    csr[p] = src[e];
  }
}

// ---------------- proj via MFMA with fused gather ----------------
__global__ __launch_bounds__(256) void k_proj_mfma(const float* __restrict__ xp,
                                                   const float* __restrict__ emb,
                                                   const unsigned short* __restrict__ Bt,
                                                   const float* __restrict__ bias,
                                                   unsigned short* __restrict__ Xb){
  __shared__ unsigned short As[64][40];
  __shared__ unsigned short Bs[128][40];
  __shared__ int ids[64];
  int tid = threadIdx.x;
  int bm = blockIdx.x * 64;
  int w = tid >> 6, lane = tid & 63;
  int wm = (w >> 1) * 32, wn = (w & 1) * 64;
  int quad = lane >> 4, l16 = lane & 15;
  if (tid < 64){
    int g = bm + tid;
    ids[tid] = (g < NNODES) ? (int)xp[(size_t)g * XP_COLS] : 0;
  }
  float4v acc[2][4];
  #pragma unroll
  for (int i = 0; i < 2; i++)
    #pragma unroll
    for (int j = 0; j < 4; j++) acc[i][j] = (float4v){0.f,0.f,0.f,0.f};
  int am = tid >> 2, ak = (tid & 3) * 8;
  int gm = bm + am;
  bool mv = gm < NNODES;
  int brow = tid >> 1, bk = (tid & 1) * 16;
  __syncthreads();

  for (int k0 = 0; k0 < 192; k0 += 32){
    float v[8];
    if (k0 < 128){
      const float* ep = emb + (size_t)ids[am] * 128 + k0 + ak;
      float4 e0 = *(const float4*)ep;
      float4 e1 = *(const float4*)(ep + 4);
      v[0]=e0.x; v[1]=e0.y; v[2]=e0.z; v[3]=e0.w;
      v[4]=e1.x; v[5]=e1.y; v[6]=e1.z; v[7]=e1.w;
    } else {
      const float* fp = xp + (size_t)gm * XP_COLS + 1 + (k0 - 128) + ak;
      #pragma unroll
      for (int i = 0; i < 8; i++) v[i] = mv ? fp[i] : 0.f;
    }
    ushort4 o0, o1;
    o0.x=f2bf(v[0]); o0.y=f2bf(v[1]); o0.z=f2bf(v[2]); o0.w=f2bf(v[3]);
    o1.x=f2bf(v[4]); o1.y=f2bf(v[5]); o1.z=f2bf(v[6]); o1.w=f2bf(v[7]);
    *(ushort4*)&As[am][ak]     = o0;
    *(ushort4*)&As[am][ak + 4] = o1;
    const unsigned short* bp = Bt + (size_t)brow * 192 + k0 + bk;
    *(uint4*)&Bs[brow][bk]     = *(const uint4*)bp;
    *(uint4*)&Bs[brow][bk + 8] = *(const uint4*)(bp + 8);
    __syncthreads();
    short8 af[2], bf[4];
    #pragma unroll
    for (int t = 0; t < 2; t++) af[t] = *(const short8*)&As[wm + t * 16 + l16][quad * 8];
    #pragma unroll
    for (int t = 0; t < 4; t++) bf[t] = *(const short8*)&Bs[wn + t * 16 + l16][quad * 8];
    #pragma unroll
    for (int tm = 0; tm < 2; tm++)
      #pragma unroll
      for (int tn = 0; tn < 4; tn++)
        acc[tm][tn] = __builtin_amdgcn_mfma_f32_16x16x32_bf16(af[tm], bf[tn], acc[tm][tn], 0, 0, 0);
    __syncthreads();
  }
  #pragma unroll
  for (int tm = 0; tm < 2; tm++){
    #pragma unroll
    for (int r = 0; r < 4; r++){
      int row = bm + wm + tm * 16 + quad * 4 + r;
      if (row >= NNODES) continue;
      #pragma unroll
      for (int tn = 0; tn < 4; tn++){
        int col = wn + tn * 16 + l16;
        float val = fmaxf(acc[tm][tn][r] + bias[col], 0.f);
        Xb[(size_t)row * 128 + col] = f2bf(val);
      }
    }
  }
}

// ---------------- MFMA GEMM with fused per-row attention dot ----------------
template<int K, int N, int MODE, int NH>
__global__ __launch_bounds__(256) void k_mfma(const unsigned short* __restrict__ A,
                                              const unsigned short* __restrict__ B0t,
                                              const unsigned short* __restrict__ B1t,
                                              void* __restrict__ C0, void* __restrict__ C1,
                                              const float* __restrict__ att,
                                              float* __restrict__ dl, float* __restrict__ dr){
  const unsigned short* Bt = blockIdx.z ? B1t : B0t;
  __shared__ unsigned short As[64][40];
  __shared__ unsigned short Bs[128][40];
  __shared__ float red[4][32];
  int tid = threadIdx.x;
  int bm = blockIdx.y * 64;
  int bn = blockIdx.x * 128;
  int head = (NH == 1) ? 0 : blockIdx.x;
  int w = tid >> 6, lane = tid & 63;
  int wm = (w >> 1) * 32, wn = (w & 1) * 64;
  int quad = lane >> 4, l16 = lane & 15;
  float av[4];
  #pragma unroll
  for (int tn = 0; tn < 4; tn++) av[tn] = att[head * 128 + wn + tn * 16 + l16];
  float4v acc[2][4];
  #pragma unroll
  for (int i = 0; i < 2; i++)
    #pragma unroll
    for (int j = 0; j < 4; j++) acc[i][j] = (float4v){0.f,0.f,0.f,0.f};
  int am = tid >> 2, ak = (tid & 3) * 8;
  int gm = bm + am;
  bool mv = gm < NNODES;
  int brow = tid >> 1, bk = (tid & 1) * 16;

  for (int k0 = 0; k0 < K; k0 += 32){
    uint4 va = {0u,0u,0u,0u};
    if (mv) va = *(const uint4*)(A + (size_t)gm * K + k0 + ak);
    *(uint4*)&As[am][ak] = va;
    const unsigned short* bp = Bt + (size_t)(bn + brow) * K + k0 + bk;
    *(uint4*)&Bs[brow][bk]     = *(const uint4*)bp;
    *(uint4*)&Bs[brow][bk + 8] = *(const uint4*)(bp + 8);
    __syncthreads();
    short8 af[2], bf[4];
    #pragma unroll
    for (int t = 0; t < 2; t++) af[t] = *(const short8*)&As[wm + t * 16 + l16][quad * 8];
    #pragma unroll
    for (int t = 0; t < 4; t++) bf[t] = *(const short8*)&Bs[wn + t * 16 + l16][quad * 8];
    #pragma unroll
    for (int tm = 0; tm < 2; tm++)
      #pragma unroll
      for (int tn = 0; tn < 4; tn++)
        acc[tm][tn] = __builtin_amdgcn_mfma_f32_16x16x32_bf16(af[tm], bf[tn], acc[tm][tn], 0, 0, 0);
    __syncthreads();
  }
  #pragma unroll
  for (int tm = 0; tm < 2; tm++){
    #pragma unroll
    for (int r = 0; r < 4; r++){
      int row = bm + wm + tm * 16 + quad * 4 + r;
      if (row < NNODES){
        #pragma unroll
        for (int tn = 0; tn < 4; tn++){
          int col = bn + wn + tn * 16 + l16;
          float val = acc[tm][tn][r];
          if (MODE == 0 || blockIdx.z == 0){
            unsigned short* C = (unsigned short*)(blockIdx.z ? C1 : C0);
            C[(size_t)row * N + col] = f2bf(val);
          } else {
            ((float*)C1)[(size_t)row * N + col] = val;
          }
        }
      }
      float pd = acc[tm][0][r] * av[0];
      pd = fmaf(acc[tm][1][r], av[1], pd);
      pd = fmaf(acc[tm][2][r], av[2], pd);
      pd = fmaf(acc[tm][3][r], av[3], pd);
      pd += __shfl_xor(pd, 1);
      pd += __shfl_xor(pd, 2);
      pd += __shfl_xor(pd, 4);
      pd += __shfl_xor(pd, 8);
      if (l16 == 0) red[w][tm * 16 + quad * 4 + r] = pd;
    }
  }
  __syncthreads();
  if (tid < 64){
    float v = (tid < 32) ? red[0][tid] + red[1][tid] : red[2][tid & 31] + red[3][tid & 31];
    int row = bm + tid;
    if (row < NNODES){
      float* D = blockIdx.z ? dr : dl;
      D[row * NH + head] = v;
    }
  }
}

// ---------------- attn1 batch compute (4 edges) ----------------
__device__ __forceinline__ void attn1_batch(const uint4* u, const float* d,
                                            const float* r, const float* a, float c0,
                                            float& m, float& s, float* acc){
  float x0[8], x1[8], x2[8], x3[8];
  unpack8(u[0], x0); unpack8(u[1], x1); unpack8(u[2], x2); unpack8(u[3], x3);
  float p0 = 0.f, p1 = 0.f, p2 = 0.f, p3 = 0.f;
  #pragma unroll
  for (int i = 0; i < 8; i++){
    p0 = fmaf(a[i], fabsf(x0[i] + r[i]), p0);
    p1 = fmaf(a[i], fabsf(x1[i] + r[i]), p1);
    p2 = fmaf(a[i], fabsf(x2[i] + r[i]), p2);
    p3 = fmaf(a[i], fabsf(x3[i] + r[i]), p3);
  }
  p0 += __shfl_xor(p0, 1); p1 += __shfl_xor(p1, 1); p2 += __shfl_xor(p2, 1); p3 += __shfl_xor(p3, 1);
  p0 += __shfl_xor(p0, 2); p1 += __shfl_xor(p1, 2); p2 += __shfl_xor(p2, 2); p3 += __shfl_xor(p3, 2);
  p0 += __shfl_xor(p0, 4); p1 += __shfl_xor(p1, 4); p2 += __shfl_xor(p2, 4); p3 += __shfl_xor(p3, 4);
  p0 += __shfl_xor(p0, 8); p1 += __shfl_xor(p1, 8); p2 += __shfl_xor(p2, 8); p3 += __shfl_xor(p3, 8);
  float e0 = fmaf(0.6f, d[0], fmaf(0.4f, p0, c0));
  float e1 = fmaf(0.6f, d[1], fmaf(0.4f, p1, c0));
  float e2 = fmaf(0.6f, d[2], fmaf(0.4f, p2, c0));
  float e3 = fmaf(0.6f, d[3], fmaf(0.4f, p3, c0));
  float emax = fmaxf(fmaxf(e0, e1), fmaxf(e2, e3));
  if (__any(emax > m)){
    float nm = fmaxf(m, emax);
    float al  = __expf(m - nm);
    float ex0 = __expf(e0 - nm), ex1 = __expf(e1 - nm);
    float ex2 = __expf(e2 - nm), ex3 = __expf(e3 - nm);
    m = nm;
    s = fmaf(s, al, (ex0 + ex1) + (ex2 + ex3));
    #pragma unroll
    for (int i = 0; i < 8; i++){
      float t = fmaf(ex0, x0[i], ex1 * x1[i]);
      t = fmaf(ex2, x2[i], t);
      t = fmaf(ex3, x3[i], t);
      acc[i] = fmaf(acc[i], al, t);
    }
  } else {
    float ex0 = __expf(e0 - m), ex1 = __expf(e1 - m);
    float ex2 = __expf(e2 - m), ex3 = __expf(e3 - m);
    s += (ex0 + ex1) + (ex2 + ex3);
    #pragma unroll
    for (int i = 0; i < 8; i++){
      float t = fmaf(ex0, x0[i], ex1 * x1[i]);
      t = fmaf(ex2, x2[i], t);
      acc[i] = fmaf(ex3, x3[i], acc[i] + t);
    }
  }
}

// ---------------- layer-1 GATv2: wave per node, 2-stage 4-edge pipeline ----------------
__global__ __launch_bounds__(256) void k_attn1(const unsigned short* __restrict__ xl,
                                               const unsigned short* __restrict__ xr,
                                               const float* __restrict__ dl, const float* __restrict__ dr,
                                               const float* __restrict__ att, const float* __restrict__ bias,
                                               const int* __restrict__ off, const int* __restrict__ csr,
                                               unsigned short* __restrict__ out){
  int lane = threadIdx.x & 63;
  int n = blockIdx.x * 4 + (threadIdx.x >> 6);
  int h = lane >> 4;
  uint4 ur = *(const uint4*)(xr + (size_t)n * 512 + lane * 8);
  float r[8]; unpack8(ur, r);
  const float* ap = att + lane * 8;
  float4 A0 = *(const float4*)ap, A1 = *(const float4*)(ap + 4);
  float a[8] = {A0.x,A0.y,A0.z,A0.w,A1.x,A1.y,A1.z,A1.w};
  float c0 = 0.6f * dr[n * 4 + h];
  int beg = off[n], end = off[n + 1];
  int cnt = end - beg;
  int nfull = cnt >> 2;

  float m = -INFINITY, s = 0.f;
  float acc[8] = {0,0,0,0,0,0,0,0};
  uint4 uA[4], uB[4];
  float dA[4], dB[4];
  int j = beg;
  if (nfull > 0){
    int s0 = csr[j], s1 = csr[j+1], s2 = csr[j+2], s3 = csr[j+3];
    uA[0] = *(const uint4*)(xl + (size_t)s0 * 512 + lane * 8);
    uA[1] = *(const uint4*)(xl + (size_t)s1 * 512 + lane * 8);
    uA[2] = *(const uint4*)(xl + (size_t)s2 * 512 + lane * 8);
    uA[3] = *(const uint4*)(xl + (size_t)s3 * 512 + lane * 8);
    dA[0] = dl[s0*4+h]; dA[1] = dl[s1*4+h]; dA[2] = dl[s2*4+h]; dA[3] = dl[s3*4+h];
  }
  for (int b = 0; b < nfull; b++){
    int jn = j + 4;
    if (b + 1 < nfull){
      int s0 = csr[jn], s1 = csr[jn+1], s2 = csr[jn+2], s3 = csr[jn+3];
      uB[0] = *(const uint4*)(xl + (size_t)s0 * 512 + lane * 8);
      uB[1] = *(const uint4*)(xl + (size_t)s1 * 512 + lane * 8);
      uB[2] = *(const uint4*)(xl + (size_t)s2 * 512 + lane * 8);
      uB[3] = *(const uint4*)(xl + (size_t)s3 * 512 + lane * 8);
      dB[0] = dl[s0*4+h]; dB[1] = dl[s1*4+h]; dB[2] = dl[s2*4+h]; dB[3] = dl[s3*4+h];
    }
    attn1_batch(uA, dA, r, a, c0, m, s, acc);
    j = jn;
    #pragma unroll
    for (int i = 0; i < 4; i++){ uA[i] = uB[i]; dA[i] = dB[i]; }
  }
  for (; j < end; j++){
    int sn = csr[j];
    float dls = dl[sn * 4 + h];
    uint4 ux = *(const uint4*)(xl + (size_t)sn * 512 + lane * 8);
    float x[8]; unpack8(ux, x);
    float p = 0.f;
    #pragma unroll
    for (int i = 0; i < 8; i++) p = fmaf(a[i], fabsf(x[i] + r[i]), p);
    p += __shfl_xor(p, 1);
    p += __shfl_xor(p, 2);
    p += __shfl_xor(p, 4);
    p += __shfl_xor(p, 8);
    float e = fmaf(0.6f, dls, fmaf(0.4f, p, c0));
    if (__any(e > m)){
      float nm = fmaxf(m, e);
      float al = __expf(m - nm);
      float ex = __expf(e - nm);
      m = nm;
      s = fmaf(s, al, ex);
      #pragma unroll
      for (int i = 0; i < 8; i++) acc[i] = fmaf(acc[i], al, ex * x[i]);
    } else {
      float ex = __expf(e - m);
      s += ex;
      #pragma unroll
      for (int i = 0; i < 8; i++) acc[i] = fmaf(ex, x[i], acc[i]);
    }
  }
  float inv = 1.f / (s + 1e-16f);
  const float* bp = bias + lane * 8;
  float4 B0 = *(const float4*)bp, B1 = *(const float4*)(bp + 4);
  float bb[8] = {B0.x,B0.y,B0.z,B0.w,B1.x,B1.y,B1.z,B1.w};
  unsigned short o[8];
  #pragma unroll
  for (int i = 0; i < 8; i++)
    o[i] = f2bf(fmaxf(fmaf(acc[i], inv, bb[i]), 0.f));
  uint4 ov;
  ov.x = (uint32)o[0] | ((uint32)o[1] << 16);
  ov.y = (uint32)o[2] | ((uint32)o[3] << 16);
  ov.z = (uint32)o[4] | ((uint32)o[5] << 16);
  ov.w = (uint32)o[6] | ((uint32)o[7] << 16);
  *(uint4*)(out + (size_t)n * 512 + lane * 8) = ov;
}

// ---------------- attn2 batch compute (4 edges) ----------------
__device__ __forceinline__ void attn2_batch(const uint32* u, const float* d,
                                            float2 rv, float2 av, float c0,
                                            float& m, float& s, float& a0, float& a1){
  float x00 = bflo(u[0]), x01 = bfhi(u[0]);
  float x10 = bflo(u[1]), x11 = bfhi(u[1]);
  float x20 = bflo(u[2]), x21 = bfhi(u[2]);
  float x30 = bflo(u[3]), x31 = bfhi(u[3]);
  float p0 = fmaf(av.x, fabsf(x00 + rv.x), av.y * fabsf(x01 + rv.y));
  float p1 = fmaf(av.x, fabsf(x10 + rv.x), av.y * fabsf(x11 + rv.y));
  float p2 = fmaf(av.x, fabsf(x20 + rv.x), av.y * fabsf(x21 + rv.y));
  float p3 = fmaf(av.x, fabsf(x30 + rv.x), av.y * fabsf(x31 + rv.y));
  p0 += __shfl_xor(p0, 1);  p1 += __shfl_xor(p1, 1);  p2 += __shfl_xor(p2, 1);  p3 += __shfl_xor(p3, 1);
  p0 += __shfl_xor(p0, 2);  p1 += __shfl_xor(p1, 2);  p2 += __shfl_xor(p2, 2);  p3 += __shfl_xor(p3, 2);
  p0 += __shfl_xor(p0, 4);  p1 += __shfl_xor(p1, 4);  p2 += __shfl_xor(p2, 4);  p3 += __shfl_xor(p3, 4);
  p0 += __shfl_xor(p0, 8);  p1 += __shfl_xor(p1, 8);  p2 += __shfl_xor(p2, 8);  p3 += __shfl_xor(p3, 8);
  p0 += __shfl_xor(p0, 16); p1 += __shfl_xor(p1, 16); p2 += __shfl_xor(p2, 16); p3 += __shfl_xor(p3, 16);
  p0 += __shfl_xor(p0, 32); p1 += __shfl_xor(p1, 32); p2 += __shfl_xor(p2, 32); p3 += __shfl_xor(p3, 32);
  float e0 = fmaf(0.6f, d[0], fmaf(0.4f, p0, c0));
  float e1 = fmaf(0.6f, d[1], fmaf(0.4f, p1, c0));
  float e2 = fmaf(0.6f, d[2], fmaf(0.4f, p2, c0));
  float e3 = fmaf(0.6f, d[3], fmaf(0.4f, p3, c0));
  float emax = fmaxf(fmaxf(e0, e1), fmaxf(e2, e3));
  if (emax > m){
    float al  = __expf(m - emax);
    float ex0 = __expf(e0 - emax), ex1 = __expf(e1 - emax);
    float ex2 = __expf(e2 - emax), ex3 = __expf(e3 - emax);
    m = emax;
    s  = fmaf(s,  al, (ex0 + ex1) + (ex2 + ex3));
    float t0 = fmaf(ex0, x00, ex1 * x10); t0 = fmaf(ex2, x20, t0); t0 = fmaf(ex3, x30, t0);
    float t1 = fmaf(ex0, x01, ex1 * x11); t1 = fmaf(ex2, x21, t1); t1 = fmaf(ex3, x31, t1);
    a0 = fmaf(a0, al, t0);
    a1 = fmaf(a1, al, t1);
  } else {
    float ex0 = __expf(e0 - m), ex1 = __expf(e1 - m);
    float ex2 = __expf(e2 - m), ex3 = __expf(e3 - m);
    s += (ex0 + ex1) + (ex2 + ex3);
    float t0 = fmaf(ex0, x00, ex1 * x10); t0 = fmaf(ex2, x20, t0);
    float t1 = fmaf(ex0, x01, ex1 * x11); t1 = fmaf(ex2, x21, t1);
    a0 = fmaf(ex3, x30, a0 + t0);
    a1 = fmaf(ex3, x31, a1 + t1);
  }
}

// ---------------- layer-2 GATv2 + fused output GEMM, 2-stage 4-edge pipeline ----------------
__global__ __launch_bounds__(256) void k_attn2(const unsigned short* __restrict__ xl,
                                               const float* __restrict__ xr,
                                               const float* __restrict__ dl, const float* __restrict__ dr,
                                               const float* __restrict__ att, const float* __restrict__ bias,
                                               const float* __restrict__ outW, const float* __restrict__ outb,
                                               const int* __restrict__ off, const int* __restrict__ csr,
                                               float* __restrict__ out){
  __shared__ float Wsh[1280];
  int tid = threadIdx.x;
  for (int i = tid; i < 1280; i += 256) Wsh[i] = outW[i];
  __syncthreads();
  int lane = tid & 63;
  int n = blockIdx.x * 4 + (tid >> 6);
  float2 rv = *(const float2*)(xr + (size_t)n * 128 + lane * 2);
  float2 av = *(const float2*)(att + lane * 2);
  float c0 = 0.6f * dr[n];
  int beg = off[n], end = off[n + 1];
  int cnt = end - beg;
  int nfull = cnt >> 2;
  float m = -INFINITY, s = 0.f;
  float a0 = 0.f, a1 = 0.f;
  uint32 uA[4], uB[4];
  float dA[4], dB[4];
  int j = beg;
  if (nfull > 0){
    int s0 = csr[j], s1 = csr[j+1], s2 = csr[j+2], s3 = csr[j+3];
    uA[0] = *(const uint32*)(xl + (size_t)s0 * 128 + lane * 2);
    uA[1] = *(const uint32*)(xl + (size_t)s1 * 128 + lane * 2);
    uA[2] = *(const uint32*)(xl + (size_t)s2 * 128 + lane * 2);
    uA[3] = *(const uint32*)(xl + (size_t)s3 * 128 + lane * 2);
    dA[0] = dl[s0]; dA[1] = dl[s1]; dA[2] = dl[s2]; dA[3] = dl[s3];
  }
  for (int b = 0; b < nfull; b++){
    int jn = j + 4;
    if (b + 1 < nfull){
      int s0 = csr[jn], s1 = csr[jn+1], s2 = csr[jn+2], s3 = csr[jn+3];
      uB[0] = *(const uint32*)(xl + (size_t)s0 * 128 + lane * 2);
      uB[1] = *(const uint32*)(xl + (size_t)s1 * 128 + lane * 2);
      uB[2] = *(const uint32*)(xl + (size_t)s2 * 128 + lane * 2);
      uB[3] = *(const uint32*)(xl + (size_t)s3 * 128 + lane * 2);
      dB[0] = dl[s0]; dB[1] = dl[s1]; dB[2] = dl[s2]; dB[3] = dl[s3];
    }
    attn2_batch(uA, dA, rv, av, c0, m, s, a0, a1);
    j = jn;
    #pragma unroll
    for (int i = 0; i < 4; i++){ uA[i] = uB[i]; dA[i] = dB[i]; }
  }
  for (; j < end; j++){
    int sn = csr[j];
    float dls = dl[sn];
    uint32 u = *(const uint32*)(xl + (size_t)sn * 128 + lane * 2);
    float x0 = bflo(u), x1 = bfhi(u);
    float p = fmaf(av.x, fabsf(x0 + rv.x), av.y * fabsf(x1 + rv.y));
    p += __shfl_xor(p, 1);
    p += __shfl_xor(p, 2);
    p += __shfl_xor(p, 4);
    p += __shfl_xor(p, 8);
    p += __shfl_xor(p, 16);
    p += __shfl_xor(p, 32);
    float e = fmaf(0.6f, dls, fmaf(0.4f, p, c0));
    if (e > m){
      float al = __expf(m - e);
      m = e;
      s  = fmaf(s,  al, 1.f);
      a0 = fmaf(a0, al, x0);
      a1 = fmaf(a1, al, x1);
    } else {
      float ex = __expf(e - m);
      s += ex;
      a0 = fmaf(ex, x0, a0);
      a1 = fmaf(ex, x1, a1);
    }
  }
  float inv = 1.f / (s + 1e-16f);
  int c = lane * 2;
  float x2_0 = fmaf(a0, inv, bias[c]);
  float x2_1 = fmaf(a1, inv, bias[c + 1]);
  #pragma unroll
  for (int o = 0; o < 10; o++){
    float p = fmaf(x2_0, Wsh[c * 10 + o], x2_1 * Wsh[(c + 1) * 10 + o]);
    p += __shfl_xor(p, 1);
    p += __shfl_xor(p, 2);
    p += __shfl_xor(p, 4);
    p += __shfl_xor(p, 8);
    p += __shfl_xor(p, 16);
    p += __shfl_xor(p, 32);
    if (lane == 0) out[(size_t)n * 10 + o] = p + outb[o];
  }
}

extern "C" void kernel_launch(void* const* d_in, const int* in_sizes, int n_in,
                              void* d_out, int out_size, void* d_ws, size_t ws_size,
                              hipStream_t stream){
  const float* xp    = (const float*)d_in[0];
  const int*   ei    = (const int*)  d_in[1];
  const float* emb   = (const float*)d_in[2];
  const float* projW = (const float*)d_in[3];
  const float* projb = (const float*)d_in[4];
  const float* W1l   = (const float*)d_in[5];
  const float* W1r   = (const float*)d_in[6];
  const float* att1  = (const float*)d_in[7];
  const float* b1    = (const float*)d_in[8];
  const float* W2l   = (const float*)d_in[9];
  const float* W2r   = (const float*)d_in[10];
  const float* att2  = (const float*)d_in[11];
  const float* b2    = (const float*)d_in[12];
  const float* outW  = (const float*)d_in[13];
  const float* outb  = (const float*)d_in[14];
  float* out = (float*)d_out;

  int E = in_sizes[1] / 2;
  const int* esrc = ei;
  const int* edst = ei + E;

  char* w = (char*)d_ws;
  int* deg  = (int*)w; w += (size_t)NNODES * 4;
  int* off  = (int*)w; w += (size_t)(NNODES + 4) * 4;
  int* cur  = (int*)w; w += (size_t)NNODES * 4;
  int* csr  = (int*)w; w += (size_t)(NNODES + E) * 4;
  unsigned short* Xb   = (unsigned short*)w; w += (size_t)NNODES * 128 * 2;
  unsigned short* Wt1l = (unsigned short*)w; w += (size_t)512 * 128 * 2;
  unsigned short* Wt1r = (unsigned short*)w; w += (size_t)512 * 128 * 2;
  unsigned short* Wt2l = (unsigned short*)w; w += (size_t)128 * 512 * 2;
  unsigned short* Wt2r = (unsigned short*)w; w += (size_t)128 * 512 * 2;
  unsigned short* Wtp  = (unsigned short*)w; w += (size_t)128 * 192 * 2;
  unsigned short* xl1b = (unsigned short*)w; w += (size_t)NNODES * 512 * 2;
  unsigned short* xr1b = (unsigned short*)w; w += (size_t)NNODES * 512 * 2;
  unsigned short* X1b  = (unsigned short*)w; w += (size_t)NNODES * 512 * 2;
  unsigned short* xl2b = (unsigned short*)w; w += (size_t)NNODES * 128 * 2;
  float* xr2 = (float*)w; w += (size_t)NNODES * 128 * 4;
  float* dl1 = (float*)w; w += (size_t)NNODES * 4 * 4;
  float* dr1 = (float*)w; w += (size_t)NNODES * 4 * 4;
  float* dl2 = (float*)w; w += (size_t)NNODES * 4;
  float* dr2 = (float*)w; w += (size_t)NNODES * 4;

  hipMemsetAsync(deg, 0, (size_t)NNODES * 4, stream);
  int cvt_total = E + 286720;
  k_cvt_count<<<(cvt_total + 255) / 256, 256, 0, stream>>>(
      edst, E, deg, W1l, W1r, W2l, W2r, projW, Wt1l, Wt1r, Wt2l, Wt2r, Wtp);
  k_scan<<<1, 256, 0, stream>>>(deg, off, cur);
  k_fill<<<(NNODES + E + 255) / 256, 256, 0, stream>>>(esrc, edst, E, cur, csr);

  k_proj_mfma<<<dim3((NNODES + 63) / 64), 256, 0, stream>>>(xp, emb, Wtp, projb, Xb);
  k_mfma<128, 512, 0, 4><<<dim3(4, (NNODES + 63) / 64, 2), 256, 0, stream>>>(
      Xb, Wt1l, Wt1r, xl1b, xr1b, att1, dl1, dr1);
  k_attn1<<<NNODES / 4, 256, 0, stream>>>(xl1b, xr1b, dl1, dr1, att1, b1, off, csr, X1b);
  k_mfma<512, 128, 1, 1><<<dim3(1, (NNODES + 63) / 64, 2), 256, 0, stream>>>(
      X1b, Wt2l, Wt2r, xl2b, xr2, att2, dl2, dr2);
  k_attn2<<<NNODES / 4, 256, 0, stream>>>(xl2b, xr2, dl2, dr2, att2, b2, outW, outb, off, csr, out);
}